// Round 1
// baseline (673.184 us; speedup 1.0000x reference)
//
#include <hip/hip_runtime.h>
#include <math.h>

// Mamba block forward: B=4, DIM=256, L=64*64=4096, D_INNER=512, D_STATE=16,
// DT_RANK=16, D_CONV=4.
// Pipeline: in_proj GEMM -> depthwise causal conv+SiLU -> x_proj -> dt_proj
// (+softplus) -> chunked selective scan -> gate -> out_proj GEMM.

namespace {
constexpr int kB   = 4;
constexpr int kDim = 256;
constexpr int kL   = 4096;
constexpr int kDI  = 512;
constexpr int kN   = 16;   // d_state
constexpr int kE2  = 1024; // 2*d_inner
constexpr int kNC  = 32;   // scan chunks
constexpr int kCS  = 128;  // chunk size (kNC*kCS == kL)
} // namespace

__device__ __forceinline__ float siluf(float x) { return x / (1.f + expf(-x)); }

// ---------------------------------------------------------------------------
// Kernel 1: xz[b,l,e] = sum_d x[b,d,l] * W[e,d]; split into u (e<512), res.
// fp32 LDS-tiled GEMM, 64x64 tile, 4x4 per-thread.
// ---------------------------------------------------------------------------
__global__ __launch_bounds__(256) void k_in_proj(const float* __restrict__ x,
                                                 const float* __restrict__ W,
                                                 float* __restrict__ u,
                                                 float* __restrict__ res) {
  __shared__ float Xs[64][64];   // [d_local][l_local]
  __shared__ float Ws[64][65];   // [d_local][e_local], padded
  const int l0 = blockIdx.x * 64;
  const int e0 = blockIdx.y * 64;
  const int b  = blockIdx.z;
  const int t  = threadIdx.x;
  const int te = t & 15;   // e sub-tile (x4)
  const int tl = t >> 4;   // l sub-tile (x4)
  const float* xb = x + (size_t)b * kDim * kL;
  float acc[4][4] = {};
  for (int d0 = 0; d0 < kDim; d0 += 64) {
#pragma unroll
    for (int k = 0; k < 16; ++k) {
      int i  = t + k * 256;
      int hi = i >> 6, lo = i & 63;
      Xs[hi][lo] = xb[(size_t)(d0 + hi) * kL + (l0 + lo)];           // coalesced over l
      Ws[lo][hi] = W[(size_t)(e0 + hi) * kDim + (d0 + lo)];          // coalesced over d
    }
    __syncthreads();
#pragma unroll 8
    for (int k = 0; k < 64; ++k) {
      float a[4], bb[4];
#pragma unroll
      for (int i = 0; i < 4; ++i) a[i] = Xs[k][tl * 4 + i];
#pragma unroll
      for (int j = 0; j < 4; ++j) bb[j] = Ws[k][te * 4 + j];
#pragma unroll
      for (int i = 0; i < 4; ++i)
#pragma unroll
        for (int j = 0; j < 4; ++j) acc[i][j] += a[i] * bb[j];
    }
    __syncthreads();
  }
  const int e = e0 + te * 4;
#pragma unroll
  for (int i = 0; i < 4; ++i) {
    int l = l0 + tl * 4 + i;
    float4 v = make_float4(acc[i][0], acc[i][1], acc[i][2], acc[i][3]);
    if (e < kDI)
      *(float4*)&u[((size_t)b * kL + l) * kDI + e] = v;
    else
      *(float4*)&res[((size_t)b * kL + l) * kDI + (e - kDI)] = v;
  }
}

// ---------------------------------------------------------------------------
// Kernel 2: causal depthwise conv (k=4) + bias + SiLU.
// uc[b,l,d] = silu(sum_k w[d,k]*u[b,l-3+k,d] + cb[d])
// ---------------------------------------------------------------------------
__global__ __launch_bounds__(256) void k_conv(const float* __restrict__ u,
                                              const float* __restrict__ cw,
                                              const float* __restrict__ cb,
                                              float* __restrict__ uc) {
  int idx = blockIdx.x * 256 + threadIdx.x;   // over B*L*DI
  int d  = idx & (kDI - 1);
  int bl = idx >> 9;                          // b*L + l
  int l  = bl & (kL - 1);
  float4 w = *(const float4*)&cw[d * 4];
  float acc = cb[d];
  const float* up = u + (size_t)(bl - l) * kDI + d;  // base of batch b
  if (l >= 3) acc += w.x * up[(size_t)(l - 3) * kDI];
  if (l >= 2) acc += w.y * up[(size_t)(l - 2) * kDI];
  if (l >= 1) acc += w.z * up[(size_t)(l - 1) * kDI];
  acc += w.w * up[(size_t)l * kDI];
  uc[idx] = siluf(acc);
}

// ---------------------------------------------------------------------------
// Kernel 3: dbc[row,e] = sum_d uc[row,d] * Wx[e,d], e in [0,48).
// One wave handles 4 rows; row (512) held in registers; wave-reduce per e.
// ---------------------------------------------------------------------------
__global__ __launch_bounds__(256) void k_xproj(const float* __restrict__ uc,
                                               const float* __restrict__ W,
                                               float* __restrict__ dbc) {
  const int lane = threadIdx.x & 63;
  const int wv   = threadIdx.x >> 6;
  const int r0   = (blockIdx.x * 4 + wv) * 4;   // 4 rows per wave
  float ur[4][8];
#pragma unroll
  for (int rr = 0; rr < 4; ++rr)
#pragma unroll
    for (int k = 0; k < 8; ++k)
      ur[rr][k] = uc[(size_t)(r0 + rr) * kDI + lane + 64 * k];
  for (int e = 0; e < 48; ++e) {
    const float* wr = W + (size_t)e * kDI;
    float w[8];
#pragma unroll
    for (int k = 0; k < 8; ++k) w[k] = wr[lane + 64 * k];
    float p0 = 0.f, p1 = 0.f, p2 = 0.f, p3 = 0.f;
#pragma unroll
    for (int k = 0; k < 8; ++k) {
      p0 += w[k] * ur[0][k];
      p1 += w[k] * ur[1][k];
      p2 += w[k] * ur[2][k];
      p3 += w[k] * ur[3][k];
    }
#pragma unroll
    for (int off = 32; off > 0; off >>= 1) {
      p0 += __shfl_down(p0, off);
      p1 += __shfl_down(p1, off);
      p2 += __shfl_down(p2, off);
      p3 += __shfl_down(p3, off);
    }
    if (lane == 0) {
      dbc[(size_t)(r0 + 0) * 48 + e] = p0;
      dbc[(size_t)(r0 + 1) * 48 + e] = p1;
      dbc[(size_t)(r0 + 2) * 48 + e] = p2;
      dbc[(size_t)(r0 + 3) * 48 + e] = p3;
    }
  }
}

// ---------------------------------------------------------------------------
// Kernel 4: delta[row,d] = softplus(sum_r dbc[row,r]*Wdt[d,r] + bdt[d])
// ---------------------------------------------------------------------------
__global__ __launch_bounds__(256) void k_dtproj(const float* __restrict__ dbc,
                                                const float* __restrict__ Wdt,
                                                const float* __restrict__ bdt,
                                                float* __restrict__ delta) {
  int idx = blockIdx.x * 256 + threadIdx.x;  // over B*L*DI
  int d = idx & (kDI - 1);
  size_t row = (size_t)(idx >> 9);
  const float* dt = dbc + row * 48;
  const float* wr = Wdt + (size_t)d * 16;
  float acc = bdt[d];
#pragma unroll
  for (int r = 0; r < 16; ++r) acc += dt[r] * wr[r];
  // softplus matching jax.nn.softplus
  delta[idx] = fmaxf(acc, 0.f) + log1pf(expf(-fabsf(acc)));
}

// ---------------------------------------------------------------------------
// Scan phase A: per (b,d,n,chunk) compose (P = prod a, S = sum b_j prod a_{>j}).
// a_l = exp(delta*A), b_l = delta*B*u.
// ---------------------------------------------------------------------------
__global__ __launch_bounds__(256) void k_scanA(const float* __restrict__ delta,
                                               const float* __restrict__ uc,
                                               const float* __restrict__ dbc,
                                               const float* __restrict__ A_log,
                                               float* __restrict__ P,
                                               float* __restrict__ S) {
  const int b  = blockIdx.z, ch = blockIdx.y;
  const int d  = blockIdx.x * 16 + (threadIdx.x & 15);
  const int n  = threadIdx.x >> 4;
  const float Av = -expf(A_log[d * kN + n]);
  const int l0 = ch * kCS;
  size_t pD = ((size_t)b * kL + l0) * kDI + d;
  size_t pB = ((size_t)b * kL + l0) * 48 + 16 + n;
  float Pv = 1.f, Sv = 0.f;
  for (int i = 0; i < kCS; ++i) {
    float dv = delta[pD];
    float uv = uc[pD];
    float Bv = dbc[pB];
    float a  = expf(dv * Av);
    Pv *= a;
    Sv = Sv * a + dv * Bv * uv;
    pD += kDI;
    pB += 48;
  }
  size_t o = (((size_t)b * kDI + d) * kN + n) * kNC + ch;
  P[o] = Pv;
  S[o] = Sv;
}

// ---------------------------------------------------------------------------
// Scan phase B: serial combine over chunks -> per-chunk initial states.
// ---------------------------------------------------------------------------
__global__ __launch_bounds__(256) void k_scanB(const float* __restrict__ P,
                                               const float* __restrict__ S,
                                               float* __restrict__ init) {
  int idx = blockIdx.x * 256 + threadIdx.x;  // over B*DI*N = 32768
  const float* Pr = P + (size_t)idx * kNC;
  const float* Sr = S + (size_t)idx * kNC;
  float* Ir = init + (size_t)idx * kNC;
  float carry = 0.f;
  for (int c = 0; c < kNC; ++c) {
    Ir[c] = carry;
    carry = Pr[c] * carry + Sr[c];
  }
}

// ---------------------------------------------------------------------------
// Scan phase C: replay chunk from init state, y[b,l,d] = sum_n s*C (shfl over n).
// Lane layout: n = t&15 (reduce group), d sub = t>>4.
// ---------------------------------------------------------------------------
__global__ __launch_bounds__(256) void k_scanC(const float* __restrict__ delta,
                                               const float* __restrict__ uc,
                                               const float* __restrict__ dbc,
                                               const float* __restrict__ A_log,
                                               const float* __restrict__ init,
                                               float* __restrict__ y) {
  const int b  = blockIdx.z, ch = blockIdx.y;
  const int n  = threadIdx.x & 15;
  const int d  = blockIdx.x * 16 + (threadIdx.x >> 4);
  const float Av = -expf(A_log[d * kN + n]);
  const int l0 = ch * kCS;
  float s = init[(((size_t)b * kDI + d) * kN + n) * kNC + ch];
  size_t pD  = ((size_t)b * kL + l0) * kDI + d;
  size_t pBC = ((size_t)b * kL + l0) * 48 + n;
  for (int i = 0; i < kCS; ++i) {
    float dv = delta[pD];
    float uv = uc[pD];
    float Bv = dbc[pBC + 16];
    float Cv = dbc[pBC + 32];
    float a  = expf(dv * Av);
    s = s * a + dv * Bv * uv;
    float p = s * Cv;
    p += __shfl_xor(p, 1);
    p += __shfl_xor(p, 2);
    p += __shfl_xor(p, 4);
    p += __shfl_xor(p, 8);
    if (n == 0) y[pD] = p;
    pD += kDI;
    pBC += 48;
  }
}

// ---------------------------------------------------------------------------
// Kernel 6: y = (y + uc*D) * silu(res), in place.
// ---------------------------------------------------------------------------
__global__ __launch_bounds__(256) void k_gate(float* __restrict__ y,
                                              const float* __restrict__ uc,
                                              const float* __restrict__ res,
                                              const float* __restrict__ Dp) {
  int idx = blockIdx.x * 256 + threadIdx.x;
  int d = idx & (kDI - 1);
  float yy = y[idx] + uc[idx] * Dp[d];
  float r = res[idx];
  y[idx] = yy * siluf(r);
}

// ---------------------------------------------------------------------------
// Kernel 7: out[b,c,l] = sum_e y[b,l,e] * Wout[c,e]  (transposed-output GEMM)
// ---------------------------------------------------------------------------
__global__ __launch_bounds__(256) void k_outproj(const float* __restrict__ y,
                                                 const float* __restrict__ W,
                                                 float* __restrict__ out) {
  __shared__ float Ys[64][65];  // [k_local][l_local], padded
  __shared__ float Ws[64][65];  // [k_local][c_local], padded
  const int l0 = blockIdx.x * 64;
  const int c0 = blockIdx.y * 64;
  const int b  = blockIdx.z;
  const int t  = threadIdx.x;
  const int tl = t & 15;   // l sub-tile (x4) -> coalesced out stores
  const int tc = t >> 4;   // c sub-tile (x4)
  float acc[4][4] = {};    // [li][cj]
  for (int k0 = 0; k0 < kDI; k0 += 64) {
#pragma unroll
    for (int k = 0; k < 16; ++k) {
      int i  = t + k * 256;
      int kk = i & 63, q = i >> 6;
      Ys[kk][q] = y[((size_t)b * kL + l0 + q) * kDI + k0 + kk];   // coalesced over e
      Ws[kk][q] = W[(size_t)(c0 + q) * kDI + k0 + kk];            // coalesced over e
    }
    __syncthreads();
#pragma unroll 8
    for (int k = 0; k < 64; ++k) {
      float a[4], bb[4];
#pragma unroll
      for (int i = 0; i < 4; ++i) a[i] = Ys[k][tl * 4 + i];
#pragma unroll
      for (int j = 0; j < 4; ++j) bb[j] = Ws[k][tc * 4 + j];
#pragma unroll
      for (int i = 0; i < 4; ++i)
#pragma unroll
        for (int j = 0; j < 4; ++j) acc[i][j] += a[i] * bb[j];
    }
    __syncthreads();
  }
#pragma unroll
  for (int j = 0; j < 4; ++j) {
    int c = c0 + tc * 4 + j;
    float4 v = make_float4(acc[0][j], acc[1][j], acc[2][j], acc[3][j]);
    *(float4*)&out[((size_t)b * kDim + c) * kL + l0 + tl * 4] = v;
  }
}

// ---------------------------------------------------------------------------
extern "C" void kernel_launch(void* const* d_in, const int* in_sizes, int n_in,
                              void* d_out, int out_size, void* d_ws, size_t ws_size,
                              hipStream_t stream) {
  const float* x       = (const float*)d_in[0];
  const float* in_w    = (const float*)d_in[1];
  const float* conv_w  = (const float*)d_in[2];
  const float* conv_b  = (const float*)d_in[3];
  const float* xproj_w = (const float*)d_in[4];
  const float* dt_w    = (const float*)d_in[5];
  const float* dt_b    = (const float*)d_in[6];
  const float* A_log   = (const float*)d_in[7];
  const float* Dp      = (const float*)d_in[8];
  const float* out_w   = (const float*)d_in[9];
  float* out = (float*)d_out;

  // workspace layout (floats); total ~150 MB
  float* ws = (float*)d_ws;
  const size_t nBLD = (size_t)kB * kL * kDI;  // 8388608
  float* u_pre = ws;
  float* resb  = u_pre + nBLD;
  float* ucb   = resb + nBLD;
  float* yb    = ucb + nBLD;
  float* dbcb  = yb + nBLD;                         // B*L*48
  float* Pb    = dbcb + (size_t)kB * kL * 48;       // B*DI*N*NC
  float* Sb    = Pb + (size_t)kB * kDI * kN * kNC;
  float* initb = Sb + (size_t)kB * kDI * kN * kNC;
  float* deltab = u_pre;  // reuse: u_pre dead after conv

  k_in_proj<<<dim3(kL / 64, kE2 / 64, kB), 256, 0, stream>>>(x, in_w, u_pre, resb);
  k_conv<<<dim3((unsigned)(nBLD / 256)), 256, 0, stream>>>(u_pre, conv_w, conv_b, ucb);
  k_xproj<<<dim3(kB * kL / 16), 256, 0, stream>>>(ucb, xproj_w, dbcb);
  k_dtproj<<<dim3((unsigned)(nBLD / 256)), 256, 0, stream>>>(dbcb, dt_w, dt_b, deltab);
  k_scanA<<<dim3(kDI / 16, kNC, kB), 256, 0, stream>>>(deltab, ucb, dbcb, A_log, Pb, Sb);
  k_scanB<<<dim3(kB * kDI * kN / 256), 256, 0, stream>>>(Pb, Sb, initb);
  k_scanC<<<dim3(kDI / 16, kNC, kB), 256, 0, stream>>>(deltab, ucb, dbcb, A_log, initb, yb);
  k_gate<<<dim3((unsigned)(nBLD / 256)), 256, 0, stream>>>(yb, ucb, resb, Dp);
  k_outproj<<<dim3(kL / 64, kDim / 64, kB), 256, 0, stream>>>(yb, out_w, out);
}

// Round 2
// 481.525 us; speedup vs baseline: 1.3980x; 1.3980x over previous
//
#include <hip/hip_runtime.h>
#include <math.h>

// Mamba block forward, channel-major intermediates [b, d, l].
// B=4, DIM=256, L=4096, D_INNER=512, D_STATE=16, DT_RANK=16, D_CONV=4.
// in_proj/out_proj: bf16 MFMA GEMM (A=[M,K] weights, B^T=[N,K] activations).

namespace {
constexpr int kB   = 4;
constexpr int kDim = 256;
constexpr int kL   = 4096;
constexpr int kDI  = 512;
constexpr int kN   = 16;
constexpr int kNC  = 32;   // scan chunks
constexpr int kCS  = 128;  // chunk size
} // namespace

typedef __attribute__((ext_vector_type(8))) short bf16x8;
typedef __attribute__((ext_vector_type(4))) float f32x4;

__device__ __forceinline__ float siluf(float x) { return x / (1.f + expf(-x)); }

__device__ __forceinline__ unsigned short f2bf(float x) {
  union { float f; unsigned int u; } v; v.f = x;
  unsigned int u = v.u;
  u += 0x7fffu + ((u >> 16) & 1u);   // RNE
  return (unsigned short)(u >> 16);
}
__device__ __forceinline__ float bf2f(unsigned short u) {
  union { unsigned int i; float f; } v; v.i = ((unsigned int)u) << 16; return v.f;
}

__device__ __forceinline__ void gload_lds16(const void* g, void* l) {
  __builtin_amdgcn_global_load_lds(
      (const __attribute__((address_space(1))) unsigned int*)g,
      (__attribute__((address_space(3))) unsigned int*)l, 16, 0, 0);
}

// ---------------------------------------------------------------------------
// Convert weights to bf16: in_proj_w [1024,256], out_proj_w [256,512].
// ---------------------------------------------------------------------------
__global__ __launch_bounds__(256) void k_wcvt(const float* __restrict__ w_in,
                                              const float* __restrict__ w_out,
                                              unsigned short* __restrict__ wib,
                                              unsigned short* __restrict__ wob) {
  int idx = blockIdx.x * 256 + threadIdx.x;
  if (idx < 262144) wib[idx] = f2bf(w_in[idx]);
  else              wob[idx - 262144] = f2bf(w_out[idx - 262144]);
}

// ---------------------------------------------------------------------------
// Transpose-convert x [b, d, l] f32 -> xt [b, l, d] bf16 (B^T for in_proj).
// ---------------------------------------------------------------------------
__global__ __launch_bounds__(256) void k_xt(const float* __restrict__ x,
                                            unsigned short* __restrict__ xt) {
  __shared__ float Xs[64][65];
  const int b = blockIdx.z, d0 = blockIdx.y * 64, l0 = blockIdx.x * 64;
  const int t = threadIdx.x, l = t & 63;
#pragma unroll
  for (int rep = 0; rep < 16; ++rep) {
    int dd = rep * 4 + (t >> 6);
    Xs[dd][l] = x[((size_t)b * kDim + d0 + dd) * kL + l0 + l];
  }
  __syncthreads();
#pragma unroll
  for (int rep = 0; rep < 8; ++rep) {
    int lj = rep * 8 + (t >> 5);
    int di = (t & 31) * 2;
    ushort2 v;
    v.x = f2bf(Xs[di][lj]);
    v.y = f2bf(Xs[di + 1][lj]);
    *(ushort2*)(xt + ((size_t)b * kL + l0 + lj) * kDim + d0 + di) = v;
  }
}

// ---------------------------------------------------------------------------
// bf16 MFMA GEMM: C[b][m][n] = sum_k A[m,k] * Bt[b][n,k].
// Tile 128x128, BK=64, 256 threads (2x2 waves of 64x64), swizzled LDS.
// SPLIT: rows m<512 -> C0 (f32 [b,512,N]); m>=512 -> C1res (bf16 [b,512,N]).
// ---------------------------------------------------------------------------
template <int K, bool SPLIT>
__global__ __launch_bounds__(256) void gemm_bt(const unsigned short* __restrict__ A,
                                               const unsigned short* __restrict__ Bt,
                                               float* __restrict__ C0,
                                               unsigned short* __restrict__ C1res,
                                               int N, int Mout) {
  __shared__ __align__(16) unsigned short As[128 * 64];
  __shared__ __align__(16) unsigned short Bs[128 * 64];
  const int n0 = blockIdx.x * 128;
  const int m0 = blockIdx.y * 128;
  const int b  = blockIdx.z;
  const int t  = threadIdx.x;
  const int wave = t >> 6, lane = t & 63;
  const int wm = wave >> 1, wn = wave & 1;
  const unsigned short* Bb = Bt + (size_t)b * N * K;

  f32x4 acc[4][4];
#pragma unroll
  for (int i = 0; i < 4; ++i)
#pragma unroll
    for (int j = 0; j < 4; ++j) acc[i][j] = (f32x4)0.0f;

  const int srow = t >> 3;   // 0..31 (per staging call)
  const int sch  = t & 7;    // 16B chunk within 128B row

  for (int kt = 0; kt < K / 64; ++kt) {
    const int k0 = kt * 64;
#pragma unroll
    for (int c = 0; c < 4; ++c) {
      int row = c * 32 + srow;
      int gch = sch ^ (row & 7);   // inverse-swizzled global source
      const unsigned short* ga = A  + (size_t)(m0 + row) * K + k0 + gch * 8;
      const unsigned short* gb = Bb + (size_t)(n0 + row) * K + k0 + gch * 8;
      char* la = (char*)As + c * 4096 + wave * 1024;
      char* lb = (char*)Bs + c * 4096 + wave * 1024;
      gload_lds16(ga, la);
      gload_lds16(gb, lb);
    }
    __syncthreads();
#pragma unroll
    for (int ks = 0; ks < 2; ++ks) {
      bf16x8 af[4], bfr[4];
#pragma unroll
      for (int f = 0; f < 4; ++f) {
        int ra = wm * 64 + f * 16 + (lane & 15);
        int ca = (ks * 4 + (lane >> 4)) ^ (ra & 7);
        af[f] = *(const bf16x8*)((const char*)As + ra * 128 + ca * 16);
        int rb = wn * 64 + f * 16 + (lane & 15);
        int cb = (ks * 4 + (lane >> 4)) ^ (rb & 7);
        bfr[f] = *(const bf16x8*)((const char*)Bs + rb * 128 + cb * 16);
      }
#pragma unroll
      for (int i = 0; i < 4; ++i)
#pragma unroll
        for (int j = 0; j < 4; ++j)
          acc[i][j] = __builtin_amdgcn_mfma_f32_16x16x32_bf16(af[i], bfr[j], acc[i][j], 0, 0, 0);
    }
    __syncthreads();
  }

  const int mbase = m0 + wm * 64;
  const int nbase = n0 + wn * 64;
  bool to_res = SPLIT && (m0 >= 512);
  int moff = to_res ? (mbase - 512) : mbase;
#pragma unroll
  for (int i = 0; i < 4; ++i)
#pragma unroll
    for (int j = 0; j < 4; ++j)
#pragma unroll
      for (int r = 0; r < 4; ++r) {
        int m = moff + i * 16 + (lane >> 4) * 4 + r;
        int n = nbase + j * 16 + (lane & 15);
        size_t off = ((size_t)b * Mout + m) * N + n;
        if (to_res) C1res[off] = f2bf(acc[i][j][r]);
        else        C0[off] = acc[i][j][r];
      }
}

// ---------------------------------------------------------------------------
// Causal depthwise conv k=4 + bias + SiLU over l, channel-major. float4.
// ---------------------------------------------------------------------------
__global__ __launch_bounds__(256) void k_conv(const float* __restrict__ u,
                                              const float* __restrict__ cw,
                                              const float* __restrict__ cb,
                                              float* __restrict__ uc) {
  int idx = blockIdx.x * 256 + threadIdx.x;   // over B*DI*(L/4)
  int l4 = (idx & (kL / 4 - 1)) * 4;
  int bd = idx >> 10;
  int d  = bd & (kDI - 1);
  const float* row = u + (size_t)bd * kL;
  float4 cur = *(const float4*)(row + l4);
  float4 prev = make_float4(0.f, 0.f, 0.f, 0.f);
  if (l4 > 0) prev = *(const float4*)(row + l4 - 4);
  float4 w = *(const float4*)(cw + d * 4);
  float bias = cb[d];
  float o0 = bias + w.x * prev.y + w.y * prev.z + w.z * prev.w + w.w * cur.x;
  float o1 = bias + w.x * prev.z + w.y * prev.w + w.z * cur.x + w.w * cur.y;
  float o2 = bias + w.x * prev.w + w.y * cur.x + w.z * cur.y + w.w * cur.z;
  float o3 = bias + w.x * cur.x  + w.y * cur.y + w.z * cur.z + w.w * cur.w;
  float4 o = make_float4(siluf(o0), siluf(o1), siluf(o2), siluf(o3));
  *(float4*)(uc + (size_t)bd * kL + l4) = o;
}

// ---------------------------------------------------------------------------
// x_proj: dbc[b, e', l] = sum_d uc[b,d,l] * Wx[e',d], e' in [0,48). VALU.
// 512 threads: 8 waves x 6 e' each; uc staged in LDS per 64-d tile.
// ---------------------------------------------------------------------------
__global__ __launch_bounds__(512) void k_xproj(const float* __restrict__ uc,
                                               const float* __restrict__ W,
                                               float* __restrict__ dbc) {
  __shared__ float Us[64][65];
  const int b = blockIdx.y, l0 = blockIdx.x * 64;
  const int t = threadIdx.x, l = t & 63, eg = t >> 6;   // eg 0..7
  float acc[6] = {};
  for (int d0 = 0; d0 < kDI; d0 += 64) {
#pragma unroll
    for (int rep = 0; rep < 8; ++rep) {
      int dd = rep * 8 + eg;
      Us[dd][l] = uc[((size_t)b * kDI + d0 + dd) * kL + l0 + l];
    }
    __syncthreads();
#pragma unroll 8
    for (int dd = 0; dd < 64; ++dd) {
      float v = Us[dd][l];
#pragma unroll
      for (int j = 0; j < 6; ++j)
        acc[j] += v * W[(size_t)(eg * 6 + j) * kDI + d0 + dd];
    }
    __syncthreads();
  }
#pragma unroll
  for (int j = 0; j < 6; ++j)
    dbc[((size_t)b * 48 + eg * 6 + j) * kL + l0 + l] = acc[j];
}

// ---------------------------------------------------------------------------
// dt_proj + softplus: delta[b,d,l] = softplus(sum_r dbc[b,r,l]*Wdt[d,r]+bdt[d])
// ---------------------------------------------------------------------------
__global__ __launch_bounds__(256) void k_dtproj(const float* __restrict__ dbc,
                                                const float* __restrict__ Wdt,
                                                const float* __restrict__ bdt,
                                                float* __restrict__ delta) {
  int idx = blockIdx.x * 256 + threadIdx.x;   // over B*DI*(L/4)
  int l4 = (idx & (kL / 4 - 1)) * 4;
  int bd = idx >> 10;
  int b = bd >> 9, d = bd & (kDI - 1);
  const float* base = dbc + (size_t)b * 48 * kL + l4;
  float bias = bdt[d];
  float4 acc = make_float4(bias, bias, bias, bias);
#pragma unroll
  for (int r = 0; r < 16; ++r) {
    float w = Wdt[d * 16 + r];
    float4 v = *(const float4*)(base + (size_t)r * kL);
    acc.x += w * v.x; acc.y += w * v.y; acc.z += w * v.z; acc.w += w * v.w;
  }
  float4 o;
  o.x = fmaxf(acc.x, 0.f) + log1pf(expf(-fabsf(acc.x)));
  o.y = fmaxf(acc.y, 0.f) + log1pf(expf(-fabsf(acc.y)));
  o.z = fmaxf(acc.z, 0.f) + log1pf(expf(-fabsf(acc.z)));
  o.w = fmaxf(acc.w, 0.f) + log1pf(expf(-fabsf(acc.w)));
  *(float4*)(delta + (size_t)bd * kL + l4) = o;
}

// ---------------------------------------------------------------------------
// Scan phase A: per (b,ch,d,n) chunk summaries P=prod a, S=sum b prod a.
// ---------------------------------------------------------------------------
__global__ __launch_bounds__(256) void k_scanA(const float* __restrict__ delta,
                                               const float* __restrict__ uc,
                                               const float* __restrict__ dbc,
                                               const float* __restrict__ A_log,
                                               float* __restrict__ P,
                                               float* __restrict__ S) {
  const int b = blockIdx.z, ch = blockIdx.y;
  const int d = blockIdx.x * 16 + (threadIdx.x & 15);
  const int n = threadIdx.x >> 4;
  const float Av = -expf(A_log[d * kN + n]);
  const int l0 = ch * kCS;
  const float* pD = delta + ((size_t)b * kDI + d) * kL + l0;
  const float* pU = uc    + ((size_t)b * kDI + d) * kL + l0;
  const float* pB = dbc   + ((size_t)b * 48 + 16 + n) * kL + l0;
  float Pv = 1.f, Sv = 0.f;
  for (int i = 0; i < kCS; i += 4) {
    float4 dv = *(const float4*)(pD + i);
    float4 uv = *(const float4*)(pU + i);
    float4 Bv = *(const float4*)(pB + i);
    float a;
    a = expf(dv.x * Av); Pv *= a; Sv = Sv * a + dv.x * Bv.x * uv.x;
    a = expf(dv.y * Av); Pv *= a; Sv = Sv * a + dv.y * Bv.y * uv.y;
    a = expf(dv.z * Av); Pv *= a; Sv = Sv * a + dv.z * Bv.z * uv.z;
    a = expf(dv.w * Av); Pv *= a; Sv = Sv * a + dv.w * Bv.w * uv.w;
  }
  size_t o = (((size_t)b * kDI + d) * kN + n) * kNC + ch;
  P[o] = Pv;
  S[o] = Sv;
}

// ---------------------------------------------------------------------------
// Scan phase B: serial combine over chunks -> per-chunk initial states.
// ---------------------------------------------------------------------------
__global__ __launch_bounds__(256) void k_scanB(const float* __restrict__ P,
                                               const float* __restrict__ S,
                                               float* __restrict__ init) {
  int idx = blockIdx.x * 256 + threadIdx.x;  // over B*DI*N = 32768
  const float* Pr = P + (size_t)idx * kNC;
  const float* Sr = S + (size_t)idx * kNC;
  float* Ir = init + (size_t)idx * kNC;
  float carry = 0.f;
  for (int c = 0; c < kNC; ++c) {
    Ir[c] = carry;
    carry = Pr[c] * carry + Sr[c];
  }
}

// ---------------------------------------------------------------------------
// Scan phase C: replay chunks; y[b,d,l] = sum_n s*C via shfl over n (low bits).
// ---------------------------------------------------------------------------
__global__ __launch_bounds__(256) void k_scanC(const float* __restrict__ delta,
                                               const float* __restrict__ uc,
                                               const float* __restrict__ dbc,
                                               const float* __restrict__ A_log,
                                               const float* __restrict__ init,
                                               float* __restrict__ y) {
  const int b = blockIdx.z, ch = blockIdx.y;
  const int n = threadIdx.x & 15;
  const int d = blockIdx.x * 16 + (threadIdx.x >> 4);
  const float Av = -expf(A_log[d * kN + n]);
  const int l0 = ch * kCS;
  const float* pD = delta + ((size_t)b * kDI + d) * kL + l0;
  const float* pU = uc    + ((size_t)b * kDI + d) * kL + l0;
  const float* pB = dbc   + ((size_t)b * 48 + 16 + n) * kL + l0;
  const float* pC = dbc   + ((size_t)b * 48 + 32 + n) * kL + l0;
  float* pY = y + ((size_t)b * kDI + d) * kL + l0;
  float s = init[(((size_t)b * kDI + d) * kN + n) * kNC + ch];
  for (int i = 0; i < kCS; i += 4) {
    float4 dv = *(const float4*)(pD + i);
    float4 uv = *(const float4*)(pU + i);
    float4 Bv = *(const float4*)(pB + i);
    float4 Cv = *(const float4*)(pC + i);
    float yv[4];
#pragma unroll
    for (int j = 0; j < 4; ++j) {
      float dd = (j == 0) ? dv.x : (j == 1) ? dv.y : (j == 2) ? dv.z : dv.w;
      float uu = (j == 0) ? uv.x : (j == 1) ? uv.y : (j == 2) ? uv.z : uv.w;
      float bb = (j == 0) ? Bv.x : (j == 1) ? Bv.y : (j == 2) ? Bv.z : Bv.w;
      float cc = (j == 0) ? Cv.x : (j == 1) ? Cv.y : (j == 2) ? Cv.z : Cv.w;
      float a = expf(dd * Av);
      s = s * a + dd * bb * uu;
      float p = s * cc;
      p += __shfl_xor(p, 1);
      p += __shfl_xor(p, 2);
      p += __shfl_xor(p, 4);
      p += __shfl_xor(p, 8);
      yv[j] = p;
    }
    if (n == 0) *(float4*)(pY + i) = make_float4(yv[0], yv[1], yv[2], yv[3]);
  }
}

// ---------------------------------------------------------------------------
// Gate + transpose-convert: yt[b,l,d] bf16 = (y + uc*D[d]) * silu(res) [d,l].
// ---------------------------------------------------------------------------
__global__ __launch_bounds__(256) void k_gate_t(const float* __restrict__ y,
                                                const float* __restrict__ uc,
                                                const unsigned short* __restrict__ resb,
                                                const float* __restrict__ Dp,
                                                unsigned short* __restrict__ yt) {
  __shared__ float Gs[64][65];
  const int b = blockIdx.z, d0 = blockIdx.y * 64, l0 = blockIdx.x * 64;
  const int t = threadIdx.x, l = t & 63;
#pragma unroll
  for (int rep = 0; rep < 16; ++rep) {
    int dd = rep * 4 + (t >> 6);
    size_t off = ((size_t)b * kDI + d0 + dd) * kL + l0 + l;
    float r = bf2f(resb[off]);
    Gs[dd][l] = (y[off] + uc[off] * Dp[d0 + dd]) * siluf(r);
  }
  __syncthreads();
#pragma unroll
  for (int rep = 0; rep < 8; ++rep) {
    int lj = rep * 8 + (t >> 5);
    int di = (t & 31) * 2;
    ushort2 v;
    v.x = f2bf(Gs[di][lj]);
    v.y = f2bf(Gs[di + 1][lj]);
    *(ushort2*)(yt + ((size_t)b * kL + l0 + lj) * kDI + d0 + di) = v;
  }
}

// ---------------------------------------------------------------------------
extern "C" void kernel_launch(void* const* d_in, const int* in_sizes, int n_in,
                              void* d_out, int out_size, void* d_ws, size_t ws_size,
                              hipStream_t stream) {
  const float* x       = (const float*)d_in[0];
  const float* in_w    = (const float*)d_in[1];
  const float* conv_w  = (const float*)d_in[2];
  const float* conv_b  = (const float*)d_in[3];
  const float* xproj_w = (const float*)d_in[4];
  const float* dt_w    = (const float*)d_in[5];
  const float* dt_b    = (const float*)d_in[6];
  const float* A_log   = (const float*)d_in[7];
  const float* Dp      = (const float*)d_in[8];
  const float* out_w   = (const float*)d_in[9];
  float* out = (float*)d_out;

  // workspace layout (~142 MB, fits proven >=150 MB allocation)
  float* ws = (float*)d_ws;
  const size_t nBLD = (size_t)kB * kDI * kL;       // 8388608
  float* u     = ws;                                // in_proj out (d<512); reused as delta
  float* uc    = u + nBLD;
  float* yb    = uc + nBLD;
  float* dbc   = yb + nBLD;                         // B*48*L = 786432
  float* xtf   = dbc + (size_t)kB * 48 * kL;        // xt region: 2097152 floats
  float* Pb    = xtf + 2097152;                     // 1048576
  float* Sb    = Pb + 1048576;                      // 1048576
  float* initb = Sb + 1048576;                      // 1048576
  unsigned short* resb = (unsigned short*)(initb + 1048576);  // bf16 res, 8388608 us
  unsigned short* wib  = resb + nBLD;               // 262144 us
  unsigned short* wob  = wib + 262144;              // 131072 us
  unsigned short* xt   = (unsigned short*)xtf;      // [b,l,256] bf16
  unsigned short* yt   = (unsigned short*)xtf;      // overlay xt+P+S (dead by gate time)
  float* deltab = u;                                // u dead after conv

  k_wcvt<<<dim3(1536), 256, 0, stream>>>(in_w, out_w, wib, wob);
  k_xt<<<dim3(kL / 64, kDim / 64, kB), 256, 0, stream>>>(x, xt);
  gemm_bt<256, true><<<dim3(kL / 128, 8, kB), 256, 0, stream>>>(wib, xt, u, resb, kL, kDI);
  k_conv<<<dim3((unsigned)(nBLD / 1024)), 256, 0, stream>>>(u, conv_w, conv_b, uc);
  k_xproj<<<dim3(kL / 64, kB), 512, 0, stream>>>(uc, xproj_w, dbc);
  k_dtproj<<<dim3((unsigned)(nBLD / 1024)), 256, 0, stream>>>(dbc, dt_w, dt_b, deltab);
  k_scanA<<<dim3(kDI / 16, kNC, kB), 256, 0, stream>>>(deltab, uc, dbc, A_log, Pb, Sb);
  k_scanB<<<dim3(kB * kDI * kN / 256), 256, 0, stream>>>(Pb, Sb, initb);
  k_scanC<<<dim3(kDI / 16, kNC, kB), 256, 0, stream>>>(deltab, uc, dbc, A_log, initb, yb);
  k_gate_t<<<dim3(kL / 64, kDI / 64, kB), 256, 0, stream>>>(yb, uc, resb, Dp, yt);
  gemm_bt<512, false><<<dim3(kL / 128, 2, kB), 256, 0, stream>>>(wob, yt, out, nullptr, kL, kDim);
}

// Round 3
// 315.786 us; speedup vs baseline: 2.1318x; 1.5248x over previous
//
#include <hip/hip_runtime.h>
#include <math.h>

// Mamba block forward, channel-major intermediates [b, d, l].
// B=4, DIM=256, L=4096, D_INNER=512, D_STATE=16, DT_RANK=16, D_CONV=4.
// in_proj/out_proj: bf16 MFMA GEMM. Scan: thread-per-d, 16 n-states in regs.

namespace {
constexpr int kB   = 4;
constexpr int kDim = 256;
constexpr int kL   = 4096;
constexpr int kDI  = 512;
constexpr int kN   = 16;
constexpr int kNC  = 64;   // scan chunks
constexpr int kCS  = 64;   // chunk size
} // namespace

typedef __attribute__((ext_vector_type(8))) short bf16x8;
typedef __attribute__((ext_vector_type(4))) float f32x4;

__device__ __forceinline__ float siluf(float x) { return x / (1.f + __expf(-x)); }

__device__ __forceinline__ unsigned short f2bf(float x) {
  union { float f; unsigned int u; } v; v.f = x;
  unsigned int u = v.u;
  u += 0x7fffu + ((u >> 16) & 1u);   // RNE
  return (unsigned short)(u >> 16);
}
__device__ __forceinline__ float bf2f(unsigned short u) {
  union { unsigned int i; float f; } v; v.i = ((unsigned int)u) << 16; return v.f;
}

__device__ __forceinline__ void gload_lds16(const void* g, void* l) {
  __builtin_amdgcn_global_load_lds(
      (const __attribute__((address_space(1))) unsigned int*)g,
      (__attribute__((address_space(3))) unsigned int*)l, 16, 0, 0);
}

// ---------------------------------------------------------------------------
// Convert weights to bf16: in_proj_w [1024,256], out_proj_w [256,512].
// ---------------------------------------------------------------------------
__global__ __launch_bounds__(256) void k_wcvt(const float* __restrict__ w_in,
                                              const float* __restrict__ w_out,
                                              unsigned short* __restrict__ wib,
                                              unsigned short* __restrict__ wob) {
  int idx = blockIdx.x * 256 + threadIdx.x;
  if (idx < 262144) wib[idx] = f2bf(w_in[idx]);
  else              wob[idx - 262144] = f2bf(w_out[idx - 262144]);
}

// ---------------------------------------------------------------------------
// Transpose-convert x [b, d, l] f32 -> xt [b, l, d] bf16 (B^T for in_proj).
// ---------------------------------------------------------------------------
__global__ __launch_bounds__(256) void k_xt(const float* __restrict__ x,
                                            unsigned short* __restrict__ xt) {
  __shared__ float Xs[64][65];
  const int b = blockIdx.z, d0 = blockIdx.y * 64, l0 = blockIdx.x * 64;
  const int t = threadIdx.x, l = t & 63;
#pragma unroll
  for (int rep = 0; rep < 16; ++rep) {
    int dd = rep * 4 + (t >> 6);
    Xs[dd][l] = x[((size_t)b * kDim + d0 + dd) * kL + l0 + l];
  }
  __syncthreads();
#pragma unroll
  for (int rep = 0; rep < 8; ++rep) {
    int lj = rep * 8 + (t >> 5);
    int di = (t & 31) * 2;
    ushort2 v;
    v.x = f2bf(Xs[di][lj]);
    v.y = f2bf(Xs[di + 1][lj]);
    *(ushort2*)(xt + ((size_t)b * kL + l0 + lj) * kDim + d0 + di) = v;
  }
}

// ---------------------------------------------------------------------------
// bf16 MFMA GEMM: C[b][m][n] = sum_k A[m,k] * Bt[b][n,k].
// Tile 128x128, BK=64, 2x2 waves, swizzled LDS via pre-swizzled global src.
// SPLIT: rows m<512 -> C0 (f32 [b,512,N]); m>=512 -> C1res (bf16 [b,512,N]).
// ---------------------------------------------------------------------------
template <int K, bool SPLIT>
__global__ __launch_bounds__(256) void gemm_bt(const unsigned short* __restrict__ A,
                                               const unsigned short* __restrict__ Bt,
                                               float* __restrict__ C0,
                                               unsigned short* __restrict__ C1res,
                                               int N, int Mout) {
  __shared__ __align__(16) unsigned short As[128 * 64];
  __shared__ __align__(16) unsigned short Bs[128 * 64];
  const int n0 = blockIdx.x * 128;
  const int m0 = blockIdx.y * 128;
  const int b  = blockIdx.z;
  const int t  = threadIdx.x;
  const int wave = t >> 6, lane = t & 63;
  const int wm = wave >> 1, wn = wave & 1;
  const unsigned short* Bb = Bt + (size_t)b * N * K;

  f32x4 acc[4][4];
#pragma unroll
  for (int i = 0; i < 4; ++i)
#pragma unroll
    for (int j = 0; j < 4; ++j) acc[i][j] = (f32x4)0.0f;

  const int srow = t >> 3;   // 0..31 (per staging call)
  const int sch  = t & 7;    // 16B chunk within 128B row

  for (int kt = 0; kt < K / 64; ++kt) {
    const int k0 = kt * 64;
#pragma unroll
    for (int c = 0; c < 4; ++c) {
      int row = c * 32 + srow;
      int gch = sch ^ (row & 7);   // inverse-swizzled global source
      const unsigned short* ga = A  + (size_t)(m0 + row) * K + k0 + gch * 8;
      const unsigned short* gb = Bb + (size_t)(n0 + row) * K + k0 + gch * 8;
      char* la = (char*)As + c * 4096 + wave * 1024;
      char* lb = (char*)Bs + c * 4096 + wave * 1024;
      gload_lds16(ga, la);
      gload_lds16(gb, lb);
    }
    __syncthreads();
#pragma unroll
    for (int ks = 0; ks < 2; ++ks) {
      bf16x8 af[4], bfr[4];
#pragma unroll
      for (int f = 0; f < 4; ++f) {
        int ra = wm * 64 + f * 16 + (lane & 15);
        int ca = (ks * 4 + (lane >> 4)) ^ (ra & 7);
        af[f] = *(const bf16x8*)((const char*)As + ra * 128 + ca * 16);
        int rb = wn * 64 + f * 16 + (lane & 15);
        int cb = (ks * 4 + (lane >> 4)) ^ (rb & 7);
        bfr[f] = *(const bf16x8*)((const char*)Bs + rb * 128 + cb * 16);
      }
#pragma unroll
      for (int i = 0; i < 4; ++i)
#pragma unroll
        for (int j = 0; j < 4; ++j)
          acc[i][j] = __builtin_amdgcn_mfma_f32_16x16x32_bf16(af[i], bfr[j], acc[i][j], 0, 0, 0);
    }
    __syncthreads();
  }

  const int mbase = m0 + wm * 64;
  const int nbase = n0 + wn * 64;
  bool to_res = SPLIT && (m0 >= 512);
  int moff = to_res ? (mbase - 512) : mbase;
#pragma unroll
  for (int i = 0; i < 4; ++i)
#pragma unroll
    for (int j = 0; j < 4; ++j)
#pragma unroll
      for (int r = 0; r < 4; ++r) {
        int m = moff + i * 16 + (lane >> 4) * 4 + r;
        int n = nbase + j * 16 + (lane & 15);
        size_t off = ((size_t)b * Mout + m) * N + n;
        if (to_res) C1res[off] = f2bf(acc[i][j][r]);
        else        C0[off] = acc[i][j][r];
      }
}

// ---------------------------------------------------------------------------
// Causal depthwise conv k=4 + bias + SiLU over l, channel-major. float4.
// ---------------------------------------------------------------------------
__global__ __launch_bounds__(256) void k_conv(const float* __restrict__ u,
                                              const float* __restrict__ cw,
                                              const float* __restrict__ cb,
                                              float* __restrict__ uc) {
  int idx = blockIdx.x * 256 + threadIdx.x;   // over B*DI*(L/4)
  int l4 = (idx & (kL / 4 - 1)) * 4;
  int bd = idx >> 10;
  int d  = bd & (kDI - 1);
  const float* row = u + (size_t)bd * kL;
  float4 cur = *(const float4*)(row + l4);
  float4 prev = make_float4(0.f, 0.f, 0.f, 0.f);
  if (l4 > 0) prev = *(const float4*)(row + l4 - 4);
  float4 w = *(const float4*)(cw + d * 4);
  float bias = cb[d];
  float o0 = bias + w.x * prev.y + w.y * prev.z + w.z * prev.w + w.w * cur.x;
  float o1 = bias + w.x * prev.z + w.y * prev.w + w.z * cur.x + w.w * cur.y;
  float o2 = bias + w.x * prev.w + w.y * cur.x + w.z * cur.y + w.w * cur.z;
  float o3 = bias + w.x * cur.x  + w.y * cur.y + w.z * cur.z + w.w * cur.w;
  float4 o = make_float4(siluf(o0), siluf(o1), siluf(o2), siluf(o3));
  *(float4*)(uc + (size_t)bd * kL + l4) = o;
}

// ---------------------------------------------------------------------------
// x_proj: dbc[b, e', l] = sum_d uc[b,d,l] * Wx[e',d], e' in [0,48). VALU.
// ---------------------------------------------------------------------------
__global__ __launch_bounds__(512) void k_xproj(const float* __restrict__ uc,
                                               const float* __restrict__ W,
                                               float* __restrict__ dbc) {
  __shared__ float Us[64][65];
  const int b = blockIdx.y, l0 = blockIdx.x * 64;
  const int t = threadIdx.x, l = t & 63, eg = t >> 6;   // eg 0..7
  float acc[6] = {};
  for (int d0 = 0; d0 < kDI; d0 += 64) {
#pragma unroll
    for (int rep = 0; rep < 8; ++rep) {
      int dd = rep * 8 + eg;
      Us[dd][l] = uc[((size_t)b * kDI + d0 + dd) * kL + l0 + l];
    }
    __syncthreads();
#pragma unroll 8
    for (int dd = 0; dd < 64; ++dd) {
      float v = Us[dd][l];
#pragma unroll
      for (int j = 0; j < 6; ++j)
        acc[j] += v * W[(size_t)(eg * 6 + j) * kDI + d0 + dd];
    }
    __syncthreads();
  }
#pragma unroll
  for (int j = 0; j < 6; ++j)
    dbc[((size_t)b * 48 + eg * 6 + j) * kL + l0 + l] = acc[j];
}

// ---------------------------------------------------------------------------
// dt_proj + softplus: delta[b,d,l] = softplus(sum_r dbc[b,r,l]*Wdt[d,r]+bdt[d])
// ---------------------------------------------------------------------------
__global__ __launch_bounds__(256) void k_dtproj(const float* __restrict__ dbc,
                                                const float* __restrict__ Wdt,
                                                const float* __restrict__ bdt,
                                                float* __restrict__ delta) {
  int idx = blockIdx.x * 256 + threadIdx.x;   // over B*DI*(L/4)
  int l4 = (idx & (kL / 4 - 1)) * 4;
  int bd = idx >> 10;
  int b = bd >> 9, d = bd & (kDI - 1);
  const float* base = dbc + (size_t)b * 48 * kL + l4;
  float bias = bdt[d];
  float4 acc = make_float4(bias, bias, bias, bias);
#pragma unroll
  for (int r = 0; r < 16; ++r) {
    float w = Wdt[d * 16 + r];
    float4 v = *(const float4*)(base + (size_t)r * kL);
    acc.x += w * v.x; acc.y += w * v.y; acc.z += w * v.z; acc.w += w * v.w;
  }
  float4 o;
  o.x = fmaxf(acc.x, 0.f) + log1pf(expf(-fabsf(acc.x)));
  o.y = fmaxf(acc.y, 0.f) + log1pf(expf(-fabsf(acc.y)));
  o.z = fmaxf(acc.z, 0.f) + log1pf(expf(-fabsf(acc.z)));
  o.w = fmaxf(acc.w, 0.f) + log1pf(expf(-fabsf(acc.w)));
  *(float4*)(delta + (size_t)bd * kL + l4) = o;
}

// ---------------------------------------------------------------------------
// Scan phase A: thread owns d, all 16 n-states in regs. Per (b,ch):
// P[n] = prod_l exp(delta*A[n]), S[n] = sum_l (delta*B*u) * suffix-prod.
// B rows staged in LDS (broadcast reads).
// ---------------------------------------------------------------------------
__global__ __launch_bounds__(256) void k_scanA(const float* __restrict__ delta,
                                               const float* __restrict__ uc,
                                               const float* __restrict__ dbc,
                                               const float* __restrict__ A_log,
                                               float* __restrict__ P,
                                               float* __restrict__ S) {
  __shared__ float Bs[16][kCS];
  const int b = blockIdx.z, ch = blockIdx.y;
  const int t = threadIdx.x;
  const int d = blockIdx.x * 256 + t;
  const int l0 = ch * kCS;
  {
    int lane = t & 63, w = t >> 6;
#pragma unroll
    for (int r = 0; r < 4; ++r) {
      int row = r * 4 + w;
      Bs[row][lane] = dbc[((size_t)b * 48 + 16 + row) * kL + l0 + lane];
    }
  }
  __syncthreads();
  float Av[16];
#pragma unroll
  for (int n = 0; n < kN; ++n) Av[n] = -__expf(A_log[d * kN + n]);
  float Pv[16], Sv[16];
#pragma unroll
  for (int n = 0; n < kN; ++n) { Pv[n] = 1.f; Sv[n] = 0.f; }
  const float* pD = delta + ((size_t)b * kDI + d) * kL + l0;
  const float* pU = uc    + ((size_t)b * kDI + d) * kL + l0;
  for (int i = 0; i < kCS; i += 4) {
    float4 dv = *(const float4*)(pD + i);
    float4 uv = *(const float4*)(pU + i);
    float4 du = make_float4(dv.x * uv.x, dv.y * uv.y, dv.z * uv.z, dv.w * uv.w);
#pragma unroll
    for (int n = 0; n < kN; ++n) {
      float4 B4 = *(const float4*)&Bs[n][i];
      float a;
      a = __expf(dv.x * Av[n]); Pv[n] *= a; Sv[n] = Sv[n] * a + du.x * B4.x;
      a = __expf(dv.y * Av[n]); Pv[n] *= a; Sv[n] = Sv[n] * a + du.y * B4.y;
      a = __expf(dv.z * Av[n]); Pv[n] *= a; Sv[n] = Sv[n] * a + du.z * B4.z;
      a = __expf(dv.w * Av[n]); Pv[n] *= a; Sv[n] = Sv[n] * a + du.w * B4.w;
    }
  }
  size_t base = (size_t)(b * kNC + ch) * kN * kDI + d;
#pragma unroll
  for (int n = 0; n < kN; ++n) {
    P[base + (size_t)n * kDI] = Pv[n];
    S[base + (size_t)n * kDI] = Sv[n];
  }
}

// ---------------------------------------------------------------------------
// Scan phase B: serial combine over chunks -> per-chunk initial states.
// Layout [b][ch][n][d], coalesced over d.
// ---------------------------------------------------------------------------
__global__ __launch_bounds__(256) void k_scanB(const float* __restrict__ P,
                                               const float* __restrict__ S,
                                               float* __restrict__ init) {
  int idx = blockIdx.x * 256 + threadIdx.x;  // b*8192 + n*512 + d
  int b = idx >> 13, nd = idx & 8191;
  float carry = 0.f;
  for (int c = 0; c < kNC; ++c) {
    size_t o = (size_t)(b * kNC + c) * 8192 + nd;
    init[o] = carry;
    carry = P[o] * carry + S[o];
  }
}

// ---------------------------------------------------------------------------
// Scan phase C + fused gate: replay chunk from init; y_d(l) = sum_n s_n C_n;
// g = (y + u*D) * silu(res); LDS-transpose -> yt[b,l,d] bf16.
// ---------------------------------------------------------------------------
__global__ __launch_bounds__(256) void k_scanC(const float* __restrict__ delta,
                                               const float* __restrict__ uc,
                                               const float* __restrict__ dbc,
                                               const float* __restrict__ A_log,
                                               const float* __restrict__ init,
                                               const unsigned short* __restrict__ resb,
                                               const float* __restrict__ Dp,
                                               unsigned short* __restrict__ yt) {
  __shared__ float BCs[32][kCS];
  __shared__ unsigned short ytile[64][264];   // [l][d_local], padded (16B-aligned rows)
  const int b = blockIdx.z, ch = blockIdx.y;
  const int t = threadIdx.x;
  const int dh = blockIdx.x;
  const int d = dh * 256 + t;
  const int l0 = ch * kCS;
  {
    int lane = t & 63, w = t >> 6;
#pragma unroll
    for (int r = 0; r < 8; ++r) {
      int row = r * 4 + w;
      BCs[row][lane] = dbc[((size_t)b * 48 + 16 + row) * kL + l0 + lane];
    }
  }
  __syncthreads();
  float Av[16];
#pragma unroll
  for (int n = 0; n < kN; ++n) Av[n] = -__expf(A_log[d * kN + n]);
  float s[16];
  {
    size_t base = (size_t)(b * kNC + ch) * kN * kDI + d;
#pragma unroll
    for (int n = 0; n < kN; ++n) s[n] = init[base + (size_t)n * kDI];
  }
  const float Dv = Dp[d];
  const float* pD = delta + ((size_t)b * kDI + d) * kL + l0;
  const float* pU = uc    + ((size_t)b * kDI + d) * kL + l0;
  const unsigned short* pR = resb + ((size_t)b * kDI + d) * kL + l0;

  for (int i = 0; i < kCS; i += 4) {
    float4 dv = *(const float4*)(pD + i);
    float4 uv = *(const float4*)(pU + i);
    float4 du = make_float4(dv.x * uv.x, dv.y * uv.y, dv.z * uv.z, dv.w * uv.w);
    float4 yacc = make_float4(0.f, 0.f, 0.f, 0.f);
#pragma unroll
    for (int n = 0; n < kN; ++n) {
      float4 B4 = *(const float4*)&BCs[n][i];
      float4 C4 = *(const float4*)&BCs[16 + n][i];
      float a;
      a = __expf(dv.x * Av[n]); s[n] = s[n] * a + du.x * B4.x; yacc.x += s[n] * C4.x;
      a = __expf(dv.y * Av[n]); s[n] = s[n] * a + du.y * B4.y; yacc.y += s[n] * C4.y;
      a = __expf(dv.z * Av[n]); s[n] = s[n] * a + du.z * B4.z; yacc.z += s[n] * C4.z;
      a = __expf(dv.w * Av[n]); s[n] = s[n] * a + du.w * B4.w; yacc.w += s[n] * C4.w;
    }
    // fused gate: g = (y + u*D) * silu(res)
    ushort4 rv = *(const ushort4*)(pR + i);
    float g0 = (yacc.x + uv.x * Dv) * siluf(bf2f(rv.x));
    float g1 = (yacc.y + uv.y * Dv) * siluf(bf2f(rv.y));
    float g2 = (yacc.z + uv.z * Dv) * siluf(bf2f(rv.z));
    float g3 = (yacc.w + uv.w * Dv) * siluf(bf2f(rv.w));
    ytile[i + 0][t] = f2bf(g0);
    ytile[i + 1][t] = f2bf(g1);
    ytile[i + 2][t] = f2bf(g2);
    ytile[i + 3][t] = f2bf(g3);
  }
  __syncthreads();
  // cooperative transposed write-out: yt[b, l0+row, dh*256 + col]
#pragma unroll
  for (int rep = 0; rep < 8; ++rep) {
    int row = rep * 8 + (t >> 5);
    int c8 = (t & 31) * 8;
    uint4 v = *(const uint4*)&ytile[row][c8];
    *(uint4*)(yt + ((size_t)b * kL + l0 + row) * kDI + dh * 256 + c8) = v;
  }
}

// ---------------------------------------------------------------------------
extern "C" void kernel_launch(void* const* d_in, const int* in_sizes, int n_in,
                              void* d_out, int out_size, void* d_ws, size_t ws_size,
                              hipStream_t stream) {
  const float* x       = (const float*)d_in[0];
  const float* in_w    = (const float*)d_in[1];
  const float* conv_w  = (const float*)d_in[2];
  const float* conv_b  = (const float*)d_in[3];
  const float* xproj_w = (const float*)d_in[4];
  const float* dt_w    = (const float*)d_in[5];
  const float* dt_b    = (const float*)d_in[6];
  const float* A_log   = (const float*)d_in[7];
  const float* Dp      = (const float*)d_in[8];
  const float* out_w   = (const float*)d_in[9];
  float* out = (float*)d_out;

  // workspace layout (~113 MB)
  float* ws = (float*)d_ws;
  const size_t nBLD = (size_t)kB * kDI * kL;        // 8388608
  float* u    = ws;                                  // in_proj u; reused as delta
  float* uc   = u + nBLD;
  float* dbc  = uc + nBLD;                           // B*48*L = 786432
  float* reg1 = dbc + (size_t)kB * 48 * kL;          // 2097152: xt | init
  float* reg2 = reg1 + 2097152;                      // 4194304: P,S | yt
  float* resf = reg2 + 4194304;                      // 4194304 f-equiv (bf16 res)
  unsigned short* resb = (unsigned short*)resf;
  unsigned short* wib  = (unsigned short*)(resf + 4194304);  // 262144 us
  unsigned short* wob  = wib + 262144;                       // 131072 us
  unsigned short* xt   = (unsigned short*)reg1;      // [b,l,256] bf16 (dead after gemm_in)
  float* initb = reg1;                               // overlays xt (written after)
  float* Pb    = reg2;                               // dead after scanB
  float* Sb    = reg2 + 2097152;
  unsigned short* yt = (unsigned short*)reg2;        // overlays P,S (written by scanC)
  float* deltab = u;                                 // u dead after conv

  k_wcvt<<<dim3(1536), 256, 0, stream>>>(in_w, out_w, wib, wob);
  k_xt<<<dim3(kL / 64, kDim / 64, kB), 256, 0, stream>>>(x, xt);
  gemm_bt<256, true><<<dim3(kL / 128, 8, kB), 256, 0, stream>>>(wib, xt, u, resb, kL, kDI);
  k_conv<<<dim3((unsigned)(nBLD / 1024)), 256, 0, stream>>>(u, conv_w, conv_b, uc);
  k_xproj<<<dim3(kL / 64, kB), 512, 0, stream>>>(uc, xproj_w, dbc);
  k_dtproj<<<dim3((unsigned)(nBLD / 1024)), 256, 0, stream>>>(dbc, dt_w, dt_b, deltab);
  k_scanA<<<dim3(2, kNC, kB), 256, 0, stream>>>(deltab, uc, dbc, A_log, Pb, Sb);
  k_scanB<<<dim3(kB * kDI * kN / 256), 256, 0, stream>>>(Pb, Sb, initb);
  k_scanC<<<dim3(2, kNC, kB), 256, 0, stream>>>(deltab, uc, dbc, A_log, initb, resb, Dp, yt);
  gemm_bt<512, false><<<dim3(kL / 128, 2, kB), 256, 0, stream>>>(wob, yt, out, nullptr, kL, kDim);
}

// Round 4
// 233.481 us; speedup vs baseline: 2.8833x; 1.3525x over previous
//
#include <hip/hip_runtime.h>
#include <math.h>

// Mamba block forward, l-major activations [b, l, d].
// B=4, DIM=256, L=4096, D_INNER=512, D_STATE=16, DT_RANK=16, D_CONV=4.
// in/out_proj + x_proj: bf16 MFMA. Scan: thread-per-d, 16 n-states in regs,
// dt_proj+softplus fused into scan phases, gate fused into scanC.

namespace {
constexpr int kB   = 4;
constexpr int kDim = 256;
constexpr int kL   = 4096;
constexpr int kDI  = 512;
constexpr int kN   = 16;
constexpr int kNC  = 64;   // scan chunks
constexpr int kCS  = 64;   // chunk size
} // namespace

typedef __attribute__((ext_vector_type(8))) short bf16x8;
typedef __attribute__((ext_vector_type(4))) float f32x4;

__device__ __forceinline__ float siluf(float x) { return x / (1.f + __expf(-x)); }

__device__ __forceinline__ unsigned short f2bf(float x) {
  union { float f; unsigned int u; } v; v.f = x;
  unsigned int u = v.u;
  u += 0x7fffu + ((u >> 16) & 1u);   // RNE
  return (unsigned short)(u >> 16);
}
__device__ __forceinline__ float bf2f(unsigned short u) {
  union { unsigned int i; float f; } v; v.i = ((unsigned int)u) << 16; return v.f;
}

__device__ __forceinline__ void gload_lds16(const void* g, void* l) {
  __builtin_amdgcn_global_load_lds(
      (const __attribute__((address_space(1))) unsigned int*)g,
      (__attribute__((address_space(3))) unsigned int*)l, 16, 0, 0);
}

// ---------------------------------------------------------------------------
// Convert weights to bf16: in_proj [1024,256], out_proj [256,512], x_proj [48,512].
// ---------------------------------------------------------------------------
__global__ __launch_bounds__(256) void k_wcvt(const float* __restrict__ w_in,
                                              const float* __restrict__ w_out,
                                              const float* __restrict__ w_x,
                                              unsigned short* __restrict__ wib,
                                              unsigned short* __restrict__ wob,
                                              unsigned short* __restrict__ wxb) {
  int idx = blockIdx.x * 256 + threadIdx.x;
  if (idx < 262144) wib[idx] = f2bf(w_in[idx]);
  else if (idx < 262144 + 131072) wob[idx - 262144] = f2bf(w_out[idx - 262144]);
  else if (idx < 262144 + 131072 + 24576) wxb[idx - 393216] = f2bf(w_x[idx - 393216]);
}

// ---------------------------------------------------------------------------
// Transpose-convert x [b, d, l] f32 -> xt [b, l, d] bf16.
// ---------------------------------------------------------------------------
__global__ __launch_bounds__(256) void k_xt(const float* __restrict__ x,
                                            unsigned short* __restrict__ xt) {
  __shared__ float Xs[64][65];
  const int b = blockIdx.z, d0 = blockIdx.y * 64, l0 = blockIdx.x * 64;
  const int t = threadIdx.x, l = t & 63;
#pragma unroll
  for (int rep = 0; rep < 16; ++rep) {
    int dd = rep * 4 + (t >> 6);
    Xs[dd][l] = x[((size_t)b * kDim + d0 + dd) * kL + l0 + l];
  }
  __syncthreads();
#pragma unroll
  for (int rep = 0; rep < 8; ++rep) {
    int lj = rep * 8 + (t >> 5);
    int di = (t & 31) * 2;
    ushort2 v;
    v.x = f2bf(Xs[di][lj]);
    v.y = f2bf(Xs[di + 1][lj]);
    *(ushort2*)(xt + ((size_t)b * kL + l0 + lj) * kDim + d0 + di) = v;
  }
}

// ---------------------------------------------------------------------------
// in_proj GEMM, l-major output: C[b][l][e] = sum_k xt[b,l,k] * W[e,k].
// Tile 128(l) x 128(e), BK=64, 2x2 waves. e0<512 -> u f32; e0>=512 -> res bf16.
// ---------------------------------------------------------------------------
__global__ __launch_bounds__(256) void gemm_in_lm(const unsigned short* __restrict__ xt,
                                                  const unsigned short* __restrict__ W,
                                                  float* __restrict__ u,
                                                  unsigned short* __restrict__ res) {
  __shared__ __align__(16) unsigned short As[128 * 64];  // xt rows (l)
  __shared__ __align__(16) unsigned short Bs[128 * 64];  // W rows (e)
  const int e0 = blockIdx.x * 128;
  const int l0 = blockIdx.y * 128;
  const int b  = blockIdx.z;
  const int t  = threadIdx.x;
  const int wave = t >> 6, lane = t & 63;
  const int wm = wave >> 1, wn = wave & 1;
  const unsigned short* Ab = xt + (size_t)b * kL * kDim;

  f32x4 acc[4][4];
#pragma unroll
  for (int i = 0; i < 4; ++i)
#pragma unroll
    for (int j = 0; j < 4; ++j) acc[i][j] = (f32x4)0.0f;

  const int srow = t >> 3, sch = t & 7;
  for (int kt = 0; kt < 4; ++kt) {
    const int k0 = kt * 64;
#pragma unroll
    for (int c = 0; c < 4; ++c) {
      int row = c * 32 + srow;
      int gch = sch ^ (row & 7);
      const unsigned short* ga = Ab + (size_t)(l0 + row) * kDim + k0 + gch * 8;
      const unsigned short* gb = W  + (size_t)(e0 + row) * kDim + k0 + gch * 8;
      gload_lds16(ga, (char*)As + c * 4096 + wave * 1024);
      gload_lds16(gb, (char*)Bs + c * 4096 + wave * 1024);
    }
    __syncthreads();
#pragma unroll
    for (int ks = 0; ks < 2; ++ks) {
      bf16x8 af[4], bfr[4];
#pragma unroll
      for (int f = 0; f < 4; ++f) {
        int ra = wm * 64 + f * 16 + (lane & 15);
        int ca = (ks * 4 + (lane >> 4)) ^ (ra & 7);
        af[f] = *(const bf16x8*)((const char*)As + ra * 128 + ca * 16);
        int rb = wn * 64 + f * 16 + (lane & 15);
        int cb = (ks * 4 + (lane >> 4)) ^ (rb & 7);
        bfr[f] = *(const bf16x8*)((const char*)Bs + rb * 128 + cb * 16);
      }
#pragma unroll
      for (int i = 0; i < 4; ++i)
#pragma unroll
        for (int j = 0; j < 4; ++j)
          acc[i][j] = __builtin_amdgcn_mfma_f32_16x16x32_bf16(af[i], bfr[j], acc[i][j], 0, 0, 0);
    }
    __syncthreads();
  }

  const bool is_u = (e0 < kDI);
#pragma unroll
  for (int i = 0; i < 4; ++i)
#pragma unroll
    for (int j = 0; j < 4; ++j)
#pragma unroll
      for (int r = 0; r < 4; ++r) {
        int l = l0 + wm * 64 + i * 16 + (lane >> 4) * 4 + r;
        int e = e0 + wn * 64 + j * 16 + (lane & 15);
        if (is_u) u[((size_t)b * kL + l) * kDI + e] = acc[i][j][r];
        else      res[((size_t)b * kL + l) * kDI + (e - kDI)] = f2bf(acc[i][j][r]);
      }
}

// ---------------------------------------------------------------------------
// Causal depthwise conv k=4 + bias + SiLU, l-major. Writes uc f32 + ucb bf16.
// ---------------------------------------------------------------------------
__global__ __launch_bounds__(256) void k_conv(const float* __restrict__ u,
                                              const float* __restrict__ cw,
                                              const float* __restrict__ cb,
                                              float* __restrict__ uc,
                                              unsigned short* __restrict__ ucb) {
  int idx = blockIdx.x * 256 + threadIdx.x;   // over B*L*(DI/4)
  int d4 = idx & 127;
  int l  = (idx >> 7) & (kL - 1);
  int b  = idx >> 19;
  int d  = d4 * 4;
  const float* rowb = u + ((size_t)b * kL + l) * kDI + d;
  float4 r0 = *(const float4*)rowb;                                  // l
  float4 r1 = (l >= 1) ? *(const float4*)(rowb - kDI)     : make_float4(0,0,0,0);
  float4 r2 = (l >= 2) ? *(const float4*)(rowb - 2 * kDI) : make_float4(0,0,0,0);
  float4 r3 = (l >= 3) ? *(const float4*)(rowb - 3 * kDI) : make_float4(0,0,0,0);
  float4 w0 = *(const float4*)(cw + (d + 0) * 4);
  float4 w1 = *(const float4*)(cw + (d + 1) * 4);
  float4 w2 = *(const float4*)(cw + (d + 2) * 4);
  float4 w3 = *(const float4*)(cw + (d + 3) * 4);
  float4 bb = *(const float4*)(cb + d);
  float4 o;
  o.x = siluf(bb.x + w0.x * r3.x + w0.y * r2.x + w0.z * r1.x + w0.w * r0.x);
  o.y = siluf(bb.y + w1.x * r3.y + w1.y * r2.y + w1.z * r1.y + w1.w * r0.y);
  o.z = siluf(bb.z + w2.x * r3.z + w2.y * r2.z + w2.z * r1.z + w2.w * r0.z);
  o.w = siluf(bb.w + w3.x * r3.w + w3.y * r2.w + w3.z * r1.w + w3.w * r0.w);
  size_t off = ((size_t)b * kL + l) * kDI + d;
  *(float4*)(uc + off) = o;
  ushort4 ob;
  ob.x = f2bf(o.x); ob.y = f2bf(o.y); ob.z = f2bf(o.z); ob.w = f2bf(o.w);
  *(ushort4*)(ucb + off) = ob;
}

// ---------------------------------------------------------------------------
// x_proj MFMA: dbc[b][m][l] = sum_k Wx[m,k] * ucb[b,l,k], m in [0,48), K=512.
// Block: M=48, N-tile=128 (4 waves x 32 l), BK=64.
// ---------------------------------------------------------------------------
__global__ __launch_bounds__(256) void k_xproj(const unsigned short* __restrict__ Wx,
                                               const unsigned short* __restrict__ ucb,
                                               float* __restrict__ dbc) {
  __shared__ __align__(16) unsigned short As[64 * 64];    // Wx rows (48 valid)
  __shared__ __align__(16) unsigned short Bs[128 * 64];   // ucb rows (l)
  const int l0 = blockIdx.x * 128;
  const int b  = blockIdx.y;
  const int t  = threadIdx.x;
  const int wave = t >> 6, lane = t & 63;
  const unsigned short* Bb = ucb + (size_t)b * kL * kDI;

  f32x4 acc[3][2];
#pragma unroll
  for (int i = 0; i < 3; ++i)
#pragma unroll
    for (int j = 0; j < 2; ++j) acc[i][j] = (f32x4)0.0f;

  const int srow = t >> 3, sch = t & 7;
  for (int kt = 0; kt < 8; ++kt) {
    const int k0 = kt * 64;
#pragma unroll
    for (int c = 0; c < 2; ++c) {
      int row = c * 32 + srow;
      int grow = row < 48 ? row : 47;
      int gch = sch ^ (row & 7);
      gload_lds16(Wx + (size_t)grow * kDI + k0 + gch * 8,
                  (char*)As + c * 4096 + wave * 1024);
    }
#pragma unroll
    for (int c = 0; c < 4; ++c) {
      int row = c * 32 + srow;
      int gch = sch ^ (row & 7);
      gload_lds16(Bb + (size_t)(l0 + row) * kDI + k0 + gch * 8,
                  (char*)Bs + c * 4096 + wave * 1024);
    }
    __syncthreads();
#pragma unroll
    for (int ks = 0; ks < 2; ++ks) {
      bf16x8 af[3], bfr[2];
#pragma unroll
      for (int f = 0; f < 3; ++f) {
        int ra = f * 16 + (lane & 15);
        int ca = (ks * 4 + (lane >> 4)) ^ (ra & 7);
        af[f] = *(const bf16x8*)((const char*)As + ra * 128 + ca * 16);
      }
#pragma unroll
      for (int f = 0; f < 2; ++f) {
        int rb = wave * 32 + f * 16 + (lane & 15);
        int cb = (ks * 4 + (lane >> 4)) ^ (rb & 7);
        bfr[f] = *(const bf16x8*)((const char*)Bs + rb * 128 + cb * 16);
      }
#pragma unroll
      for (int i = 0; i < 3; ++i)
#pragma unroll
        for (int j = 0; j < 2; ++j)
          acc[i][j] = __builtin_amdgcn_mfma_f32_16x16x32_bf16(af[i], bfr[j], acc[i][j], 0, 0, 0);
    }
    __syncthreads();
  }
#pragma unroll
  for (int i = 0; i < 3; ++i)
#pragma unroll
    for (int j = 0; j < 2; ++j)
#pragma unroll
      for (int r = 0; r < 4; ++r) {
        int m = i * 16 + (lane >> 4) * 4 + r;
        int l = l0 + wave * 32 + j * 16 + (lane & 15);
        dbc[((size_t)b * 48 + m) * kL + l] = acc[i][j][r];
      }
}

// ---------------------------------------------------------------------------
// Scan phase A (fused dt_proj+softplus): thread owns d, 16 (P,S) pairs in regs.
// ---------------------------------------------------------------------------
__global__ __launch_bounds__(256) void k_scanA(const float* __restrict__ uc,
                                               const float* __restrict__ dbc,
                                               const float* __restrict__ A_log,
                                               const float* __restrict__ Wdt,
                                               const float* __restrict__ bdt,
                                               float* __restrict__ P,
                                               float* __restrict__ S) {
  __shared__ __align__(16) float DtB[32][kCS];   // rows 0-15 dt, 16-31 B
  const int b = blockIdx.z, ch = blockIdx.y;
  const int t = threadIdx.x;
  const int d = blockIdx.x * 256 + t;
  const int l0 = ch * kCS;
  {
    int lane = t & 63, w = t >> 6;
#pragma unroll
    for (int r = 0; r < 8; ++r) {
      int row = r * 4 + w;
      DtB[row][lane] = dbc[((size_t)b * 48 + row) * kL + l0 + lane];
    }
  }
  __syncthreads();
  float Av[16], Wr[16];
#pragma unroll
  for (int q = 0; q < 4; ++q) {
    float4 a4 = *(const float4*)(A_log + d * 16 + q * 4);
    Av[q * 4 + 0] = -__expf(a4.x); Av[q * 4 + 1] = -__expf(a4.y);
    Av[q * 4 + 2] = -__expf(a4.z); Av[q * 4 + 3] = -__expf(a4.w);
    float4 w4 = *(const float4*)(Wdt + d * 16 + q * 4);
    Wr[q * 4 + 0] = w4.x; Wr[q * 4 + 1] = w4.y; Wr[q * 4 + 2] = w4.z; Wr[q * 4 + 3] = w4.w;
  }
  const float bias = bdt[d];
  float Pv[16], Sv[16];
#pragma unroll
  for (int n = 0; n < kN; ++n) { Pv[n] = 1.f; Sv[n] = 0.f; }
  const float* pU = uc + ((size_t)b * kL + l0) * kDI + d;

  for (int i = 0; i < kCS; i += 4) {
    // delta for 4 l's
    float del[4] = {bias, bias, bias, bias};
#pragma unroll
    for (int r = 0; r < 16; ++r) {
      float4 v = *(const float4*)&DtB[r][i];
      del[0] += Wr[r] * v.x; del[1] += Wr[r] * v.y;
      del[2] += Wr[r] * v.z; del[3] += Wr[r] * v.w;
    }
    float du[4];
#pragma unroll
    for (int jj = 0; jj < 4; ++jj) {
      float x = del[jj];
      x = fmaxf(x, 0.f) + log1pf(__expf(-fabsf(x)));   // softplus
      del[jj] = x;
      du[jj] = x * pU[(size_t)(i + jj) * kDI];
    }
#pragma unroll
    for (int n = 0; n < kN; ++n) {
      float4 B4 = *(const float4*)&DtB[16 + n][i];
      float a;
      a = __expf(del[0] * Av[n]); Pv[n] *= a; Sv[n] = Sv[n] * a + du[0] * B4.x;
      a = __expf(del[1] * Av[n]); Pv[n] *= a; Sv[n] = Sv[n] * a + du[1] * B4.y;
      a = __expf(del[2] * Av[n]); Pv[n] *= a; Sv[n] = Sv[n] * a + du[2] * B4.z;
      a = __expf(del[3] * Av[n]); Pv[n] *= a; Sv[n] = Sv[n] * a + du[3] * B4.w;
    }
  }
  size_t base = (size_t)(b * kNC + ch) * (kN * kDI) + d;
#pragma unroll
  for (int n = 0; n < kN; ++n) {
    P[base + (size_t)n * kDI] = Pv[n];
    S[base + (size_t)n * kDI] = Sv[n];
  }
}

// ---------------------------------------------------------------------------
// Scan phase B: combine chunk summaries -> per-chunk init states. 8-deep MLP.
// ---------------------------------------------------------------------------
__global__ __launch_bounds__(256) void k_scanB(const float* __restrict__ P,
                                               const float* __restrict__ S,
                                               float* __restrict__ init) {
  int idx = blockIdx.x * 256 + threadIdx.x;  // b*8192 + n*512 + d
  int b = idx >> 13, nd = idx & 8191;
  size_t base = (size_t)b * kNC * 8192 + nd;
  float carry = 0.f;
  for (int c0 = 0; c0 < kNC; c0 += 8) {
    float p[8], s[8];
#pragma unroll
    for (int j = 0; j < 8; ++j) {
      size_t o = base + (size_t)(c0 + j) * 8192;
      p[j] = P[o]; s[j] = S[o];
    }
#pragma unroll
    for (int j = 0; j < 8; ++j) {
      init[base + (size_t)(c0 + j) * 8192] = carry;
      carry = p[j] * carry + s[j];
    }
  }
}

// ---------------------------------------------------------------------------
// Scan phase C (fused dt_proj + gate): replay chunk, y = sum_n s_n*C_n;
// g = (y + u*D)*silu(res) -> yt[b,l,d] bf16 (direct, coalesced).
// ---------------------------------------------------------------------------
__global__ __launch_bounds__(256) void k_scanC(const float* __restrict__ uc,
                                               const float* __restrict__ dbc,
                                               const float* __restrict__ A_log,
                                               const float* __restrict__ Wdt,
                                               const float* __restrict__ bdt,
                                               const float* __restrict__ init,
                                               const unsigned short* __restrict__ resb,
                                               const float* __restrict__ Dp,
                                               unsigned short* __restrict__ yt) {
  __shared__ __align__(16) float DtBC[48][kCS];  // 0-15 dt, 16-31 B, 32-47 C
  const int b = blockIdx.z, ch = blockIdx.y;
  const int t = threadIdx.x;
  const int d = blockIdx.x * 256 + t;
  const int l0 = ch * kCS;
  {
    int lane = t & 63, w = t >> 6;
#pragma unroll
    for (int r = 0; r < 12; ++r) {
      int row = r * 4 + w;
      DtBC[row][lane] = dbc[((size_t)b * 48 + row) * kL + l0 + lane];
    }
  }
  __syncthreads();
  float Av[16], Wr[16];
#pragma unroll
  for (int q = 0; q < 4; ++q) {
    float4 a4 = *(const float4*)(A_log + d * 16 + q * 4);
    Av[q * 4 + 0] = -__expf(a4.x); Av[q * 4 + 1] = -__expf(a4.y);
    Av[q * 4 + 2] = -__expf(a4.z); Av[q * 4 + 3] = -__expf(a4.w);
    float4 w4 = *(const float4*)(Wdt + d * 16 + q * 4);
    Wr[q * 4 + 0] = w4.x; Wr[q * 4 + 1] = w4.y; Wr[q * 4 + 2] = w4.z; Wr[q * 4 + 3] = w4.w;
  }
  const float bias = bdt[d];
  const float Dv = Dp[d];
  float s[16];
  {
    size_t base = (size_t)(b * kNC + ch) * (kN * kDI) + d;
#pragma unroll
    for (int n = 0; n < kN; ++n) s[n] = init[base + (size_t)n * kDI];
  }
  const float* pU = uc + ((size_t)b * kL + l0) * kDI + d;
  const unsigned short* pR = resb + ((size_t)b * kL + l0) * kDI + d;
  unsigned short* pY = yt + ((size_t)b * kL + l0) * kDI + d;

  for (int i = 0; i < kCS; i += 4) {
    float del[4] = {bias, bias, bias, bias};
#pragma unroll
    for (int r = 0; r < 16; ++r) {
      float4 v = *(const float4*)&DtBC[r][i];
      del[0] += Wr[r] * v.x; del[1] += Wr[r] * v.y;
      del[2] += Wr[r] * v.z; del[3] += Wr[r] * v.w;
    }
    float uv[4], du[4], yacc[4] = {0.f, 0.f, 0.f, 0.f};
#pragma unroll
    for (int jj = 0; jj < 4; ++jj) {
      float x = del[jj];
      x = fmaxf(x, 0.f) + log1pf(__expf(-fabsf(x)));
      del[jj] = x;
      uv[jj] = pU[(size_t)(i + jj) * kDI];
      du[jj] = x * uv[jj];
    }
#pragma unroll
    for (int n = 0; n < kN; ++n) {
      float4 B4 = *(const float4*)&DtBC[16 + n][i];
      float4 C4 = *(const float4*)&DtBC[32 + n][i];
      float a;
      a = __expf(del[0] * Av[n]); s[n] = s[n] * a + du[0] * B4.x; yacc[0] += s[n] * C4.x;
      a = __expf(del[1] * Av[n]); s[n] = s[n] * a + du[1] * B4.y; yacc[1] += s[n] * C4.y;
      a = __expf(del[2] * Av[n]); s[n] = s[n] * a + du[2] * B4.z; yacc[2] += s[n] * C4.z;
      a = __expf(del[3] * Av[n]); s[n] = s[n] * a + du[3] * B4.w; yacc[3] += s[n] * C4.w;
    }
#pragma unroll
    for (int jj = 0; jj < 4; ++jj) {
      float r = bf2f(pR[(size_t)(i + jj) * kDI]);
      float g = (yacc[jj] + uv[jj] * Dv) * siluf(r);
      pY[(size_t)(i + jj) * kDI] = f2bf(g);
    }
  }
}

// ---------------------------------------------------------------------------
// out_proj GEMM: out[b][c][l] = sum_k Wo[c,k] * yt[b,l,k]. (R3-proven form)
// ---------------------------------------------------------------------------
__global__ __launch_bounds__(256) void gemm_out(const unsigned short* __restrict__ A,
                                                const unsigned short* __restrict__ Bt,
                                                float* __restrict__ C0) {
  __shared__ __align__(16) unsigned short As[128 * 64];
  __shared__ __align__(16) unsigned short Bs[128 * 64];
  const int n0 = blockIdx.x * 128;
  const int m0 = blockIdx.y * 128;
  const int b  = blockIdx.z;
  const int t  = threadIdx.x;
  const int wave = t >> 6, lane = t & 63;
  const int wm = wave >> 1, wn = wave & 1;
  const unsigned short* Bb = Bt + (size_t)b * kL * kDI;

  f32x4 acc[4][4];
#pragma unroll
  for (int i = 0; i < 4; ++i)
#pragma unroll
    for (int j = 0; j < 4; ++j) acc[i][j] = (f32x4)0.0f;

  const int srow = t >> 3, sch = t & 7;
  for (int kt = 0; kt < 8; ++kt) {
    const int k0 = kt * 64;
#pragma unroll
    for (int c = 0; c < 4; ++c) {
      int row = c * 32 + srow;
      int gch = sch ^ (row & 7);
      gload_lds16(A  + (size_t)(m0 + row) * kDI + k0 + gch * 8,
                  (char*)As + c * 4096 + wave * 1024);
      gload_lds16(Bb + (size_t)(n0 + row) * kDI + k0 + gch * 8,
                  (char*)Bs + c * 4096 + wave * 1024);
    }
    __syncthreads();
#pragma unroll
    for (int ks = 0; ks < 2; ++ks) {
      bf16x8 af[4], bfr[4];
#pragma unroll
      for (int f = 0; f < 4; ++f) {
        int ra = wm * 64 + f * 16 + (lane & 15);
        int ca = (ks * 4 + (lane >> 4)) ^ (ra & 7);
        af[f] = *(const bf16x8*)((const char*)As + ra * 128 + ca * 16);
        int rb = wn * 64 + f * 16 + (lane & 15);
        int cb = (ks * 4 + (lane >> 4)) ^ (rb & 7);
        bfr[f] = *(const bf16x8*)((const char*)Bs + rb * 128 + cb * 16);
      }
#pragma unroll
      for (int i = 0; i < 4; ++i)
#pragma unroll
        for (int j = 0; j < 4; ++j)
          acc[i][j] = __builtin_amdgcn_mfma_f32_16x16x32_bf16(af[i], bfr[j], acc[i][j], 0, 0, 0);
    }
    __syncthreads();
  }
#pragma unroll
  for (int i = 0; i < 4; ++i)
#pragma unroll
    for (int j = 0; j < 4; ++j)
#pragma unroll
      for (int r = 0; r < 4; ++r) {
        int m = m0 + wm * 64 + i * 16 + (lane >> 4) * 4 + r;
        int n = n0 + wn * 64 + j * 16 + (lane & 15);
        C0[((size_t)b * kDim + m) * kL + n] = acc[i][j][r];
      }
}

// ---------------------------------------------------------------------------
extern "C" void kernel_launch(void* const* d_in, const int* in_sizes, int n_in,
                              void* d_out, int out_size, void* d_ws, size_t ws_size,
                              hipStream_t stream) {
  const float* x       = (const float*)d_in[0];
  const float* in_w    = (const float*)d_in[1];
  const float* conv_w  = (const float*)d_in[2];
  const float* conv_b  = (const float*)d_in[3];
  const float* xproj_w = (const float*)d_in[4];
  const float* dt_w    = (const float*)d_in[5];
  const float* dt_b    = (const float*)d_in[6];
  const float* A_log   = (const float*)d_in[7];
  const float* Dp      = (const float*)d_in[8];
  const float* out_w   = (const float*)d_in[9];
  float* out = (float*)d_out;

  float* ws = (float*)d_ws;
  const size_t nBLD = (size_t)kB * kL * kDI;        // 8388608
  float* u    = ws;                                  // [b,l,512] f32
  float* uc   = u + nBLD;                            // [b,l,512] f32
  unsigned short* ucb = (unsigned short*)(uc + nBLD);        // [b,l,512] bf16
  float* dbc  = (float*)(ucb + nBLD);                // [b,48,L] f32
  float* reg1 = dbc + (size_t)kB * 48 * kL;          // 2097152 f: xt | init
  float* reg2 = reg1 + 2097152;                      // 4194304 f: P,S | yt
  unsigned short* resb = (unsigned short*)(reg2 + 4194304);  // [b,l,512] bf16
  unsigned short* wib  = resb + nBLD;                // 262144
  unsigned short* wob  = wib + 262144;               // 131072
  unsigned short* wxb  = wob + 131072;               // 24576
  unsigned short* xt   = (unsigned short*)reg1;      // dead after gemm_in
  float* initb = reg1;                               // written by scanB
  float* Pb    = reg2;
  float* Sb    = reg2 + 2097152;
  unsigned short* yt = (unsigned short*)reg2;        // overlays P,S (dead)

  k_wcvt<<<dim3(1632), 256, 0, stream>>>(in_w, out_w, xproj_w, wib, wob, wxb);
  k_xt<<<dim3(kL / 64, kDim / 64, kB), 256, 0, stream>>>(x, xt);
  gemm_in_lm<<<dim3(8, kL / 128, kB), 256, 0, stream>>>(xt, wib, u, resb);
  k_conv<<<dim3((unsigned)(nBLD / 1024)), 256, 0, stream>>>(u, conv_w, conv_b, uc, ucb);
  k_xproj<<<dim3(kL / 128, kB), 256, 0, stream>>>(wxb, ucb, dbc);
  k_scanA<<<dim3(2, kNC, kB), 256, 0, stream>>>(uc, dbc, A_log, dt_w, dt_b, Pb, Sb);
  k_scanB<<<dim3(kB * kDI * kN / 256), 256, 0, stream>>>(Pb, Sb, initb);
  k_scanC<<<dim3(2, kNC, kB), 256, 0, stream>>>(uc, dbc, A_log, dt_w, dt_b, initb, resb, Dp, yt);
  gemm_out<<<dim3(kL / 128, kDim / 128, kB), 256, 0, stream>>>(wob, yt, out);
}

// Round 5
// 210.460 us; speedup vs baseline: 3.1986x; 1.1094x over previous
//
#include <hip/hip_runtime.h>
#include <math.h>

// Mamba block forward, l-major activations [b, l, d].
// B=4, DIM=256, L=4096, D_INNER=512, D_STATE=16, DT_RANK=16, D_CONV=4.
// in/out_proj + x_proj: bf16 MFMA. Scan: thread-per-d, 16 n-states in regs,
// dt_proj+softplus fused; A-structure fast path (Av[n] = (n+1)*Av[0]) turns
// 16 exps/element into 1 exp + mul chain (guarded, generic fallback).

namespace {
constexpr int kB   = 4;
constexpr int kDim = 256;
constexpr int kL   = 4096;
constexpr int kDI  = 512;
constexpr int kN   = 16;
constexpr int kNC  = 128;  // scan chunks
constexpr int kCS  = 32;   // chunk size
} // namespace

typedef __attribute__((ext_vector_type(8))) short bf16x8;
typedef __attribute__((ext_vector_type(4))) float f32x4;

__device__ __forceinline__ float siluf(float x) { return x / (1.f + __expf(-x)); }

__device__ __forceinline__ unsigned short f2bf(float x) {
  union { float f; unsigned int u; } v; v.f = x;
  unsigned int u = v.u;
  u += 0x7fffu + ((u >> 16) & 1u);   // RNE
  return (unsigned short)(u >> 16);
}
__device__ __forceinline__ float bf2f(unsigned short u) {
  union { unsigned int i; float f; } v; v.i = ((unsigned int)u) << 16; return v.f;
}

__device__ __forceinline__ void gload_lds16(const void* g, void* l) {
  __builtin_amdgcn_global_load_lds(
      (const __attribute__((address_space(1))) unsigned int*)g,
      (__attribute__((address_space(3))) unsigned int*)l, 16, 0, 0);
}

// ---------------------------------------------------------------------------
// Convert weights to bf16.
// ---------------------------------------------------------------------------
__global__ __launch_bounds__(256) void k_wcvt(const float* __restrict__ w_in,
                                              const float* __restrict__ w_out,
                                              const float* __restrict__ w_x,
                                              unsigned short* __restrict__ wib,
                                              unsigned short* __restrict__ wob,
                                              unsigned short* __restrict__ wxb) {
  int idx = blockIdx.x * 256 + threadIdx.x;
  if (idx < 262144) wib[idx] = f2bf(w_in[idx]);
  else if (idx < 262144 + 131072) wob[idx - 262144] = f2bf(w_out[idx - 262144]);
  else if (idx < 262144 + 131072 + 24576) wxb[idx - 393216] = f2bf(w_x[idx - 393216]);
}

// ---------------------------------------------------------------------------
// Transpose-convert x [b, d, l] f32 -> xt [b, l, d] bf16.
// ---------------------------------------------------------------------------
__global__ __launch_bounds__(256) void k_xt(const float* __restrict__ x,
                                            unsigned short* __restrict__ xt) {
  __shared__ float Xs[64][65];
  const int b = blockIdx.z, d0 = blockIdx.y * 64, l0 = blockIdx.x * 64;
  const int t = threadIdx.x, l = t & 63;
#pragma unroll
  for (int rep = 0; rep < 16; ++rep) {
    int dd = rep * 4 + (t >> 6);
    Xs[dd][l] = x[((size_t)b * kDim + d0 + dd) * kL + l0 + l];
  }
  __syncthreads();
#pragma unroll
  for (int rep = 0; rep < 8; ++rep) {
    int lj = rep * 8 + (t >> 5);
    int di = (t & 31) * 2;
    ushort2 v;
    v.x = f2bf(Xs[di][lj]);
    v.y = f2bf(Xs[di + 1][lj]);
    *(ushort2*)(xt + ((size_t)b * kL + l0 + lj) * kDim + d0 + di) = v;
  }
}

// ---------------------------------------------------------------------------
// in_proj GEMM, l-major bf16 output: C[b][l][e] = sum_k xt[b,l,k] * W[e,k].
// e<512 -> ubf; e>=512 -> resb.
// ---------------------------------------------------------------------------
__global__ __launch_bounds__(256) void gemm_in_lm(const unsigned short* __restrict__ xt,
                                                  const unsigned short* __restrict__ W,
                                                  unsigned short* __restrict__ ubf,
                                                  unsigned short* __restrict__ resb) {
  __shared__ __align__(16) unsigned short As[128 * 64];
  __shared__ __align__(16) unsigned short Bs[128 * 64];
  const int e0 = blockIdx.x * 128;
  const int l0 = blockIdx.y * 128;
  const int b  = blockIdx.z;
  const int t  = threadIdx.x;
  const int wave = t >> 6, lane = t & 63;
  const int wm = wave >> 1, wn = wave & 1;
  const unsigned short* Ab = xt + (size_t)b * kL * kDim;

  f32x4 acc[4][4];
#pragma unroll
  for (int i = 0; i < 4; ++i)
#pragma unroll
    for (int j = 0; j < 4; ++j) acc[i][j] = (f32x4)0.0f;

  const int srow = t >> 3, sch = t & 7;
  for (int kt = 0; kt < 4; ++kt) {
    const int k0 = kt * 64;
#pragma unroll
    for (int c = 0; c < 4; ++c) {
      int row = c * 32 + srow;
      int gch = sch ^ (row & 7);
      gload_lds16(Ab + (size_t)(l0 + row) * kDim + k0 + gch * 8,
                  (char*)As + c * 4096 + wave * 1024);
      gload_lds16(W  + (size_t)(e0 + row) * kDim + k0 + gch * 8,
                  (char*)Bs + c * 4096 + wave * 1024);
    }
    __syncthreads();
#pragma unroll
    for (int ks = 0; ks < 2; ++ks) {
      bf16x8 af[4], bfr[4];
#pragma unroll
      for (int f = 0; f < 4; ++f) {
        int ra = wm * 64 + f * 16 + (lane & 15);
        int ca = (ks * 4 + (lane >> 4)) ^ (ra & 7);
        af[f] = *(const bf16x8*)((const char*)As + ra * 128 + ca * 16);
        int rb = wn * 64 + f * 16 + (lane & 15);
        int cb = (ks * 4 + (lane >> 4)) ^ (rb & 7);
        bfr[f] = *(const bf16x8*)((const char*)Bs + rb * 128 + cb * 16);
      }
#pragma unroll
      for (int i = 0; i < 4; ++i)
#pragma unroll
        for (int j = 0; j < 4; ++j)
          acc[i][j] = __builtin_amdgcn_mfma_f32_16x16x32_bf16(af[i], bfr[j], acc[i][j], 0, 0, 0);
    }
    __syncthreads();
  }

  const bool is_u = (e0 < kDI);
  unsigned short* dst = is_u ? ubf : resb;
  const int ebase = is_u ? e0 : (e0 - kDI);
#pragma unroll
  for (int i = 0; i < 4; ++i)
#pragma unroll
    for (int j = 0; j < 4; ++j)
#pragma unroll
      for (int r = 0; r < 4; ++r) {
        int l = l0 + wm * 64 + i * 16 + (lane >> 4) * 4 + r;
        int e = ebase + wn * 64 + j * 16 + (lane & 15);
        dst[((size_t)b * kL + l) * kDI + e] = f2bf(acc[i][j][r]);
      }
}

// ---------------------------------------------------------------------------
// Causal depthwise conv k=4 + bias + SiLU, l-major, bf16 in/out, 8 d/thread.
// ---------------------------------------------------------------------------
__global__ __launch_bounds__(256) void k_conv(const unsigned short* __restrict__ ubf,
                                              const float* __restrict__ cw,
                                              const float* __restrict__ cb,
                                              unsigned short* __restrict__ ucb) {
  int idx = blockIdx.x * 256 + threadIdx.x;   // over B*L*64
  int d8 = idx & 63;
  int l  = (idx >> 6) & (kL - 1);
  int b  = idx >> 18;
  int d0 = d8 * 8;
  const unsigned short* row = ubf + ((size_t)b * kL + l) * kDI + d0;
  uint4 zero = make_uint4(0, 0, 0, 0);
  uint4 c0 = *(const uint4*)row;
  uint4 c1 = (l >= 1) ? *(const uint4*)(row - kDI)     : zero;
  uint4 c2 = (l >= 2) ? *(const uint4*)(row - 2 * kDI) : zero;
  uint4 c3 = (l >= 3) ? *(const uint4*)(row - 3 * kDI) : zero;
  const unsigned int* p0 = (const unsigned int*)&c0;
  const unsigned int* p1 = (const unsigned int*)&c1;
  const unsigned int* p2 = (const unsigned int*)&c2;
  const unsigned int* p3 = (const unsigned int*)&c3;
  unsigned short ov[8];
#pragma unroll
  for (int c = 0; c < 8; ++c) {
    int q = c >> 1, hi = c & 1;
    float u0 = bf2f((unsigned short)(hi ? (p0[q] >> 16) : (p0[q] & 0xffff)));
    float u1 = bf2f((unsigned short)(hi ? (p1[q] >> 16) : (p1[q] & 0xffff)));
    float u2 = bf2f((unsigned short)(hi ? (p2[q] >> 16) : (p2[q] & 0xffff)));
    float u3 = bf2f((unsigned short)(hi ? (p3[q] >> 16) : (p3[q] & 0xffff)));
    float4 w = *(const float4*)(cw + (d0 + c) * 4);
    float acc = cb[d0 + c] + w.x * u3 + w.y * u2 + w.z * u1 + w.w * u0;
    ov[c] = f2bf(siluf(acc));
  }
  *(uint4*)(ucb + ((size_t)b * kL + l) * kDI + d0) = *(const uint4*)ov;
}

// ---------------------------------------------------------------------------
// x_proj MFMA: dbc[b][m][l] = sum_k Wx[m,k] * ucb[b,l,k], m in [0,48), K=512.
// ---------------------------------------------------------------------------
__global__ __launch_bounds__(256) void k_xproj(const unsigned short* __restrict__ Wx,
                                               const unsigned short* __restrict__ ucb,
                                               float* __restrict__ dbc) {
  __shared__ __align__(16) unsigned short As[64 * 64];
  __shared__ __align__(16) unsigned short Bs[128 * 64];
  const int l0 = blockIdx.x * 128;
  const int b  = blockIdx.y;
  const int t  = threadIdx.x;
  const int wave = t >> 6, lane = t & 63;
  const unsigned short* Bb = ucb + (size_t)b * kL * kDI;

  f32x4 acc[3][2];
#pragma unroll
  for (int i = 0; i < 3; ++i)
#pragma unroll
    for (int j = 0; j < 2; ++j) acc[i][j] = (f32x4)0.0f;

  const int srow = t >> 3, sch = t & 7;
  for (int kt = 0; kt < 8; ++kt) {
    const int k0 = kt * 64;
#pragma unroll
    for (int c = 0; c < 2; ++c) {
      int row = c * 32 + srow;
      int grow = row < 48 ? row : 47;
      int gch = sch ^ (row & 7);
      gload_lds16(Wx + (size_t)grow * kDI + k0 + gch * 8,
                  (char*)As + c * 4096 + wave * 1024);
    }
#pragma unroll
    for (int c = 0; c < 4; ++c) {
      int row = c * 32 + srow;
      int gch = sch ^ (row & 7);
      gload_lds16(Bb + (size_t)(l0 + row) * kDI + k0 + gch * 8,
                  (char*)Bs + c * 4096 + wave * 1024);
    }
    __syncthreads();
#pragma unroll
    for (int ks = 0; ks < 2; ++ks) {
      bf16x8 af[3], bfr[2];
#pragma unroll
      for (int f = 0; f < 3; ++f) {
        int ra = f * 16 + (lane & 15);
        int ca = (ks * 4 + (lane >> 4)) ^ (ra & 7);
        af[f] = *(const bf16x8*)((const char*)As + ra * 128 + ca * 16);
      }
#pragma unroll
      for (int f = 0; f < 2; ++f) {
        int rb = wave * 32 + f * 16 + (lane & 15);
        int cb = (ks * 4 + (lane >> 4)) ^ (rb & 7);
        bfr[f] = *(const bf16x8*)((const char*)Bs + rb * 128 + cb * 16);
      }
#pragma unroll
      for (int i = 0; i < 3; ++i)
#pragma unroll
        for (int j = 0; j < 2; ++j)
          acc[i][j] = __builtin_amdgcn_mfma_f32_16x16x32_bf16(af[i], bfr[j], acc[i][j], 0, 0, 0);
    }
    __syncthreads();
  }
#pragma unroll
  for (int i = 0; i < 3; ++i)
#pragma unroll
    for (int j = 0; j < 2; ++j)
#pragma unroll
      for (int r = 0; r < 4; ++r) {
        int m = i * 16 + (lane >> 4) * 4 + r;
        int l = l0 + wave * 32 + j * 16 + (lane & 15);
        dbc[((size_t)b * 48 + m) * kL + l] = acc[i][j][r];
      }
}

// ---------------------------------------------------------------------------
// Scan phase A (fused dt_proj+softplus): thread owns d, 16 (P,S) in regs.
// Fast path (Av[n]=(n+1)Av[0]): 1 exp/l + power chain; P = exp(Av[n]*sum d).
// ---------------------------------------------------------------------------
__global__ __launch_bounds__(256) void k_scanA(const unsigned short* __restrict__ ucb,
                                               const float* __restrict__ dbc,
                                               const float* __restrict__ A_log,
                                               const float* __restrict__ Wdt,
                                               const float* __restrict__ bdt,
                                               float* __restrict__ P,
                                               float* __restrict__ S) {
  __shared__ __align__(16) float DtB[32][kCS];   // rows 0-15 dt, 16-31 B
  const int b = blockIdx.z, ch = blockIdx.y;
  const int t = threadIdx.x;
  const int d = blockIdx.x * 256 + t;
  const int l0 = ch * kCS;
  {
    int lane = t & 31, g = t >> 5;
#pragma unroll
    for (int r = 0; r < 4; ++r) {
      int row = r * 8 + g;
      DtB[row][lane] = dbc[((size_t)b * 48 + row) * kL + l0 + lane];
    }
  }
  __syncthreads();
  float Av[16], Wr[16];
#pragma unroll
  for (int q = 0; q < 4; ++q) {
    float4 a4 = *(const float4*)(A_log + d * 16 + q * 4);
    Av[q * 4 + 0] = -__expf(a4.x); Av[q * 4 + 1] = -__expf(a4.y);
    Av[q * 4 + 2] = -__expf(a4.z); Av[q * 4 + 3] = -__expf(a4.w);
    float4 w4 = *(const float4*)(Wdt + d * 16 + q * 4);
    Wr[q * 4 + 0] = w4.x; Wr[q * 4 + 1] = w4.y; Wr[q * 4 + 2] = w4.z; Wr[q * 4 + 3] = w4.w;
  }
  bool fast = true;
#pragma unroll
  for (int n = 1; n < kN; ++n)
    fast = fast && (fabsf(Av[n] - (n + 1) * Av[0]) <= 1e-5f * fabsf(Av[n]));
  const float bias = bdt[d];
  const unsigned short* pU = ucb + ((size_t)b * kL + l0) * kDI + d;
  size_t obase = (size_t)(b * kNC + ch) * (kN * kDI) + d;

  float Sv[16];
#pragma unroll
  for (int n = 0; n < kN; ++n) Sv[n] = 0.f;

  if (fast) {
    const float Av0 = Av[0];
    float sd = 0.f;
    for (int i = 0; i < kCS; i += 4) {
      float del[4] = {bias, bias, bias, bias};
#pragma unroll
      for (int r = 0; r < 16; ++r) {
        float4 v = *(const float4*)&DtB[r][i];
        del[0] += Wr[r] * v.x; del[1] += Wr[r] * v.y;
        del[2] += Wr[r] * v.z; del[3] += Wr[r] * v.w;
      }
      float du[4], E[4];
#pragma unroll
      for (int jj = 0; jj < 4; ++jj) {
        float xdl = del[jj];
        xdl = fmaxf(xdl, 0.f) + log1pf(__expf(-fabsf(xdl)));
        du[jj] = xdl * bf2f(pU[(size_t)(i + jj) * kDI]);
        E[jj] = __expf(xdl * Av0);
        sd += xdl;
      }
      float a0 = E[0], a1 = E[1], a2 = E[2], a3 = E[3];
#pragma unroll
      for (int n = 0; n < kN; ++n) {
        float4 B4 = *(const float4*)&DtB[16 + n][i];
        Sv[n] = Sv[n] * a0 + du[0] * B4.x;
        Sv[n] = Sv[n] * a1 + du[1] * B4.y;
        Sv[n] = Sv[n] * a2 + du[2] * B4.z;
        Sv[n] = Sv[n] * a3 + du[3] * B4.w;
        if (n < kN - 1) { a0 *= E[0]; a1 *= E[1]; a2 *= E[2]; a3 *= E[3]; }
      }
    }
    float targ = sd * Av0, arg = targ;
#pragma unroll
    for (int n = 0; n < kN; ++n) {
      P[obase + (size_t)n * kDI] = __expf(arg);
      S[obase + (size_t)n * kDI] = Sv[n];
      arg += targ;
    }
  } else {
    float Pv[16];
#pragma unroll
    for (int n = 0; n < kN; ++n) Pv[n] = 1.f;
    for (int i = 0; i < kCS; i += 4) {
      float del[4] = {bias, bias, bias, bias};
#pragma unroll
      for (int r = 0; r < 16; ++r) {
        float4 v = *(const float4*)&DtB[r][i];
        del[0] += Wr[r] * v.x; del[1] += Wr[r] * v.y;
        del[2] += Wr[r] * v.z; del[3] += Wr[r] * v.w;
      }
      float du[4];
#pragma unroll
      for (int jj = 0; jj < 4; ++jj) {
        float xdl = del[jj];
        xdl = fmaxf(xdl, 0.f) + log1pf(__expf(-fabsf(xdl)));
        del[jj] = xdl;
        du[jj] = xdl * bf2f(pU[(size_t)(i + jj) * kDI]);
      }
#pragma unroll
      for (int n = 0; n < kN; ++n) {
        float4 B4 = *(const float4*)&DtB[16 + n][i];
        float a;
        a = __expf(del[0] * Av[n]); Pv[n] *= a; Sv[n] = Sv[n] * a + du[0] * B4.x;
        a = __expf(del[1] * Av[n]); Pv[n] *= a; Sv[n] = Sv[n] * a + du[1] * B4.y;
        a = __expf(del[2] * Av[n]); Pv[n] *= a; Sv[n] = Sv[n] * a + du[2] * B4.z;
        a = __expf(del[3] * Av[n]); Pv[n] *= a; Sv[n] = Sv[n] * a + du[3] * B4.w;
      }
    }
#pragma unroll
    for (int n = 0; n < kN; ++n) {
      P[obase + (size_t)n * kDI] = Pv[n];
      S[obase + (size_t)n * kDI] = Sv[n];
    }
  }
}

// ---------------------------------------------------------------------------
// Scan phase B: combine chunk summaries -> per-chunk init states. 8-deep.
// ---------------------------------------------------------------------------
__global__ __launch_bounds__(256) void k_scanB(const float* __restrict__ P,
                                               const float* __restrict__ S,
                                               float* __restrict__ init) {
  int idx = blockIdx.x * 256 + threadIdx.x;  // b*8192 + n*512 + d
  int b = idx >> 13, nd = idx & 8191;
  size_t base = (size_t)b * kNC * 8192 + nd;
  float carry = 0.f;
  for (int c0 = 0; c0 < kNC; c0 += 8) {
    float p[8], s[8];
#pragma unroll
    for (int j = 0; j < 8; ++j) {
      size_t o = base + (size_t)(c0 + j) * 8192;
      p[j] = P[o]; s[j] = S[o];
    }
#pragma unroll
    for (int j = 0; j < 8; ++j) {
      init[base + (size_t)(c0 + j) * 8192] = carry;
      carry = p[j] * carry + s[j];
    }
  }
}

// ---------------------------------------------------------------------------
// Scan phase C (fused dt_proj + gate): replay chunk, y = sum_n s_n*C_n;
// g = (y + u*D)*silu(res) -> yt[b,l,d] bf16. Fast path as scanA.
// ---------------------------------------------------------------------------
__global__ __launch_bounds__(256) void k_scanC(const unsigned short* __restrict__ ucb,
                                               const float* __restrict__ dbc,
                                               const float* __restrict__ A_log,
                                               const float* __restrict__ Wdt,
                                               const float* __restrict__ bdt,
                                               const float* __restrict__ init,
                                               const unsigned short* __restrict__ resb,
                                               const float* __restrict__ Dp,
                                               unsigned short* __restrict__ yt) {
  __shared__ __align__(16) float DtBC[48][kCS];  // 0-15 dt, 16-31 B, 32-47 C
  const int b = blockIdx.z, ch = blockIdx.y;
  const int t = threadIdx.x;
  const int d = blockIdx.x * 256 + t;
  const int l0 = ch * kCS;
  {
    int lane = t & 31, g = t >> 5;
#pragma unroll
    for (int r = 0; r < 6; ++r) {
      int row = r * 8 + g;
      DtBC[row][lane] = dbc[((size_t)b * 48 + row) * kL + l0 + lane];
    }
  }
  __syncthreads();
  float Av[16], Wr[16];
#pragma unroll
  for (int q = 0; q < 4; ++q) {
    float4 a4 = *(const float4*)(A_log + d * 16 + q * 4);
    Av[q * 4 + 0] = -__expf(a4.x); Av[q * 4 + 1] = -__expf(a4.y);
    Av[q * 4 + 2] = -__expf(a4.z); Av[q * 4 + 3] = -__expf(a4.w);
    float4 w4 = *(const float4*)(Wdt + d * 16 + q * 4);
    Wr[q * 4 + 0] = w4.x; Wr[q * 4 + 1] = w4.y; Wr[q * 4 + 2] = w4.z; Wr[q * 4 + 3] = w4.w;
  }
  bool fast = true;
#pragma unroll
  for (int n = 1; n < kN; ++n)
    fast = fast && (fabsf(Av[n] - (n + 1) * Av[0]) <= 1e-5f * fabsf(Av[n]));
  const float bias = bdt[d];
  const float Dv = Dp[d];
  float s[16];
  {
    size_t base = (size_t)(b * kNC + ch) * (kN * kDI) + d;
#pragma unroll
    for (int n = 0; n < kN; ++n) s[n] = init[base + (size_t)n * kDI];
  }
  const unsigned short* pU = ucb + ((size_t)b * kL + l0) * kDI + d;
  const unsigned short* pR = resb + ((size_t)b * kL + l0) * kDI + d;
  unsigned short* pY = yt + ((size_t)b * kL + l0) * kDI + d;

  if (fast) {
    const float Av0 = Av[0];
    for (int i = 0; i < kCS; i += 4) {
      float del[4] = {bias, bias, bias, bias};
#pragma unroll
      for (int r = 0; r < 16; ++r) {
        float4 v = *(const float4*)&DtBC[r][i];
        del[0] += Wr[r] * v.x; del[1] += Wr[r] * v.y;
        del[2] += Wr[r] * v.z; del[3] += Wr[r] * v.w;
      }
      float uv[4], du[4], E[4], yacc[4] = {0.f, 0.f, 0.f, 0.f};
#pragma unroll
      for (int jj = 0; jj < 4; ++jj) {
        float xdl = del[jj];
        xdl = fmaxf(xdl, 0.f) + log1pf(__expf(-fabsf(xdl)));
        uv[jj] = bf2f(pU[(size_t)(i + jj) * kDI]);
        du[jj] = xdl * uv[jj];
        E[jj] = __expf(xdl * Av0);
      }
      float a0 = E[0], a1 = E[1], a2 = E[2], a3 = E[3];
#pragma unroll
      for (int n = 0; n < kN; ++n) {
        float4 B4 = *(const float4*)&DtBC[16 + n][i];
        float4 C4 = *(const float4*)&DtBC[32 + n][i];
        s[n] = s[n] * a0 + du[0] * B4.x; yacc[0] += s[n] * C4.x;
        s[n] = s[n] * a1 + du[1] * B4.y; yacc[1] += s[n] * C4.y;
        s[n] = s[n] * a2 + du[2] * B4.z; yacc[2] += s[n] * C4.z;
        s[n] = s[n] * a3 + du[3] * B4.w; yacc[3] += s[n] * C4.w;
        if (n < kN - 1) { a0 *= E[0]; a1 *= E[1]; a2 *= E[2]; a3 *= E[3]; }
      }
#pragma unroll
      for (int jj = 0; jj < 4; ++jj) {
        float r = bf2f(pR[(size_t)(i + jj) * kDI]);
        float gv = (yacc[jj] + uv[jj] * Dv) * siluf(r);
        pY[(size_t)(i + jj) * kDI] = f2bf(gv);
      }
    }
  } else {
    for (int i = 0; i < kCS; i += 4) {
      float del[4] = {bias, bias, bias, bias};
#pragma unroll
      for (int r = 0; r < 16; ++r) {
        float4 v = *(const float4*)&DtBC[r][i];
        del[0] += Wr[r] * v.x; del[1] += Wr[r] * v.y;
        del[2] += Wr[r] * v.z; del[3] += Wr[r] * v.w;
      }
      float uv[4], du[4], yacc[4] = {0.f, 0.f, 0.f, 0.f};
#pragma unroll
      for (int jj = 0; jj < 4; ++jj) {
        float xdl = del[jj];
        xdl = fmaxf(xdl, 0.f) + log1pf(__expf(-fabsf(xdl)));
        del[jj] = xdl;
        uv[jj] = bf2f(pU[(size_t)(i + jj) * kDI]);
        du[jj] = xdl * uv[jj];
      }
#pragma unroll
      for (int n = 0; n < kN; ++n) {
        float4 B4 = *(const float4*)&DtBC[16 + n][i];
        float4 C4 = *(const float4*)&DtBC[32 + n][i];
        float a;
        a = __expf(del[0] * Av[n]); s[n] = s[n] * a + du[0] * B4.x; yacc[0] += s[n] * C4.x;
        a = __expf(del[1] * Av[n]); s[n] = s[n] * a + du[1] * B4.y; yacc[1] += s[n] * C4.y;
        a = __expf(del[2] * Av[n]); s[n] = s[n] * a + du[2] * B4.z; yacc[2] += s[n] * C4.z;
        a = __expf(del[3] * Av[n]); s[n] = s[n] * a + du[3] * B4.w; yacc[3] += s[n] * C4.w;
      }
#pragma unroll
      for (int jj = 0; jj < 4; ++jj) {
        float r = bf2f(pR[(size_t)(i + jj) * kDI]);
        float gv = (yacc[jj] + uv[jj] * Dv) * siluf(r);
        pY[(size_t)(i + jj) * kDI] = f2bf(gv);
      }
    }
  }
}

// ---------------------------------------------------------------------------
// out_proj GEMM: out[b][c][l] = sum_k Wo[c,k] * yt[b,l,k].
// ---------------------------------------------------------------------------
__global__ __launch_bounds__(256) void gemm_out(const unsigned short* __restrict__ A,
                                                const unsigned short* __restrict__ Bt,
                                                float* __restrict__ C0) {
  __shared__ __align__(16) unsigned short As[128 * 64];
  __shared__ __align__(16) unsigned short Bs[128 * 64];
  const int n0 = blockIdx.x * 128;
  const int m0 = blockIdx.y * 128;
  const int b  = blockIdx.z;
  const int t  = threadIdx.x;
  const int wave = t >> 6, lane = t & 63;
  const int wm = wave >> 1, wn = wave & 1;
  const unsigned short* Bb = Bt + (size_t)b * kL * kDI;

  f32x4 acc[4][4];
#pragma unroll
  for (int i = 0; i < 4; ++i)
#pragma unroll
    for (int j = 0; j < 4; ++j) acc[i][j] = (f32x4)0.0f;

  const int srow = t >> 3, sch = t & 7;
  for (int kt = 0; kt < 8; ++kt) {
    const int k0 = kt * 64;
#pragma unroll
    for (int c = 0; c < 4; ++c) {
      int row = c * 32 + srow;
      int gch = sch ^ (row & 7);
      gload_lds16(A  + (size_t)(m0 + row) * kDI + k0 + gch * 8,
                  (char*)As + c * 4096 + wave * 1024);
      gload_lds16(Bb + (size_t)(n0 + row) * kDI + k0 + gch * 8,
                  (char*)Bs + c * 4096 + wave * 1024);
    }
    __syncthreads();
#pragma unroll
    for (int ks = 0; ks < 2; ++ks) {
      bf16x8 af[4], bfr[4];
#pragma unroll
      for (int f = 0; f < 4; ++f) {
        int ra = wm * 64 + f * 16 + (lane & 15);
        int ca = (ks * 4 + (lane >> 4)) ^ (ra & 7);
        af[f] = *(const bf16x8*)((const char*)As + ra * 128 + ca * 16);
        int rb = wn * 64 + f * 16 + (lane & 15);
        int cb = (ks * 4 + (lane >> 4)) ^ (rb & 7);
        bfr[f] = *(const bf16x8*)((const char*)Bs + rb * 128 + cb * 16);
      }
#pragma unroll
      for (int i = 0; i < 4; ++i)
#pragma unroll
        for (int j = 0; j < 4; ++j)
          acc[i][j] = __builtin_amdgcn_mfma_f32_16x16x32_bf16(af[i], bfr[j], acc[i][j], 0, 0, 0);
    }
    __syncthreads();
  }
#pragma unroll
  for (int i = 0; i < 4; ++i)
#pragma unroll
    for (int j = 0; j < 4; ++j)
#pragma unroll
      for (int r = 0; r < 4; ++r) {
        int m = m0 + wm * 64 + i * 16 + (lane >> 4) * 4 + r;
        int n = n0 + wn * 64 + j * 16 + (lane & 15);
        C0[((size_t)b * kDim + m) * kL + n] = acc[i][j][r];
      }
}

// ---------------------------------------------------------------------------
extern "C" void kernel_launch(void* const* d_in, const int* in_sizes, int n_in,
                              void* d_out, int out_size, void* d_ws, size_t ws_size,
                              hipStream_t stream) {
  const float* x       = (const float*)d_in[0];
  const float* in_w    = (const float*)d_in[1];
  const float* conv_w  = (const float*)d_in[2];
  const float* conv_b  = (const float*)d_in[3];
  const float* xproj_w = (const float*)d_in[4];
  const float* dt_w    = (const float*)d_in[5];
  const float* dt_b    = (const float*)d_in[6];
  const float* A_log   = (const float*)d_in[7];
  const float* Dp      = (const float*)d_in[8];
  const float* out_w   = (const float*)d_in[9];
  float* out = (float*)d_out;

  // workspace layout (~105 MB)
  float* ws = (float*)d_ws;
  const size_t nBLD  = (size_t)kB * kL * kDI;                 // 8388608
  const size_t nPS   = (size_t)kB * kNC * kN * kDI;           // 4194304
  float* dbc   = ws;                                          // 786432 f
  float* Pb    = dbc + (size_t)kB * 48 * kL;                  // 4194304 f
  float* Sb    = Pb + nPS;                                    // 4194304 f
  float* initb = Sb + nPS;                                    // 4194304 f
  unsigned short* ubf  = (unsigned short*)(initb + nPS);      // nBLD us
  unsigned short* ucb  = ubf + nBLD;
  unsigned short* resb = ucb + nBLD;
  unsigned short* wib  = resb + nBLD;                         // 262144
  unsigned short* wob  = wib + 262144;                        // 131072
  unsigned short* wxb  = wob + 131072;                        // 24576
  unsigned short* xt   = (unsigned short*)initb;              // dead before scanB
  unsigned short* yt   = (unsigned short*)Pb;                 // P dead after scanB

  k_wcvt<<<dim3(1632), 256, 0, stream>>>(in_w, out_w, xproj_w, wib, wob, wxb);
  k_xt<<<dim3(kL / 64, kDim / 64, kB), 256, 0, stream>>>(x, xt);
  gemm_in_lm<<<dim3(8, kL / 128, kB), 256, 0, stream>>>(xt, wib, ubf, resb);
  k_conv<<<dim3((unsigned)(kB * kL * 64 / 256)), 256, 0, stream>>>(ubf, conv_w, conv_b, ucb);
  k_xproj<<<dim3(kL / 128, kB), 256, 0, stream>>>(wxb, ucb, dbc);
  k_scanA<<<dim3(2, kNC, kB), 256, 0, stream>>>(ucb, dbc, A_log, dt_w, dt_b, Pb, Sb);
  k_scanB<<<dim3(kB * kDI * kN / 256), 256, 0, stream>>>(Pb, Sb, initb);
  k_scanC<<<dim3(2, kNC, kB), 256, 0, stream>>>(ucb, dbc, A_log, dt_w, dt_b, initb, resb, Dp, yt);
  gemm_out<<<dim3(kL / 128, kDim / 128, kB), 256, 0, stream>>>(wob, yt, out);
}

// Round 6
// 167.675 us; speedup vs baseline: 4.0148x; 1.2552x over previous
//
#include <hip/hip_runtime.h>
#include <math.h>

// Mamba block forward, l-major activations [b, l, d].
// B=4, DIM=256, L=4096, D_INNER=512, D_STATE=16, DT_RANK=16, D_CONV=4.
// in/out_proj + x_proj: bf16 MFMA. Scan: thread-per-d, 16 n-states in regs.
// R6: scanA stores delta (scanC no longer recomputes dt_proj/softplus);
// A-structure check hoisted to k_aprep (global flag + Av0[d]); softplus via
// __logf; silu via v_rcp.

namespace {
constexpr int kB   = 4;
constexpr int kDim = 256;
constexpr int kL   = 4096;
constexpr int kDI  = 512;
constexpr int kN   = 16;
constexpr int kNC  = 128;  // scan chunks
constexpr int kCS  = 32;   // chunk size
} // namespace

typedef __attribute__((ext_vector_type(8))) short bf16x8;
typedef __attribute__((ext_vector_type(4))) float f32x4;

__device__ __forceinline__ float rcpf(float x) { return __builtin_amdgcn_rcpf(x); }
__device__ __forceinline__ float siluf(float x) { return x * rcpf(1.f + __expf(-x)); }
__device__ __forceinline__ float softplusf(float x) {
  return fmaxf(x, 0.f) + __logf(1.f + __expf(-fabsf(x)));
}

__device__ __forceinline__ unsigned short f2bf(float x) {
  union { float f; unsigned int u; } v; v.f = x;
  unsigned int u = v.u;
  u += 0x7fffu + ((u >> 16) & 1u);   // RNE
  return (unsigned short)(u >> 16);
}
__device__ __forceinline__ float bf2f(unsigned short u) {
  union { unsigned int i; float f; } v; v.i = ((unsigned int)u) << 16; return v.f;
}

__device__ __forceinline__ void gload_lds16(const void* g, void* l) {
  __builtin_amdgcn_global_load_lds(
      (const __attribute__((address_space(1))) unsigned int*)g,
      (__attribute__((address_space(3))) unsigned int*)l, 16, 0, 0);
}

// ---------------------------------------------------------------------------
// Convert weights to bf16.
// ---------------------------------------------------------------------------
__global__ __launch_bounds__(256) void k_wcvt(const float* __restrict__ w_in,
                                              const float* __restrict__ w_out,
                                              const float* __restrict__ w_x,
                                              unsigned short* __restrict__ wib,
                                              unsigned short* __restrict__ wob,
                                              unsigned short* __restrict__ wxb) {
  int idx = blockIdx.x * 256 + threadIdx.x;
  if (idx < 262144) wib[idx] = f2bf(w_in[idx]);
  else if (idx < 262144 + 131072) wob[idx - 262144] = f2bf(w_out[idx - 262144]);
  else if (idx < 262144 + 131072 + 24576) wxb[idx - 393216] = f2bf(w_x[idx - 393216]);
}

// ---------------------------------------------------------------------------
// A-structure prep: Av0[d] = -exp(A_log[d,0]); fast flag &= (Av[n]==(n+1)Av0).
// flag pre-set nonzero via hipMemsetAsync.
// ---------------------------------------------------------------------------
__global__ __launch_bounds__(256) void k_aprep(const float* __restrict__ A_log,
                                               float* __restrict__ Avz,
                                               unsigned int* __restrict__ flag) {
  int d = blockIdx.x * 256 + threadIdx.x;
  float a0 = -__expf(A_log[d * kN]);
  bool ok = true;
#pragma unroll
  for (int n = 1; n < kN; ++n) {
    float av = -__expf(A_log[d * kN + n]);
    ok = ok && (fabsf(av - (n + 1) * a0) <= 1e-5f * fabsf(av));
  }
  Avz[d] = a0;
  if (!ok) atomicAnd(flag, 0u);
}

// ---------------------------------------------------------------------------
// Transpose-convert x [b, d, l] f32 -> xt [b, l, d] bf16.
// ---------------------------------------------------------------------------
__global__ __launch_bounds__(256) void k_xt(const float* __restrict__ x,
                                            unsigned short* __restrict__ xt) {
  __shared__ float Xs[64][65];
  const int b = blockIdx.z, d0 = blockIdx.y * 64, l0 = blockIdx.x * 64;
  const int t = threadIdx.x, l = t & 63;
#pragma unroll
  for (int rep = 0; rep < 16; ++rep) {
    int dd = rep * 4 + (t >> 6);
    Xs[dd][l] = x[((size_t)b * kDim + d0 + dd) * kL + l0 + l];
  }
  __syncthreads();
#pragma unroll
  for (int rep = 0; rep < 8; ++rep) {
    int lj = rep * 8 + (t >> 5);
    int di = (t & 31) * 2;
    ushort2 v;
    v.x = f2bf(Xs[di][lj]);
    v.y = f2bf(Xs[di + 1][lj]);
    *(ushort2*)(xt + ((size_t)b * kL + l0 + lj) * kDim + d0 + di) = v;
  }
}

// ---------------------------------------------------------------------------
// in_proj GEMM, l-major bf16 output: C[b][l][e] = sum_k xt[b,l,k] * W[e,k].
// ---------------------------------------------------------------------------
__global__ __launch_bounds__(256) void gemm_in_lm(const unsigned short* __restrict__ xt,
                                                  const unsigned short* __restrict__ W,
                                                  unsigned short* __restrict__ ubf,
                                                  unsigned short* __restrict__ resb) {
  __shared__ __align__(16) unsigned short As[128 * 64];
  __shared__ __align__(16) unsigned short Bs[128 * 64];
  const int e0 = blockIdx.x * 128;
  const int l0 = blockIdx.y * 128;
  const int b  = blockIdx.z;
  const int t  = threadIdx.x;
  const int wave = t >> 6, lane = t & 63;
  const int wm = wave >> 1, wn = wave & 1;
  const unsigned short* Ab = xt + (size_t)b * kL * kDim;

  f32x4 acc[4][4];
#pragma unroll
  for (int i = 0; i < 4; ++i)
#pragma unroll
    for (int j = 0; j < 4; ++j) acc[i][j] = (f32x4)0.0f;

  const int srow = t >> 3, sch = t & 7;
  for (int kt = 0; kt < 4; ++kt) {
    const int k0 = kt * 64;
#pragma unroll
    for (int c = 0; c < 4; ++c) {
      int row = c * 32 + srow;
      int gch = sch ^ (row & 7);
      gload_lds16(Ab + (size_t)(l0 + row) * kDim + k0 + gch * 8,
                  (char*)As + c * 4096 + wave * 1024);
      gload_lds16(W  + (size_t)(e0 + row) * kDim + k0 + gch * 8,
                  (char*)Bs + c * 4096 + wave * 1024);
    }
    __syncthreads();
#pragma unroll
    for (int ks = 0; ks < 2; ++ks) {
      bf16x8 af[4], bfr[4];
#pragma unroll
      for (int f = 0; f < 4; ++f) {
        int ra = wm * 64 + f * 16 + (lane & 15);
        int ca = (ks * 4 + (lane >> 4)) ^ (ra & 7);
        af[f] = *(const bf16x8*)((const char*)As + ra * 128 + ca * 16);
        int rb = wn * 64 + f * 16 + (lane & 15);
        int cb = (ks * 4 + (lane >> 4)) ^ (rb & 7);
        bfr[f] = *(const bf16x8*)((const char*)Bs + rb * 128 + cb * 16);
      }
#pragma unroll
      for (int i = 0; i < 4; ++i)
#pragma unroll
        for (int j = 0; j < 4; ++j)
          acc[i][j] = __builtin_amdgcn_mfma_f32_16x16x32_bf16(af[i], bfr[j], acc[i][j], 0, 0, 0);
    }
    __syncthreads();
  }

  const bool is_u = (e0 < kDI);
  unsigned short* dst = is_u ? ubf : resb;
  const int ebase = is_u ? e0 : (e0 - kDI);
#pragma unroll
  for (int i = 0; i < 4; ++i)
#pragma unroll
    for (int j = 0; j < 4; ++j)
#pragma unroll
      for (int r = 0; r < 4; ++r) {
        int l = l0 + wm * 64 + i * 16 + (lane >> 4) * 4 + r;
        int e = ebase + wn * 64 + j * 16 + (lane & 15);
        dst[((size_t)b * kL + l) * kDI + e] = f2bf(acc[i][j][r]);
      }
}

// ---------------------------------------------------------------------------
// Causal depthwise conv k=4 + bias + SiLU, l-major, bf16 in/out, 8 d/thread.
// ---------------------------------------------------------------------------
__global__ __launch_bounds__(256) void k_conv(const unsigned short* __restrict__ ubf,
                                              const float* __restrict__ cw,
                                              const float* __restrict__ cb,
                                              unsigned short* __restrict__ ucb) {
  int idx = blockIdx.x * 256 + threadIdx.x;   // over B*L*64
  int d8 = idx & 63;
  int l  = (idx >> 6) & (kL - 1);
  int b  = idx >> 18;
  int d0 = d8 * 8;
  const unsigned short* row = ubf + ((size_t)b * kL + l) * kDI + d0;
  uint4 zero = make_uint4(0, 0, 0, 0);
  uint4 c0 = *(const uint4*)row;
  uint4 c1 = (l >= 1) ? *(const uint4*)(row - kDI)     : zero;
  uint4 c2 = (l >= 2) ? *(const uint4*)(row - 2 * kDI) : zero;
  uint4 c3 = (l >= 3) ? *(const uint4*)(row - 3 * kDI) : zero;
  const unsigned int* p0 = (const unsigned int*)&c0;
  const unsigned int* p1 = (const unsigned int*)&c1;
  const unsigned int* p2 = (const unsigned int*)&c2;
  const unsigned int* p3 = (const unsigned int*)&c3;
  unsigned short ov[8];
#pragma unroll
  for (int c = 0; c < 8; ++c) {
    int q = c >> 1, hi = c & 1;
    float u0 = bf2f((unsigned short)(hi ? (p0[q] >> 16) : (p0[q] & 0xffff)));
    float u1 = bf2f((unsigned short)(hi ? (p1[q] >> 16) : (p1[q] & 0xffff)));
    float u2 = bf2f((unsigned short)(hi ? (p2[q] >> 16) : (p2[q] & 0xffff)));
    float u3 = bf2f((unsigned short)(hi ? (p3[q] >> 16) : (p3[q] & 0xffff)));
    float4 w = *(const float4*)(cw + (d0 + c) * 4);
    float acc = cb[d0 + c] + w.x * u3 + w.y * u2 + w.z * u1 + w.w * u0;
    ov[c] = f2bf(siluf(acc));
  }
  *(uint4*)(ucb + ((size_t)b * kL + l) * kDI + d0) = *(const uint4*)ov;
}

// ---------------------------------------------------------------------------
// x_proj MFMA: dbc[b][m][l] = sum_k Wx[m,k] * ucb[b,l,k], m in [0,48), K=512.
// ---------------------------------------------------------------------------
__global__ __launch_bounds__(256) void k_xproj(const unsigned short* __restrict__ Wx,
                                               const unsigned short* __restrict__ ucb,
                                               float* __restrict__ dbc) {
  __shared__ __align__(16) unsigned short As[64 * 64];
  __shared__ __align__(16) unsigned short Bs[128 * 64];
  const int l0 = blockIdx.x * 128;
  const int b  = blockIdx.y;
  const int t  = threadIdx.x;
  const int wave = t >> 6, lane = t & 63;
  const unsigned short* Bb = ucb + (size_t)b * kL * kDI;

  f32x4 acc[3][2];
#pragma unroll
  for (int i = 0; i < 3; ++i)
#pragma unroll
    for (int j = 0; j < 2; ++j) acc[i][j] = (f32x4)0.0f;

  const int srow = t >> 3, sch = t & 7;
  for (int kt = 0; kt < 8; ++kt) {
    const int k0 = kt * 64;
#pragma unroll
    for (int c = 0; c < 2; ++c) {
      int row = c * 32 + srow;
      int grow = row < 48 ? row : 47;
      int gch = sch ^ (row & 7);
      gload_lds16(Wx + (size_t)grow * kDI + k0 + gch * 8,
                  (char*)As + c * 4096 + wave * 1024);
    }
#pragma unroll
    for (int c = 0; c < 4; ++c) {
      int row = c * 32 + srow;
      int gch = sch ^ (row & 7);
      gload_lds16(Bb + (size_t)(l0 + row) * kDI + k0 + gch * 8,
                  (char*)Bs + c * 4096 + wave * 1024);
    }
    __syncthreads();
#pragma unroll
    for (int ks = 0; ks < 2; ++ks) {
      bf16x8 af[3], bfr[2];
#pragma unroll
      for (int f = 0; f < 3; ++f) {
        int ra = f * 16 + (lane & 15);
        int ca = (ks * 4 + (lane >> 4)) ^ (ra & 7);
        af[f] = *(const bf16x8*)((const char*)As + ra * 128 + ca * 16);
      }
#pragma unroll
      for (int f = 0; f < 2; ++f) {
        int rb = wave * 32 + f * 16 + (lane & 15);
        int cb = (ks * 4 + (lane >> 4)) ^ (rb & 7);
        bfr[f] = *(const bf16x8*)((const char*)Bs + rb * 128 + cb * 16);
      }
#pragma unroll
      for (int i = 0; i < 3; ++i)
#pragma unroll
        for (int j = 0; j < 2; ++j)
          acc[i][j] = __builtin_amdgcn_mfma_f32_16x16x32_bf16(af[i], bfr[j], acc[i][j], 0, 0, 0);
    }
    __syncthreads();
  }
#pragma unroll
  for (int i = 0; i < 3; ++i)
#pragma unroll
    for (int j = 0; j < 2; ++j)
#pragma unroll
      for (int r = 0; r < 4; ++r) {
        int m = i * 16 + (lane >> 4) * 4 + r;
        int l = l0 + wave * 32 + j * 16 + (lane & 15);
        dbc[((size_t)b * 48 + m) * kL + l] = acc[i][j][r];
      }
}

// ---------------------------------------------------------------------------
// Scan phase A (fused dt_proj+softplus): thread owns d, 16 (P,S) in regs.
// Stores delta f32 for scanC. Fast path: 1 exp/l + power chain.
// ---------------------------------------------------------------------------
__global__ __launch_bounds__(256) void k_scanA(const unsigned short* __restrict__ ucb,
                                               const float* __restrict__ dbc,
                                               const float* __restrict__ A_log,
                                               const float* __restrict__ Avz,
                                               const unsigned int* __restrict__ flag,
                                               const float* __restrict__ Wdt,
                                               const float* __restrict__ bdt,
                                               float* __restrict__ delta,
                                               float* __restrict__ P,
                                               float* __restrict__ S) {
  __shared__ __align__(16) float DtB[32][kCS];   // rows 0-15 dt, 16-31 B
  const int b = blockIdx.z, ch = blockIdx.y;
  const int t = threadIdx.x;
  const int d = blockIdx.x * 256 + t;
  const int l0 = ch * kCS;
  {
    int lane = t & 31, g = t >> 5;
#pragma unroll
    for (int r = 0; r < 4; ++r) {
      int row = r * 8 + g;
      DtB[row][lane] = dbc[((size_t)b * 48 + row) * kL + l0 + lane];
    }
  }
  __syncthreads();
  float Wr[16];
#pragma unroll
  for (int q = 0; q < 4; ++q) {
    float4 w4 = *(const float4*)(Wdt + d * 16 + q * 4);
    Wr[q * 4 + 0] = w4.x; Wr[q * 4 + 1] = w4.y; Wr[q * 4 + 2] = w4.z; Wr[q * 4 + 3] = w4.w;
  }
  const bool fast = (*flag != 0u);
  const float Av0 = Avz[d];
  const float bias = bdt[d];
  const unsigned short* pU = ucb + ((size_t)b * kL + l0) * kDI + d;
  float* pDel = delta + ((size_t)b * kL + l0) * kDI + d;
  size_t obase = (size_t)(b * kNC + ch) * (kN * kDI) + d;

  float Sv[16];
#pragma unroll
  for (int n = 0; n < kN; ++n) Sv[n] = 0.f;

  if (fast) {
    float sd = 0.f;
    for (int i = 0; i < kCS; i += 4) {
      float del[4] = {bias, bias, bias, bias};
#pragma unroll
      for (int r = 0; r < 16; ++r) {
        float4 v = *(const float4*)&DtB[r][i];
        del[0] += Wr[r] * v.x; del[1] += Wr[r] * v.y;
        del[2] += Wr[r] * v.z; del[3] += Wr[r] * v.w;
      }
      float du[4], E[4];
#pragma unroll
      for (int jj = 0; jj < 4; ++jj) {
        float xdl = softplusf(del[jj]);
        pDel[(size_t)(i + jj) * kDI] = xdl;
        du[jj] = xdl * bf2f(pU[(size_t)(i + jj) * kDI]);
        E[jj] = __expf(xdl * Av0);
        sd += xdl;
      }
      float a0 = E[0], a1 = E[1], a2 = E[2], a3 = E[3];
#pragma unroll
      for (int n = 0; n < kN; ++n) {
        float4 B4 = *(const float4*)&DtB[16 + n][i];
        Sv[n] = Sv[n] * a0 + du[0] * B4.x;
        Sv[n] = Sv[n] * a1 + du[1] * B4.y;
        Sv[n] = Sv[n] * a2 + du[2] * B4.z;
        Sv[n] = Sv[n] * a3 + du[3] * B4.w;
        if (n < kN - 1) { a0 *= E[0]; a1 *= E[1]; a2 *= E[2]; a3 *= E[3]; }
      }
    }
    float targ = sd * Av0, arg = targ;
#pragma unroll
    for (int n = 0; n < kN; ++n) {
      P[obase + (size_t)n * kDI] = __expf(arg);
      S[obase + (size_t)n * kDI] = Sv[n];
      arg += targ;
    }
  } else {
    float Av[16];
#pragma unroll
    for (int n = 0; n < kN; ++n) Av[n] = -__expf(A_log[d * kN + n]);
    float Pv[16];
#pragma unroll
    for (int n = 0; n < kN; ++n) Pv[n] = 1.f;
    for (int i = 0; i < kCS; i += 4) {
      float del[4] = {bias, bias, bias, bias};
#pragma unroll
      for (int r = 0; r < 16; ++r) {
        float4 v = *(const float4*)&DtB[r][i];
        del[0] += Wr[r] * v.x; del[1] += Wr[r] * v.y;
        del[2] += Wr[r] * v.z; del[3] += Wr[r] * v.w;
      }
      float du[4];
#pragma unroll
      for (int jj = 0; jj < 4; ++jj) {
        float xdl = softplusf(del[jj]);
        del[jj] = xdl;
        pDel[(size_t)(i + jj) * kDI] = xdl;
        du[jj] = xdl * bf2f(pU[(size_t)(i + jj) * kDI]);
      }
#pragma unroll
      for (int n = 0; n < kN; ++n) {
        float4 B4 = *(const float4*)&DtB[16 + n][i];
        float a;
        a = __expf(del[0] * Av[n]); Pv[n] *= a; Sv[n] = Sv[n] * a + du[0] * B4.x;
        a = __expf(del[1] * Av[n]); Pv[n] *= a; Sv[n] = Sv[n] * a + du[1] * B4.y;
        a = __expf(del[2] * Av[n]); Pv[n] *= a; Sv[n] = Sv[n] * a + du[2] * B4.z;
        a = __expf(del[3] * Av[n]); Pv[n] *= a; Sv[n] = Sv[n] * a + du[3] * B4.w;
      }
    }
#pragma unroll
    for (int n = 0; n < kN; ++n) {
      P[obase + (size_t)n * kDI] = Pv[n];
      S[obase + (size_t)n * kDI] = Sv[n];
    }
  }
}

// ---------------------------------------------------------------------------
// Scan phase B: combine chunk summaries -> per-chunk init states. 8-deep.
// ---------------------------------------------------------------------------
__global__ __launch_bounds__(256) void k_scanB(const float* __restrict__ P,
                                               const float* __restrict__ S,
                                               float* __restrict__ init) {
  int idx = blockIdx.x * 256 + threadIdx.x;  // b*8192 + n*512 + d
  int b = idx >> 13, nd = idx & 8191;
  size_t base = (size_t)b * kNC * 8192 + nd;
  float carry = 0.f;
  for (int c0 = 0; c0 < kNC; c0 += 8) {
    float p[8], s[8];
#pragma unroll
    for (int j = 0; j < 8; ++j) {
      size_t o = base + (size_t)(c0 + j) * 8192;
      p[j] = P[o]; s[j] = S[o];
    }
#pragma unroll
    for (int j = 0; j < 8; ++j) {
      init[base + (size_t)(c0 + j) * 8192] = carry;
      carry = p[j] * carry + s[j];
    }
  }
}

// ---------------------------------------------------------------------------
// Scan phase C (+gate): replay chunk using stored delta; y = sum_n s_n*C_n;
// g = (y + u*D)*silu(res) -> yt bf16.
// ---------------------------------------------------------------------------
__global__ __launch_bounds__(256) void k_scanC(const unsigned short* __restrict__ ucb,
                                               const float* __restrict__ delta,
                                               const float* __restrict__ dbc,
                                               const float* __restrict__ A_log,
                                               const float* __restrict__ Avz,
                                               const unsigned int* __restrict__ flag,
                                               const float* __restrict__ init,
                                               const unsigned short* __restrict__ resb,
                                               const float* __restrict__ Dp,
                                               unsigned short* __restrict__ yt) {
  __shared__ __align__(16) float BCs[32][kCS];  // 0-15 B, 16-31 C
  const int b = blockIdx.z, ch = blockIdx.y;
  const int t = threadIdx.x;
  const int d = blockIdx.x * 256 + t;
  const int l0 = ch * kCS;
  {
    int lane = t & 31, g = t >> 5;
#pragma unroll
    for (int r = 0; r < 4; ++r) {
      int row = r * 8 + g;
      BCs[row][lane] = dbc[((size_t)b * 48 + 16 + row) * kL + l0 + lane];
    }
  }
  __syncthreads();
  const bool fast = (*flag != 0u);
  const float Av0 = Avz[d];
  const float Dv = Dp[d];
  float s[16];
  {
    size_t base = (size_t)(b * kNC + ch) * (kN * kDI) + d;
#pragma unroll
    for (int n = 0; n < kN; ++n) s[n] = init[base + (size_t)n * kDI];
  }
  const unsigned short* pU = ucb + ((size_t)b * kL + l0) * kDI + d;
  const float* pDel = delta + ((size_t)b * kL + l0) * kDI + d;
  const unsigned short* pR = resb + ((size_t)b * kL + l0) * kDI + d;
  unsigned short* pY = yt + ((size_t)b * kL + l0) * kDI + d;

  if (fast) {
    for (int i = 0; i < kCS; i += 4) {
      float uv[4], du[4], E[4], yacc[4] = {0.f, 0.f, 0.f, 0.f};
#pragma unroll
      for (int jj = 0; jj < 4; ++jj) {
        float xdl = pDel[(size_t)(i + jj) * kDI];
        uv[jj] = bf2f(pU[(size_t)(i + jj) * kDI]);
        du[jj] = xdl * uv[jj];
        E[jj] = __expf(xdl * Av0);
      }
      float a0 = E[0], a1 = E[1], a2 = E[2], a3 = E[3];
#pragma unroll
      for (int n = 0; n < kN; ++n) {
        float4 B4 = *(const float4*)&BCs[n][i];
        float4 C4 = *(const float4*)&BCs[16 + n][i];
        s[n] = s[n] * a0 + du[0] * B4.x; yacc[0] += s[n] * C4.x;
        s[n] = s[n] * a1 + du[1] * B4.y; yacc[1] += s[n] * C4.y;
        s[n] = s[n] * a2 + du[2] * B4.z; yacc[2] += s[n] * C4.z;
        s[n] = s[n] * a3 + du[3] * B4.w; yacc[3] += s[n] * C4.w;
        if (n < kN - 1) { a0 *= E[0]; a1 *= E[1]; a2 *= E[2]; a3 *= E[3]; }
      }
#pragma unroll
      for (int jj = 0; jj < 4; ++jj) {
        float r = bf2f(pR[(size_t)(i + jj) * kDI]);
        float gv = (yacc[jj] + uv[jj] * Dv) * siluf(r);
        pY[(size_t)(i + jj) * kDI] = f2bf(gv);
      }
    }
  } else {
    float Av[16];
#pragma unroll
    for (int n = 0; n < kN; ++n) Av[n] = -__expf(A_log[d * kN + n]);
    for (int i = 0; i < kCS; i += 4) {
      float uv[4], du[4], del[4], yacc[4] = {0.f, 0.f, 0.f, 0.f};
#pragma unroll
      for (int jj = 0; jj < 4; ++jj) {
        del[jj] = pDel[(size_t)(i + jj) * kDI];
        uv[jj] = bf2f(pU[(size_t)(i + jj) * kDI]);
        du[jj] = del[jj] * uv[jj];
      }
#pragma unroll
      for (int n = 0; n < kN; ++n) {
        float4 B4 = *(const float4*)&BCs[n][i];
        float4 C4 = *(const float4*)&BCs[16 + n][i];
        float a;
        a = __expf(del[0] * Av[n]); s[n] = s[n] * a + du[0] * B4.x; yacc[0] += s[n] * C4.x;
        a = __expf(del[1] * Av[n]); s[n] = s[n] * a + du[1] * B4.y; yacc[1] += s[n] * C4.y;
        a = __expf(del[2] * Av[n]); s[n] = s[n] * a + du[2] * B4.z; yacc[2] += s[n] * C4.z;
        a = __expf(del[3] * Av[n]); s[n] = s[n] * a + du[3] * B4.w; yacc[3] += s[n] * C4.w;
      }
#pragma unroll
      for (int jj = 0; jj < 4; ++jj) {
        float r = bf2f(pR[(size_t)(i + jj) * kDI]);
        float gv = (yacc[jj] + uv[jj] * Dv) * siluf(r);
        pY[(size_t)(i + jj) * kDI] = f2bf(gv);
      }
    }
  }
}

// ---------------------------------------------------------------------------
// out_proj GEMM: out[b][c][l] = sum_k Wo[c,k] * yt[b,l,k].
// ---------------------------------------------------------------------------
__global__ __launch_bounds__(256) void gemm_out(const unsigned short* __restrict__ A,
                                                const unsigned short* __restrict__ Bt,
                                                float* __restrict__ C0) {
  __shared__ __align__(16) unsigned short As[128 * 64];
  __shared__ __align__(16) unsigned short Bs[128 * 64];
  const int n0 = blockIdx.x * 128;
  const int m0 = blockIdx.y * 128;
  const int b  = blockIdx.z;
  const int t  = threadIdx.x;
  const int wave = t >> 6, lane = t & 63;
  const int wm = wave >> 1, wn = wave & 1;
  const unsigned short* Bb = Bt + (size_t)b * kL * kDI;

  f32x4 acc[4][4];
#pragma unroll
  for (int i = 0; i < 4; ++i)
#pragma unroll
    for (int j = 0; j < 4; ++j) acc[i][j] = (f32x4)0.0f;

  const int srow = t >> 3, sch = t & 7;
  for (int kt = 0; kt < 8; ++kt) {
    const int k0 = kt * 64;
#pragma unroll
    for (int c = 0; c < 4; ++c) {
      int row = c * 32 + srow;
      int gch = sch ^ (row & 7);
      gload_lds16(A  + (size_t)(m0 + row) * kDI + k0 + gch * 8,
                  (char*)As + c * 4096 + wave * 1024);
      gload_lds16(Bb + (size_t)(n0 + row) * kDI + k0 + gch * 8,
                  (char*)Bs + c * 4096 + wave * 1024);
    }
    __syncthreads();
#pragma unroll
    for (int ks = 0; ks < 2; ++ks) {
      bf16x8 af[4], bfr[4];
#pragma unroll
      for (int f = 0; f < 4; ++f) {
        int ra = wm * 64 + f * 16 + (lane & 15);
        int ca = (ks * 4 + (lane >> 4)) ^ (ra & 7);
        af[f] = *(const bf16x8*)((const char*)As + ra * 128 + ca * 16);
        int rb = wn * 64 + f * 16 + (lane & 15);
        int cb = (ks * 4 + (lane >> 4)) ^ (rb & 7);
        bfr[f] = *(const bf16x8*)((const char*)Bs + rb * 128 + cb * 16);
      }
#pragma unroll
      for (int i = 0; i < 4; ++i)
#pragma unroll
        for (int j = 0; j < 4; ++j)
          acc[i][j] = __builtin_amdgcn_mfma_f32_16x16x32_bf16(af[i], bfr[j], acc[i][j], 0, 0, 0);
    }
    __syncthreads();
  }
#pragma unroll
  for (int i = 0; i < 4; ++i)
#pragma unroll
    for (int j = 0; j < 4; ++j)
#pragma unroll
      for (int r = 0; r < 4; ++r) {
        int m = m0 + wm * 64 + i * 16 + (lane >> 4) * 4 + r;
        int n = n0 + wn * 64 + j * 16 + (lane & 15);
        C0[((size_t)b * kDim + m) * kL + n] = acc[i][j][r];
      }
}

// ---------------------------------------------------------------------------
extern "C" void kernel_launch(void* const* d_in, const int* in_sizes, int n_in,
                              void* d_out, int out_size, void* d_ws, size_t ws_size,
                              hipStream_t stream) {
  const float* x       = (const float*)d_in[0];
  const float* in_w    = (const float*)d_in[1];
  const float* conv_w  = (const float*)d_in[2];
  const float* conv_b  = (const float*)d_in[3];
  const float* xproj_w = (const float*)d_in[4];
  const float* dt_w    = (const float*)d_in[5];
  const float* dt_b    = (const float*)d_in[6];
  const float* A_log   = (const float*)d_in[7];
  const float* Dp      = (const float*)d_in[8];
  const float* out_w   = (const float*)d_in[9];
  float* out = (float*)d_out;

  // workspace layout (~114 MB)
  float* ws = (float*)d_ws;
  const size_t nBLD  = (size_t)kB * kL * kDI;                 // 8388608
  const size_t nPS   = (size_t)kB * kNC * kN * kDI;           // 4194304
  float* dbc    = ws;                                         // 786432 f
  float* Pb     = dbc + (size_t)kB * 48 * kL;                 // nPS
  float* Sb     = Pb + nPS;                                   // nPS
  float* initb  = Sb + nPS;                                   // nPS
  float* deltaf = initb + nPS;                                // nBLD f
  unsigned short* ubf  = (unsigned short*)(deltaf + nBLD);    // nBLD us
  unsigned short* ucb  = ubf + nBLD;
  unsigned short* resb = ucb + nBLD;
  unsigned short* wib  = resb + nBLD;                         // 262144
  unsigned short* wob  = wib + 262144;                        // 131072
  unsigned short* wxb  = wob + 131072;                        // 24576
  float* Avz           = (float*)(wxb + 24576);               // 512 f
  unsigned int* flag   = (unsigned int*)(Avz + 512);          // 1 u32
  unsigned short* xt   = (unsigned short*)initb;              // dead before scanB
  unsigned short* yt   = (unsigned short*)Pb;                 // P dead after scanB

  hipMemsetAsync(flag, 0xFF, 4, stream);
  k_wcvt<<<dim3(1632), 256, 0, stream>>>(in_w, out_w, xproj_w, wib, wob, wxb);
  k_aprep<<<dim3(2), 256, 0, stream>>>(A_log, Avz, flag);
  k_xt<<<dim3(kL / 64, kDim / 64, kB), 256, 0, stream>>>(x, xt);
  gemm_in_lm<<<dim3(8, kL / 128, kB), 256, 0, stream>>>(xt, wib, ubf, resb);
  k_conv<<<dim3((unsigned)(kB * kL * 64 / 256)), 256, 0, stream>>>(ubf, conv_w, conv_b, ucb);
  k_xproj<<<dim3(kL / 128, kB), 256, 0, stream>>>(wxb, ucb, dbc);
  k_scanA<<<dim3(2, kNC, kB), 256, 0, stream>>>(ucb, dbc, A_log, Avz, flag, dt_w, dt_b, deltaf, Pb, Sb);
  k_scanB<<<dim3(kB * kDI * kN / 256), 256, 0, stream>>>(Pb, Sb, initb);
  k_scanC<<<dim3(2, kNC, kB), 256, 0, stream>>>(ucb, deltaf, dbc, A_log, Avz, flag, initb, resb, Dp, yt);
  gemm_out<<<dim3(kL / 128, kDim / 128, kB), 256, 0, stream>>>(wob, yt, out);
}

// Round 7
// 165.080 us; speedup vs baseline: 4.0779x; 1.0157x over previous
//
#include <hip/hip_runtime.h>
#include <math.h>

// Mamba block forward, l-major activations [b, l, d].
// B=4, DIM=256, L=4096, D_INNER=512, D_STATE=16, DT_RANK=16, D_CONV=4.
// in/out_proj + x_proj: bf16 MFMA. Scan: thread-per-d, 16 n-states in regs.
// R7: flag init moved into k_wcvt (hipMemsetAsync graph-captured as a ~40us
// serialized fillBuffer per replay -- removed).

namespace {
constexpr int kB   = 4;
constexpr int kDim = 256;
constexpr int kL   = 4096;
constexpr int kDI  = 512;
constexpr int kN   = 16;
constexpr int kNC  = 128;  // scan chunks
constexpr int kCS  = 32;   // chunk size
} // namespace

typedef __attribute__((ext_vector_type(8))) short bf16x8;
typedef __attribute__((ext_vector_type(4))) float f32x4;

__device__ __forceinline__ float rcpf(float x) { return __builtin_amdgcn_rcpf(x); }
__device__ __forceinline__ float siluf(float x) { return x * rcpf(1.f + __expf(-x)); }
__device__ __forceinline__ float softplusf(float x) {
  return fmaxf(x, 0.f) + __logf(1.f + __expf(-fabsf(x)));
}

__device__ __forceinline__ unsigned short f2bf(float x) {
  union { float f; unsigned int u; } v; v.f = x;
  unsigned int u = v.u;
  u += 0x7fffu + ((u >> 16) & 1u);   // RNE
  return (unsigned short)(u >> 16);
}
__device__ __forceinline__ float bf2f(unsigned short u) {
  union { unsigned int i; float f; } v; v.i = ((unsigned int)u) << 16; return v.f;
}

__device__ __forceinline__ void gload_lds16(const void* g, void* l) {
  __builtin_amdgcn_global_load_lds(
      (const __attribute__((address_space(1))) unsigned int*)g,
      (__attribute__((address_space(3))) unsigned int*)l, 16, 0, 0);
}

// ---------------------------------------------------------------------------
// Convert weights to bf16; thread (0,0) also initializes the fast-path flag
// (stream-ordered before k_aprep's atomicAnd).
// ---------------------------------------------------------------------------
__global__ __launch_bounds__(256) void k_wcvt(const float* __restrict__ w_in,
                                              const float* __restrict__ w_out,
                                              const float* __restrict__ w_x,
                                              unsigned short* __restrict__ wib,
                                              unsigned short* __restrict__ wob,
                                              unsigned short* __restrict__ wxb,
                                              unsigned int* __restrict__ flag) {
  int idx = blockIdx.x * 256 + threadIdx.x;
  if (idx == 0) *flag = 0xFFFFFFFFu;
  if (idx < 262144) wib[idx] = f2bf(w_in[idx]);
  else if (idx < 262144 + 131072) wob[idx - 262144] = f2bf(w_out[idx - 262144]);
  else if (idx < 262144 + 131072 + 24576) wxb[idx - 393216] = f2bf(w_x[idx - 393216]);
}

// ---------------------------------------------------------------------------
// A-structure prep: Av0[d] = -exp(A_log[d,0]); fast flag &= (Av[n]==(n+1)Av0).
// ---------------------------------------------------------------------------
__global__ __launch_bounds__(256) void k_aprep(const float* __restrict__ A_log,
                                               float* __restrict__ Avz,
                                               unsigned int* __restrict__ flag) {
  int d = blockIdx.x * 256 + threadIdx.x;
  float a0 = -__expf(A_log[d * kN]);
  bool ok = true;
#pragma unroll
  for (int n = 1; n < kN; ++n) {
    float av = -__expf(A_log[d * kN + n]);
    ok = ok && (fabsf(av - (n + 1) * a0) <= 1e-5f * fabsf(av));
  }
  Avz[d] = a0;
  if (!ok) atomicAnd(flag, 0u);
}

// ---------------------------------------------------------------------------
// Transpose-convert x [b, d, l] f32 -> xt [b, l, d] bf16.
// ---------------------------------------------------------------------------
__global__ __launch_bounds__(256) void k_xt(const float* __restrict__ x,
                                            unsigned short* __restrict__ xt) {
  __shared__ float Xs[64][65];
  const int b = blockIdx.z, d0 = blockIdx.y * 64, l0 = blockIdx.x * 64;
  const int t = threadIdx.x, l = t & 63;
#pragma unroll
  for (int rep = 0; rep < 16; ++rep) {
    int dd = rep * 4 + (t >> 6);
    Xs[dd][l] = x[((size_t)b * kDim + d0 + dd) * kL + l0 + l];
  }
  __syncthreads();
#pragma unroll
  for (int rep = 0; rep < 8; ++rep) {
    int lj = rep * 8 + (t >> 5);
    int di = (t & 31) * 2;
    ushort2 v;
    v.x = f2bf(Xs[di][lj]);
    v.y = f2bf(Xs[di + 1][lj]);
    *(ushort2*)(xt + ((size_t)b * kL + l0 + lj) * kDim + d0 + di) = v;
  }
}

// ---------------------------------------------------------------------------
// in_proj GEMM, l-major bf16 output: C[b][l][e] = sum_k xt[b,l,k] * W[e,k].
// ---------------------------------------------------------------------------
__global__ __launch_bounds__(256) void gemm_in_lm(const unsigned short* __restrict__ xt,
                                                  const unsigned short* __restrict__ W,
                                                  unsigned short* __restrict__ ubf,
                                                  unsigned short* __restrict__ resb) {
  __shared__ __align__(16) unsigned short As[128 * 64];
  __shared__ __align__(16) unsigned short Bs[128 * 64];
  const int e0 = blockIdx.x * 128;
  const int l0 = blockIdx.y * 128;
  const int b  = blockIdx.z;
  const int t  = threadIdx.x;
  const int wave = t >> 6, lane = t & 63;
  const int wm = wave >> 1, wn = wave & 1;
  const unsigned short* Ab = xt + (size_t)b * kL * kDim;

  f32x4 acc[4][4];
#pragma unroll
  for (int i = 0; i < 4; ++i)
#pragma unroll
    for (int j = 0; j < 4; ++j) acc[i][j] = (f32x4)0.0f;

  const int srow = t >> 3, sch = t & 7;
  for (int kt = 0; kt < 4; ++kt) {
    const int k0 = kt * 64;
#pragma unroll
    for (int c = 0; c < 4; ++c) {
      int row = c * 32 + srow;
      int gch = sch ^ (row & 7);
      gload_lds16(Ab + (size_t)(l0 + row) * kDim + k0 + gch * 8,
                  (char*)As + c * 4096 + wave * 1024);
      gload_lds16(W  + (size_t)(e0 + row) * kDim + k0 + gch * 8,
                  (char*)Bs + c * 4096 + wave * 1024);
    }
    __syncthreads();
#pragma unroll
    for (int ks = 0; ks < 2; ++ks) {
      bf16x8 af[4], bfr[4];
#pragma unroll
      for (int f = 0; f < 4; ++f) {
        int ra = wm * 64 + f * 16 + (lane & 15);
        int ca = (ks * 4 + (lane >> 4)) ^ (ra & 7);
        af[f] = *(const bf16x8*)((const char*)As + ra * 128 + ca * 16);
        int rb = wn * 64 + f * 16 + (lane & 15);
        int cb = (ks * 4 + (lane >> 4)) ^ (rb & 7);
        bfr[f] = *(const bf16x8*)((const char*)Bs + rb * 128 + cb * 16);
      }
#pragma unroll
      for (int i = 0; i < 4; ++i)
#pragma unroll
        for (int j = 0; j < 4; ++j)
          acc[i][j] = __builtin_amdgcn_mfma_f32_16x16x32_bf16(af[i], bfr[j], acc[i][j], 0, 0, 0);
    }
    __syncthreads();
  }

  const bool is_u = (e0 < kDI);
  unsigned short* dst = is_u ? ubf : resb;
  const int ebase = is_u ? e0 : (e0 - kDI);
#pragma unroll
  for (int i = 0; i < 4; ++i)
#pragma unroll
    for (int j = 0; j < 4; ++j)
#pragma unroll
      for (int r = 0; r < 4; ++r) {
        int l = l0 + wm * 64 + i * 16 + (lane >> 4) * 4 + r;
        int e = ebase + wn * 64 + j * 16 + (lane & 15);
        dst[((size_t)b * kL + l) * kDI + e] = f2bf(acc[i][j][r]);
      }
}

// ---------------------------------------------------------------------------
// Causal depthwise conv k=4 + bias + SiLU, l-major, bf16 in/out, 8 d/thread.
// ---------------------------------------------------------------------------
__global__ __launch_bounds__(256) void k_conv(const unsigned short* __restrict__ ubf,
                                              const float* __restrict__ cw,
                                              const float* __restrict__ cb,
                                              unsigned short* __restrict__ ucb) {
  int idx = blockIdx.x * 256 + threadIdx.x;   // over B*L*64
  int d8 = idx & 63;
  int l  = (idx >> 6) & (kL - 1);
  int b  = idx >> 18;
  int d0 = d8 * 8;
  const unsigned short* row = ubf + ((size_t)b * kL + l) * kDI + d0;
  uint4 zero = make_uint4(0, 0, 0, 0);
  uint4 c0 = *(const uint4*)row;
  uint4 c1 = (l >= 1) ? *(const uint4*)(row - kDI)     : zero;
  uint4 c2 = (l >= 2) ? *(const uint4*)(row - 2 * kDI) : zero;
  uint4 c3 = (l >= 3) ? *(const uint4*)(row - 3 * kDI) : zero;
  const unsigned int* p0 = (const unsigned int*)&c0;
  const unsigned int* p1 = (const unsigned int*)&c1;
  const unsigned int* p2 = (const unsigned int*)&c2;
  const unsigned int* p3 = (const unsigned int*)&c3;
  unsigned short ov[8];
#pragma unroll
  for (int c = 0; c < 8; ++c) {
    int q = c >> 1, hi = c & 1;
    float u0 = bf2f((unsigned short)(hi ? (p0[q] >> 16) : (p0[q] & 0xffff)));
    float u1 = bf2f((unsigned short)(hi ? (p1[q] >> 16) : (p1[q] & 0xffff)));
    float u2 = bf2f((unsigned short)(hi ? (p2[q] >> 16) : (p2[q] & 0xffff)));
    float u3 = bf2f((unsigned short)(hi ? (p3[q] >> 16) : (p3[q] & 0xffff)));
    float4 w = *(const float4*)(cw + (d0 + c) * 4);
    float acc = cb[d0 + c] + w.x * u3 + w.y * u2 + w.z * u1 + w.w * u0;
    ov[c] = f2bf(siluf(acc));
  }
  *(uint4*)(ucb + ((size_t)b * kL + l) * kDI + d0) = *(const uint4*)ov;
}

// ---------------------------------------------------------------------------
// x_proj MFMA: dbc[b][m][l] = sum_k Wx[m,k] * ucb[b,l,k], m in [0,48), K=512.
// ---------------------------------------------------------------------------
__global__ __launch_bounds__(256) void k_xproj(const unsigned short* __restrict__ Wx,
                                               const unsigned short* __restrict__ ucb,
                                               float* __restrict__ dbc) {
  __shared__ __align__(16) unsigned short As[64 * 64];
  __shared__ __align__(16) unsigned short Bs[128 * 64];
  const int l0 = blockIdx.x * 128;
  const int b  = blockIdx.y;
  const int t  = threadIdx.x;
  const int wave = t >> 6, lane = t & 63;
  const unsigned short* Bb = ucb + (size_t)b * kL * kDI;

  f32x4 acc[3][2];
#pragma unroll
  for (int i = 0; i < 3; ++i)
#pragma unroll
    for (int j = 0; j < 2; ++j) acc[i][j] = (f32x4)0.0f;

  const int srow = t >> 3, sch = t & 7;
  for (int kt = 0; kt < 8; ++kt) {
    const int k0 = kt * 64;
#pragma unroll
    for (int c = 0; c < 2; ++c) {
      int row = c * 32 + srow;
      int grow = row < 48 ? row : 47;
      int gch = sch ^ (row & 7);
      gload_lds16(Wx + (size_t)grow * kDI + k0 + gch * 8,
                  (char*)As + c * 4096 + wave * 1024);
    }
#pragma unroll
    for (int c = 0; c < 4; ++c) {
      int row = c * 32 + srow;
      int gch = sch ^ (row & 7);
      gload_lds16(Bb + (size_t)(l0 + row) * kDI + k0 + gch * 8,
                  (char*)Bs + c * 4096 + wave * 1024);
    }
    __syncthreads();
#pragma unroll
    for (int ks = 0; ks < 2; ++ks) {
      bf16x8 af[3], bfr[2];
#pragma unroll
      for (int f = 0; f < 3; ++f) {
        int ra = f * 16 + (lane & 15);
        int ca = (ks * 4 + (lane >> 4)) ^ (ra & 7);
        af[f] = *(const bf16x8*)((const char*)As + ra * 128 + ca * 16);
      }
#pragma unroll
      for (int f = 0; f < 2; ++f) {
        int rb = wave * 32 + f * 16 + (lane & 15);
        int cb = (ks * 4 + (lane >> 4)) ^ (rb & 7);
        bfr[f] = *(const bf16x8*)((const char*)Bs + rb * 128 + cb * 16);
      }
#pragma unroll
      for (int i = 0; i < 3; ++i)
#pragma unroll
        for (int j = 0; j < 2; ++j)
          acc[i][j] = __builtin_amdgcn_mfma_f32_16x16x32_bf16(af[i], bfr[j], acc[i][j], 0, 0, 0);
    }
    __syncthreads();
  }
#pragma unroll
  for (int i = 0; i < 3; ++i)
#pragma unroll
    for (int j = 0; j < 2; ++j)
#pragma unroll
      for (int r = 0; r < 4; ++r) {
        int m = i * 16 + (lane >> 4) * 4 + r;
        int l = l0 + wave * 32 + j * 16 + (lane & 15);
        dbc[((size_t)b * 48 + m) * kL + l] = acc[i][j][r];
      }
}

// ---------------------------------------------------------------------------
// Scan phase A (fused dt_proj+softplus): thread owns d, 16 (P,S) in regs.
// Stores delta f32 for scanC. Fast path: 1 exp/l + power chain.
// ---------------------------------------------------------------------------
__global__ __launch_bounds__(256) void k_scanA(const unsigned short* __restrict__ ucb,
                                               const float* __restrict__ dbc,
                                               const float* __restrict__ A_log,
                                               const float* __restrict__ Avz,
                                               const unsigned int* __restrict__ flag,
                                               const float* __restrict__ Wdt,
                                               const float* __restrict__ bdt,
                                               float* __restrict__ delta,
                                               float* __restrict__ P,
                                               float* __restrict__ S) {
  __shared__ __align__(16) float DtB[32][kCS];   // rows 0-15 dt, 16-31 B
  const int b = blockIdx.z, ch = blockIdx.y;
  const int t = threadIdx.x;
  const int d = blockIdx.x * 256 + t;
  const int l0 = ch * kCS;
  {
    int lane = t & 31, g = t >> 5;
#pragma unroll
    for (int r = 0; r < 4; ++r) {
      int row = r * 8 + g;
      DtB[row][lane] = dbc[((size_t)b * 48 + row) * kL + l0 + lane];
    }
  }
  __syncthreads();
  float Wr[16];
#pragma unroll
  for (int q = 0; q < 4; ++q) {
    float4 w4 = *(const float4*)(Wdt + d * 16 + q * 4);
    Wr[q * 4 + 0] = w4.x; Wr[q * 4 + 1] = w4.y; Wr[q * 4 + 2] = w4.z; Wr[q * 4 + 3] = w4.w;
  }
  const bool fast = (*flag != 0u);
  const float Av0 = Avz[d];
  const float bias = bdt[d];
  const unsigned short* pU = ucb + ((size_t)b * kL + l0) * kDI + d;
  float* pDel = delta + ((size_t)b * kL + l0) * kDI + d;
  size_t obase = (size_t)(b * kNC + ch) * (kN * kDI) + d;

  float Sv[16];
#pragma unroll
  for (int n = 0; n < kN; ++n) Sv[n] = 0.f;

  if (fast) {
    float sd = 0.f;
    for (int i = 0; i < kCS; i += 4) {
      float del[4] = {bias, bias, bias, bias};
#pragma unroll
      for (int r = 0; r < 16; ++r) {
        float4 v = *(const float4*)&DtB[r][i];
        del[0] += Wr[r] * v.x; del[1] += Wr[r] * v.y;
        del[2] += Wr[r] * v.z; del[3] += Wr[r] * v.w;
      }
      float du[4], E[4];
#pragma unroll
      for (int jj = 0; jj < 4; ++jj) {
        float xdl = softplusf(del[jj]);
        pDel[(size_t)(i + jj) * kDI] = xdl;
        du[jj] = xdl * bf2f(pU[(size_t)(i + jj) * kDI]);
        E[jj] = __expf(xdl * Av0);
        sd += xdl;
      }
      float a0 = E[0], a1 = E[1], a2 = E[2], a3 = E[3];
#pragma unroll
      for (int n = 0; n < kN; ++n) {
        float4 B4 = *(const float4*)&DtB[16 + n][i];
        Sv[n] = Sv[n] * a0 + du[0] * B4.x;
        Sv[n] = Sv[n] * a1 + du[1] * B4.y;
        Sv[n] = Sv[n] * a2 + du[2] * B4.z;
        Sv[n] = Sv[n] * a3 + du[3] * B4.w;
        if (n < kN - 1) { a0 *= E[0]; a1 *= E[1]; a2 *= E[2]; a3 *= E[3]; }
      }
    }
    float targ = sd * Av0, arg = targ;
#pragma unroll
    for (int n = 0; n < kN; ++n) {
      P[obase + (size_t)n * kDI] = __expf(arg);
      S[obase + (size_t)n * kDI] = Sv[n];
      arg += targ;
    }
  } else {
    float Av[16];
#pragma unroll
    for (int n = 0; n < kN; ++n) Av[n] = -__expf(A_log[d * kN + n]);
    float Pv[16];
#pragma unroll
    for (int n = 0; n < kN; ++n) Pv[n] = 1.f;
    for (int i = 0; i < kCS; i += 4) {
      float del[4] = {bias, bias, bias, bias};
#pragma unroll
      for (int r = 0; r < 16; ++r) {
        float4 v = *(const float4*)&DtB[r][i];
        del[0] += Wr[r] * v.x; del[1] += Wr[r] * v.y;
        del[2] += Wr[r] * v.z; del[3] += Wr[r] * v.w;
      }
      float du[4];
#pragma unroll
      for (int jj = 0; jj < 4; ++jj) {
        float xdl = softplusf(del[jj]);
        del[jj] = xdl;
        pDel[(size_t)(i + jj) * kDI] = xdl;
        du[jj] = xdl * bf2f(pU[(size_t)(i + jj) * kDI]);
      }
#pragma unroll
      for (int n = 0; n < kN; ++n) {
        float4 B4 = *(const float4*)&DtB[16 + n][i];
        float a;
        a = __expf(del[0] * Av[n]); Pv[n] *= a; Sv[n] = Sv[n] * a + du[0] * B4.x;
        a = __expf(del[1] * Av[n]); Pv[n] *= a; Sv[n] = Sv[n] * a + du[1] * B4.y;
        a = __expf(del[2] * Av[n]); Pv[n] *= a; Sv[n] = Sv[n] * a + du[2] * B4.z;
        a = __expf(del[3] * Av[n]); Pv[n] *= a; Sv[n] = Sv[n] * a + du[3] * B4.w;
      }
    }
#pragma unroll
    for (int n = 0; n < kN; ++n) {
      P[obase + (size_t)n * kDI] = Pv[n];
      S[obase + (size_t)n * kDI] = Sv[n];
    }
  }
}

// ---------------------------------------------------------------------------
// Scan phase B: combine chunk summaries -> per-chunk init states. 8-deep.
// ---------------------------------------------------------------------------
__global__ __launch_bounds__(256) void k_scanB(const float* __restrict__ P,
                                               const float* __restrict__ S,
                                               float* __restrict__ init) {
  int idx = blockIdx.x * 256 + threadIdx.x;  // b*8192 + n*512 + d
  int b = idx >> 13, nd = idx & 8191;
  size_t base = (size_t)b * kNC * 8192 + nd;
  float carry = 0.f;
  for (int c0 = 0; c0 < kNC; c0 += 8) {
    float p[8], s[8];
#pragma unroll
    for (int j = 0; j < 8; ++j) {
      size_t o = base + (size_t)(c0 + j) * 8192;
      p[j] = P[o]; s[j] = S[o];
    }
#pragma unroll
    for (int j = 0; j < 8; ++j) {
      init[base + (size_t)(c0 + j) * 8192] = carry;
      carry = p[j] * carry + s[j];
    }
  }
}

// ---------------------------------------------------------------------------
// Scan phase C (+gate): replay chunk using stored delta; y = sum_n s_n*C_n;
// g = (y + u*D)*silu(res) -> yt bf16.
// ---------------------------------------------------------------------------
__global__ __launch_bounds__(256) void k_scanC(const unsigned short* __restrict__ ucb,
                                               const float* __restrict__ delta,
                                               const float* __restrict__ dbc,
                                               const float* __restrict__ A_log,
                                               const float* __restrict__ Avz,
                                               const unsigned int* __restrict__ flag,
                                               const float* __restrict__ init,
                                               const unsigned short* __restrict__ resb,
                                               const float* __restrict__ Dp,
                                               unsigned short* __restrict__ yt) {
  __shared__ __align__(16) float BCs[32][kCS];  // 0-15 B, 16-31 C
  const int b = blockIdx.z, ch = blockIdx.y;
  const int t = threadIdx.x;
  const int d = blockIdx.x * 256 + t;
  const int l0 = ch * kCS;
  {
    int lane = t & 31, g = t >> 5;
#pragma unroll
    for (int r = 0; r < 4; ++r) {
      int row = r * 8 + g;
      BCs[row][lane] = dbc[((size_t)b * 48 + 16 + row) * kL + l0 + lane];
    }
  }
  __syncthreads();
  const bool fast = (*flag != 0u);
  const float Av0 = Avz[d];
  const float Dv = Dp[d];
  float s[16];
  {
    size_t base = (size_t)(b * kNC + ch) * (kN * kDI) + d;
#pragma unroll
    for (int n = 0; n < kN; ++n) s[n] = init[base + (size_t)n * kDI];
  }
  const unsigned short* pU = ucb + ((size_t)b * kL + l0) * kDI + d;
  const float* pDel = delta + ((size_t)b * kL + l0) * kDI + d;
  const unsigned short* pR = resb + ((size_t)b * kL + l0) * kDI + d;
  unsigned short* pY = yt + ((size_t)b * kL + l0) * kDI + d;

  if (fast) {
    for (int i = 0; i < kCS; i += 4) {
      float uv[4], du[4], E[4], yacc[4] = {0.f, 0.f, 0.f, 0.f};
#pragma unroll
      for (int jj = 0; jj < 4; ++jj) {
        float xdl = pDel[(size_t)(i + jj) * kDI];
        uv[jj] = bf2f(pU[(size_t)(i + jj) * kDI]);
        du[jj] = xdl * uv[jj];
        E[jj] = __expf(xdl * Av0);
      }
      float a0 = E[0], a1 = E[1], a2 = E[2], a3 = E[3];
#pragma unroll
      for (int n = 0; n < kN; ++n) {
        float4 B4 = *(const float4*)&BCs[n][i];
        float4 C4 = *(const float4*)&BCs[16 + n][i];
        s[n] = s[n] * a0 + du[0] * B4.x; yacc[0] += s[n] * C4.x;
        s[n] = s[n] * a1 + du[1] * B4.y; yacc[1] += s[n] * C4.y;
        s[n] = s[n] * a2 + du[2] * B4.z; yacc[2] += s[n] * C4.z;
        s[n] = s[n] * a3 + du[3] * B4.w; yacc[3] += s[n] * C4.w;
        if (n < kN - 1) { a0 *= E[0]; a1 *= E[1]; a2 *= E[2]; a3 *= E[3]; }
      }
#pragma unroll
      for (int jj = 0; jj < 4; ++jj) {
        float r = bf2f(pR[(size_t)(i + jj) * kDI]);
        float gv = (yacc[jj] + uv[jj] * Dv) * siluf(r);
        pY[(size_t)(i + jj) * kDI] = f2bf(gv);
      }
    }
  } else {
    float Av[16];
#pragma unroll
    for (int n = 0; n < kN; ++n) Av[n] = -__expf(A_log[d * kN + n]);
    for (int i = 0; i < kCS; i += 4) {
      float uv[4], du[4], del[4], yacc[4] = {0.f, 0.f, 0.f, 0.f};
#pragma unroll
      for (int jj = 0; jj < 4; ++jj) {
        del[jj] = pDel[(size_t)(i + jj) * kDI];
        uv[jj] = bf2f(pU[(size_t)(i + jj) * kDI]);
        du[jj] = del[jj] * uv[jj];
      }
#pragma unroll
      for (int n = 0; n < kN; ++n) {
        float4 B4 = *(const float4*)&BCs[n][i];
        float4 C4 = *(const float4*)&BCs[16 + n][i];
        float a;
        a = __expf(del[0] * Av[n]); s[n] = s[n] * a + du[0] * B4.x; yacc[0] += s[n] * C4.x;
        a = __expf(del[1] * Av[n]); s[n] = s[n] * a + du[1] * B4.y; yacc[1] += s[n] * C4.y;
        a = __expf(del[2] * Av[n]); s[n] = s[n] * a + du[2] * B4.z; yacc[2] += s[n] * C4.z;
        a = __expf(del[3] * Av[n]); s[n] = s[n] * a + du[3] * B4.w; yacc[3] += s[n] * C4.w;
      }
#pragma unroll
      for (int jj = 0; jj < 4; ++jj) {
        float r = bf2f(pR[(size_t)(i + jj) * kDI]);
        float gv = (yacc[jj] + uv[jj] * Dv) * siluf(r);
        pY[(size_t)(i + jj) * kDI] = f2bf(gv);
      }
    }
  }
}

// ---------------------------------------------------------------------------
// out_proj GEMM: out[b][c][l] = sum_k Wo[c,k] * yt[b,l,k].
// ---------------------------------------------------------------------------
__global__ __launch_bounds__(256) void gemm_out(const unsigned short* __restrict__ A,
                                                const unsigned short* __restrict__ Bt,
                                                float* __restrict__ C0) {
  __shared__ __align__(16) unsigned short As[128 * 64];
  __shared__ __align__(16) unsigned short Bs[128 * 64];
  const int n0 = blockIdx.x * 128;
  const int m0 = blockIdx.y * 128;
  const int b  = blockIdx.z;
  const int t  = threadIdx.x;
  const int wave = t >> 6, lane = t & 63;
  const int wm = wave >> 1, wn = wave & 1;
  const unsigned short* Bb = Bt + (size_t)b * kL * kDI;

  f32x4 acc[4][4];
#pragma unroll
  for (int i = 0; i < 4; ++i)
#pragma unroll
    for (int j = 0; j < 4; ++j) acc[i][j] = (f32x4)0.0f;

  const int srow = t >> 3, sch = t & 7;
  for (int kt = 0; kt < 8; ++kt) {
    const int k0 = kt * 64;
#pragma unroll
    for (int c = 0; c < 4; ++c) {
      int row = c * 32 + srow;
      int gch = sch ^ (row & 7);
      gload_lds16(A  + (size_t)(m0 + row) * kDI + k0 + gch * 8,
                  (char*)As + c * 4096 + wave * 1024);
      gload_lds16(Bb + (size_t)(n0 + row) * kDI + k0 + gch * 8,
                  (char*)Bs + c * 4096 + wave * 1024);
    }
    __syncthreads();
#pragma unroll
    for (int ks = 0; ks < 2; ++ks) {
      bf16x8 af[4], bfr[4];
#pragma unroll
      for (int f = 0; f < 4; ++f) {
        int ra = wm * 64 + f * 16 + (lane & 15);
        int ca = (ks * 4 + (lane >> 4)) ^ (ra & 7);
        af[f] = *(const bf16x8*)((const char*)As + ra * 128 + ca * 16);
        int rb = wn * 64 + f * 16 + (lane & 15);
        int cb = (ks * 4 + (lane >> 4)) ^ (rb & 7);
        bfr[f] = *(const bf16x8*)((const char*)Bs + rb * 128 + cb * 16);
      }
#pragma unroll
      for (int i = 0; i < 4; ++i)
#pragma unroll
        for (int j = 0; j < 4; ++j)
          acc[i][j] = __builtin_amdgcn_mfma_f32_16x16x32_bf16(af[i], bfr[j], acc[i][j], 0, 0, 0);
    }
    __syncthreads();
  }
#pragma unroll
  for (int i = 0; i < 4; ++i)
#pragma unroll
    for (int j = 0; j < 4; ++j)
#pragma unroll
      for (int r = 0; r < 4; ++r) {
        int m = m0 + wm * 64 + i * 16 + (lane >> 4) * 4 + r;
        int n = n0 + wn * 64 + j * 16 + (lane & 15);
        C0[((size_t)b * kDim + m) * kL + n] = acc[i][j][r];
      }
}

// ---------------------------------------------------------------------------
extern "C" void kernel_launch(void* const* d_in, const int* in_sizes, int n_in,
                              void* d_out, int out_size, void* d_ws, size_t ws_size,
                              hipStream_t stream) {
  const float* x       = (const float*)d_in[0];
  const float* in_w    = (const float*)d_in[1];
  const float* conv_w  = (const float*)d_in[2];
  const float* conv_b  = (const float*)d_in[3];
  const float* xproj_w = (const float*)d_in[4];
  const float* dt_w    = (const float*)d_in[5];
  const float* dt_b    = (const float*)d_in[6];
  const float* A_log   = (const float*)d_in[7];
  const float* Dp      = (const float*)d_in[8];
  const float* out_w   = (const float*)d_in[9];
  float* out = (float*)d_out;

  // workspace layout (~114 MB)
  float* ws = (float*)d_ws;
  const size_t nBLD  = (size_t)kB * kL * kDI;                 // 8388608
  const size_t nPS   = (size_t)kB * kNC * kN * kDI;           // 4194304
  float* dbc    = ws;                                         // 786432 f
  float* Pb     = dbc + (size_t)kB * 48 * kL;                 // nPS
  float* Sb     = Pb + nPS;                                   // nPS
  float* initb  = Sb + nPS;                                   // nPS
  float* deltaf = initb + nPS;                                // nBLD f
  unsigned short* ubf  = (unsigned short*)(deltaf + nBLD);    // nBLD us
  unsigned short* ucb  = ubf + nBLD;
  unsigned short* resb = ucb + nBLD;
  unsigned short* wib  = resb + nBLD;                         // 262144
  unsigned short* wob  = wib + 262144;                        // 131072
  unsigned short* wxb  = wob + 131072;                        // 24576
  float* Avz           = (float*)(wxb + 24576);               // 512 f
  unsigned int* flag   = (unsigned int*)(Avz + 512);          // 1 u32
  unsigned short* xt   = (unsigned short*)initb;              // dead before scanB
  unsigned short* yt   = (unsigned short*)Pb;                 // P dead after scanB

  k_wcvt<<<dim3(1632), 256, 0, stream>>>(in_w, out_w, xproj_w, wib, wob, wxb, flag);
  k_aprep<<<dim3(2), 256, 0, stream>>>(A_log, Avz, flag);
  k_xt<<<dim3(kL / 64, kDim / 64, kB), 256, 0, stream>>>(x, xt);
  gemm_in_lm<<<dim3(8, kL / 128, kB), 256, 0, stream>>>(xt, wib, ubf, resb);
  k_conv<<<dim3((unsigned)(kB * kL * 64 / 256)), 256, 0, stream>>>(ubf, conv_w, conv_b, ucb);
  k_xproj<<<dim3(kL / 128, kB), 256, 0, stream>>>(wxb, ucb, dbc);
  k_scanA<<<dim3(2, kNC, kB), 256, 0, stream>>>(ucb, dbc, A_log, Avz, flag, dt_w, dt_b, deltaf, Pb, Sb);
  k_scanB<<<dim3(kB * kDI * kN / 256), 256, 0, stream>>>(Pb, Sb, initb);
  k_scanC<<<dim3(2, kNC, kB), 256, 0, stream>>>(ucb, deltaf, dbc, A_log, Avz, flag, initb, resb, Dp, yt);
  gemm_out<<<dim3(kL / 128, kDim / 128, kB), 256, 0, stream>>>(wob, yt, out);
}

// Round 8
// 164.149 us; speedup vs baseline: 4.1011x; 1.0057x over previous
//
#include <hip/hip_runtime.h>
#include <math.h>

// Mamba block forward, l-major activations [b, l, d].
// B=4, DIM=256, L=4096, D_INNER=512, D_STATE=16, DT_RANK=16, D_CONV=4.
// in/out_proj + x_proj: bf16 MFMA. Scan: thread-per-d, 16 n-states in regs.
// R8: packed-f32 (v_pk_fma_f32) pairing of the scan n-loops and scanA's
// dt-GEMM -- n=2m in component .x, n=2m+1 in .y; power chain stepped by
// (E^2,E^2). Bit-identical math, half the VALU issue.

namespace {
constexpr int kB   = 4;
constexpr int kDim = 256;
constexpr int kL   = 4096;
constexpr int kDI  = 512;
constexpr int kN   = 16;
constexpr int kNC  = 128;  // scan chunks
constexpr int kCS  = 32;   // chunk size
} // namespace

typedef __attribute__((ext_vector_type(8))) short bf16x8;
typedef __attribute__((ext_vector_type(4))) float f32x4;
typedef __attribute__((ext_vector_type(2))) float f32x2;

__device__ __forceinline__ float rcpf(float x) { return __builtin_amdgcn_rcpf(x); }
__device__ __forceinline__ float siluf(float x) { return x * rcpf(1.f + __expf(-x)); }
__device__ __forceinline__ float softplusf(float x) {
  return fmaxf(x, 0.f) + __logf(1.f + __expf(-fabsf(x)));
}

__device__ __forceinline__ unsigned short f2bf(float x) {
  union { float f; unsigned int u; } v; v.f = x;
  unsigned int u = v.u;
  u += 0x7fffu + ((u >> 16) & 1u);   // RNE
  return (unsigned short)(u >> 16);
}
__device__ __forceinline__ float bf2f(unsigned short u) {
  union { unsigned int i; float f; } v; v.i = ((unsigned int)u) << 16; return v.f;
}

__device__ __forceinline__ void gload_lds16(const void* g, void* l) {
  __builtin_amdgcn_global_load_lds(
      (const __attribute__((address_space(1))) unsigned int*)g,
      (__attribute__((address_space(3))) unsigned int*)l, 16, 0, 0);
}

// ---------------------------------------------------------------------------
// Convert weights to bf16; thread (0,0) also initializes the fast-path flag.
// ---------------------------------------------------------------------------
__global__ __launch_bounds__(256) void k_wcvt(const float* __restrict__ w_in,
                                              const float* __restrict__ w_out,
                                              const float* __restrict__ w_x,
                                              unsigned short* __restrict__ wib,
                                              unsigned short* __restrict__ wob,
                                              unsigned short* __restrict__ wxb,
                                              unsigned int* __restrict__ flag) {
  int idx = blockIdx.x * 256 + threadIdx.x;
  if (idx == 0) *flag = 0xFFFFFFFFu;
  if (idx < 262144) wib[idx] = f2bf(w_in[idx]);
  else if (idx < 262144 + 131072) wob[idx - 262144] = f2bf(w_out[idx - 262144]);
  else if (idx < 262144 + 131072 + 24576) wxb[idx - 393216] = f2bf(w_x[idx - 393216]);
}

// ---------------------------------------------------------------------------
// A-structure prep: Av0[d] = -exp(A_log[d,0]); fast flag &= (Av[n]==(n+1)Av0).
// ---------------------------------------------------------------------------
__global__ __launch_bounds__(256) void k_aprep(const float* __restrict__ A_log,
                                               float* __restrict__ Avz,
                                               unsigned int* __restrict__ flag) {
  int d = blockIdx.x * 256 + threadIdx.x;
  float a0 = -__expf(A_log[d * kN]);
  bool ok = true;
#pragma unroll
  for (int n = 1; n < kN; ++n) {
    float av = -__expf(A_log[d * kN + n]);
    ok = ok && (fabsf(av - (n + 1) * a0) <= 1e-5f * fabsf(av));
  }
  Avz[d] = a0;
  if (!ok) atomicAnd(flag, 0u);
}

// ---------------------------------------------------------------------------
// Transpose-convert x [b, d, l] f32 -> xt [b, l, d] bf16.
// ---------------------------------------------------------------------------
__global__ __launch_bounds__(256) void k_xt(const float* __restrict__ x,
                                            unsigned short* __restrict__ xt) {
  __shared__ float Xs[64][65];
  const int b = blockIdx.z, d0 = blockIdx.y * 64, l0 = blockIdx.x * 64;
  const int t = threadIdx.x, l = t & 63;
#pragma unroll
  for (int rep = 0; rep < 16; ++rep) {
    int dd = rep * 4 + (t >> 6);
    Xs[dd][l] = x[((size_t)b * kDim + d0 + dd) * kL + l0 + l];
  }
  __syncthreads();
#pragma unroll
  for (int rep = 0; rep < 8; ++rep) {
    int lj = rep * 8 + (t >> 5);
    int di = (t & 31) * 2;
    ushort2 v;
    v.x = f2bf(Xs[di][lj]);
    v.y = f2bf(Xs[di + 1][lj]);
    *(ushort2*)(xt + ((size_t)b * kL + l0 + lj) * kDim + d0 + di) = v;
  }
}

// ---------------------------------------------------------------------------
// in_proj GEMM, l-major bf16 output: C[b][l][e] = sum_k xt[b,l,k] * W[e,k].
// ---------------------------------------------------------------------------
__global__ __launch_bounds__(256) void gemm_in_lm(const unsigned short* __restrict__ xt,
                                                  const unsigned short* __restrict__ W,
                                                  unsigned short* __restrict__ ubf,
                                                  unsigned short* __restrict__ resb) {
  __shared__ __align__(16) unsigned short As[128 * 64];
  __shared__ __align__(16) unsigned short Bs[128 * 64];
  const int e0 = blockIdx.x * 128;
  const int l0 = blockIdx.y * 128;
  const int b  = blockIdx.z;
  const int t  = threadIdx.x;
  const int wave = t >> 6, lane = t & 63;
  const int wm = wave >> 1, wn = wave & 1;
  const unsigned short* Ab = xt + (size_t)b * kL * kDim;

  f32x4 acc[4][4];
#pragma unroll
  for (int i = 0; i < 4; ++i)
#pragma unroll
    for (int j = 0; j < 4; ++j) acc[i][j] = (f32x4)0.0f;

  const int srow = t >> 3, sch = t & 7;
  for (int kt = 0; kt < 4; ++kt) {
    const int k0 = kt * 64;
#pragma unroll
    for (int c = 0; c < 4; ++c) {
      int row = c * 32 + srow;
      int gch = sch ^ (row & 7);
      gload_lds16(Ab + (size_t)(l0 + row) * kDim + k0 + gch * 8,
                  (char*)As + c * 4096 + wave * 1024);
      gload_lds16(W  + (size_t)(e0 + row) * kDim + k0 + gch * 8,
                  (char*)Bs + c * 4096 + wave * 1024);
    }
    __syncthreads();
#pragma unroll
    for (int ks = 0; ks < 2; ++ks) {
      bf16x8 af[4], bfr[4];
#pragma unroll
      for (int f = 0; f < 4; ++f) {
        int ra = wm * 64 + f * 16 + (lane & 15);
        int ca = (ks * 4 + (lane >> 4)) ^ (ra & 7);
        af[f] = *(const bf16x8*)((const char*)As + ra * 128 + ca * 16);
        int rb = wn * 64 + f * 16 + (lane & 15);
        int cb = (ks * 4 + (lane >> 4)) ^ (rb & 7);
        bfr[f] = *(const bf16x8*)((const char*)Bs + rb * 128 + cb * 16);
      }
#pragma unroll
      for (int i = 0; i < 4; ++i)
#pragma unroll
        for (int j = 0; j < 4; ++j)
          acc[i][j] = __builtin_amdgcn_mfma_f32_16x16x32_bf16(af[i], bfr[j], acc[i][j], 0, 0, 0);
    }
    __syncthreads();
  }

  const bool is_u = (e0 < kDI);
  unsigned short* dst = is_u ? ubf : resb;
  const int ebase = is_u ? e0 : (e0 - kDI);
#pragma unroll
  for (int i = 0; i < 4; ++i)
#pragma unroll
    for (int j = 0; j < 4; ++j)
#pragma unroll
      for (int r = 0; r < 4; ++r) {
        int l = l0 + wm * 64 + i * 16 + (lane >> 4) * 4 + r;
        int e = ebase + wn * 64 + j * 16 + (lane & 15);
        dst[((size_t)b * kL + l) * kDI + e] = f2bf(acc[i][j][r]);
      }
}

// ---------------------------------------------------------------------------
// Causal depthwise conv k=4 + bias + SiLU, l-major, bf16 in/out, 8 d/thread.
// ---------------------------------------------------------------------------
__global__ __launch_bounds__(256) void k_conv(const unsigned short* __restrict__ ubf,
                                              const float* __restrict__ cw,
                                              const float* __restrict__ cb,
                                              unsigned short* __restrict__ ucb) {
  int idx = blockIdx.x * 256 + threadIdx.x;   // over B*L*64
  int d8 = idx & 63;
  int l  = (idx >> 6) & (kL - 1);
  int b  = idx >> 18;
  int d0 = d8 * 8;
  const unsigned short* row = ubf + ((size_t)b * kL + l) * kDI + d0;
  uint4 zero = make_uint4(0, 0, 0, 0);
  uint4 c0 = *(const uint4*)row;
  uint4 c1 = (l >= 1) ? *(const uint4*)(row - kDI)     : zero;
  uint4 c2 = (l >= 2) ? *(const uint4*)(row - 2 * kDI) : zero;
  uint4 c3 = (l >= 3) ? *(const uint4*)(row - 3 * kDI) : zero;
  const unsigned int* p0 = (const unsigned int*)&c0;
  const unsigned int* p1 = (const unsigned int*)&c1;
  const unsigned int* p2 = (const unsigned int*)&c2;
  const unsigned int* p3 = (const unsigned int*)&c3;
  unsigned short ov[8];
#pragma unroll
  for (int c = 0; c < 8; ++c) {
    int q = c >> 1, hi = c & 1;
    float u0 = bf2f((unsigned short)(hi ? (p0[q] >> 16) : (p0[q] & 0xffff)));
    float u1 = bf2f((unsigned short)(hi ? (p1[q] >> 16) : (p1[q] & 0xffff)));
    float u2 = bf2f((unsigned short)(hi ? (p2[q] >> 16) : (p2[q] & 0xffff)));
    float u3 = bf2f((unsigned short)(hi ? (p3[q] >> 16) : (p3[q] & 0xffff)));
    float4 w = *(const float4*)(cw + (d0 + c) * 4);
    float acc = cb[d0 + c] + w.x * u3 + w.y * u2 + w.z * u1 + w.w * u0;
    ov[c] = f2bf(siluf(acc));
  }
  *(uint4*)(ucb + ((size_t)b * kL + l) * kDI + d0) = *(const uint4*)ov;
}

// ---------------------------------------------------------------------------
// x_proj MFMA: dbc[b][m][l] = sum_k Wx[m,k] * ucb[b,l,k], m in [0,48), K=512.
// ---------------------------------------------------------------------------
__global__ __launch_bounds__(256) void k_xproj(const unsigned short* __restrict__ Wx,
                                               const unsigned short* __restrict__ ucb,
                                               float* __restrict__ dbc) {
  __shared__ __align__(16) unsigned short As[64 * 64];
  __shared__ __align__(16) unsigned short Bs[128 * 64];
  const int l0 = blockIdx.x * 128;
  const int b  = blockIdx.y;
  const int t  = threadIdx.x;
  const int wave = t >> 6, lane = t & 63;
  const unsigned short* Bb = ucb + (size_t)b * kL * kDI;

  f32x4 acc[3][2];
#pragma unroll
  for (int i = 0; i < 3; ++i)
#pragma unroll
    for (int j = 0; j < 2; ++j) acc[i][j] = (f32x4)0.0f;

  const int srow = t >> 3, sch = t & 7;
  for (int kt = 0; kt < 8; ++kt) {
    const int k0 = kt * 64;
#pragma unroll
    for (int c = 0; c < 2; ++c) {
      int row = c * 32 + srow;
      int grow = row < 48 ? row : 47;
      int gch = sch ^ (row & 7);
      gload_lds16(Wx + (size_t)grow * kDI + k0 + gch * 8,
                  (char*)As + c * 4096 + wave * 1024);
    }
#pragma unroll
    for (int c = 0; c < 4; ++c) {
      int row = c * 32 + srow;
      int gch = sch ^ (row & 7);
      gload_lds16(Bb + (size_t)(l0 + row) * kDI + k0 + gch * 8,
                  (char*)Bs + c * 4096 + wave * 1024);
    }
    __syncthreads();
#pragma unroll
    for (int ks = 0; ks < 2; ++ks) {
      bf16x8 af[3], bfr[2];
#pragma unroll
      for (int f = 0; f < 3; ++f) {
        int ra = f * 16 + (lane & 15);
        int ca = (ks * 4 + (lane >> 4)) ^ (ra & 7);
        af[f] = *(const bf16x8*)((const char*)As + ra * 128 + ca * 16);
      }
#pragma unroll
      for (int f = 0; f < 2; ++f) {
        int rb = wave * 32 + f * 16 + (lane & 15);
        int cb = (ks * 4 + (lane >> 4)) ^ (rb & 7);
        bfr[f] = *(const bf16x8*)((const char*)Bs + rb * 128 + cb * 16);
      }
#pragma unroll
      for (int i = 0; i < 3; ++i)
#pragma unroll
        for (int j = 0; j < 2; ++j)
          acc[i][j] = __builtin_amdgcn_mfma_f32_16x16x32_bf16(af[i], bfr[j], acc[i][j], 0, 0, 0);
    }
    __syncthreads();
  }
#pragma unroll
  for (int i = 0; i < 3; ++i)
#pragma unroll
    for (int j = 0; j < 2; ++j)
#pragma unroll
      for (int r = 0; r < 4; ++r) {
        int m = i * 16 + (lane >> 4) * 4 + r;
        int l = l0 + wave * 32 + j * 16 + (lane & 15);
        dbc[((size_t)b * 48 + m) * kL + l] = acc[i][j][r];
      }
}

// ---------------------------------------------------------------------------
// Scan phase A (fused dt_proj+softplus): thread owns d. Packed-f32 n-loop.
// ---------------------------------------------------------------------------
__global__ __launch_bounds__(256) void k_scanA(const unsigned short* __restrict__ ucb,
                                               const float* __restrict__ dbc,
                                               const float* __restrict__ A_log,
                                               const float* __restrict__ Avz,
                                               const unsigned int* __restrict__ flag,
                                               const float* __restrict__ Wdt,
                                               const float* __restrict__ bdt,
                                               float* __restrict__ delta,
                                               float* __restrict__ P,
                                               float* __restrict__ S) {
  __shared__ __align__(16) float DtB[32][kCS];   // rows 0-15 dt, 16-31 B
  const int b = blockIdx.z, ch = blockIdx.y;
  const int t = threadIdx.x;
  const int d = blockIdx.x * 256 + t;
  const int l0 = ch * kCS;
  {
    int lane = t & 31, g = t >> 5;
#pragma unroll
    for (int r = 0; r < 4; ++r) {
      int row = r * 8 + g;
      DtB[row][lane] = dbc[((size_t)b * 48 + row) * kL + l0 + lane];
    }
  }
  __syncthreads();
  float Wr[16];
#pragma unroll
  for (int q = 0; q < 4; ++q) {
    float4 w4 = *(const float4*)(Wdt + d * 16 + q * 4);
    Wr[q * 4 + 0] = w4.x; Wr[q * 4 + 1] = w4.y; Wr[q * 4 + 2] = w4.z; Wr[q * 4 + 3] = w4.w;
  }
  const bool fast = (*flag != 0u);
  const float Av0 = Avz[d];
  const float bias = bdt[d];
  const unsigned short* pU = ucb + ((size_t)b * kL + l0) * kDI + d;
  float* pDel = delta + ((size_t)b * kL + l0) * kDI + d;
  size_t obase = (size_t)(b * kNC + ch) * (kN * kDI) + d;

  if (fast) {
    f32x2 Sv2[8];
#pragma unroll
    for (int m = 0; m < 8; ++m) Sv2[m] = (f32x2){0.f, 0.f};
    float sd = 0.f;
    for (int i = 0; i < kCS; i += 4) {
      // dt-GEMM, paired over l (bit-identical per component)
      f32x2 d01 = {bias, bias}, d23 = {bias, bias};
#pragma unroll
      for (int r = 0; r < 16; ++r) {
        float4 v = *(const float4*)&DtB[r][i];
        f32x2 w2 = {Wr[r], Wr[r]};
        d01 = d01 + w2 * (f32x2){v.x, v.y};
        d23 = d23 + w2 * (f32x2){v.z, v.w};
      }
      float del[4] = {d01.x, d01.y, d23.x, d23.y};
      f32x2 a2[4], e2[4], du2[4];
#pragma unroll
      for (int jj = 0; jj < 4; ++jj) {
        float xdl = softplusf(del[jj]);
        pDel[(size_t)(i + jj) * kDI] = xdl;
        float duv = xdl * bf2f(pU[(size_t)(i + jj) * kDI]);
        du2[jj] = (f32x2){duv, duv};
        float E = __expf(xdl * Av0);
        float Esq = E * E;
        a2[jj] = (f32x2){E, Esq};
        e2[jj] = (f32x2){Esq, Esq};
        sd += xdl;
      }
#pragma unroll
      for (int m = 0; m < 8; ++m) {
        float4 Ba = *(const float4*)&DtB[16 + 2 * m][i];
        float4 Bb = *(const float4*)&DtB[16 + 2 * m + 1][i];
        Sv2[m] = Sv2[m] * a2[0] + du2[0] * (f32x2){Ba.x, Bb.x};
        Sv2[m] = Sv2[m] * a2[1] + du2[1] * (f32x2){Ba.y, Bb.y};
        Sv2[m] = Sv2[m] * a2[2] + du2[2] * (f32x2){Ba.z, Bb.z};
        Sv2[m] = Sv2[m] * a2[3] + du2[3] * (f32x2){Ba.w, Bb.w};
        if (m < 7) {
          a2[0] *= e2[0]; a2[1] *= e2[1]; a2[2] *= e2[2]; a2[3] *= e2[3];
        }
      }
    }
    float targ = sd * Av0, arg = targ;
#pragma unroll
    for (int n = 0; n < kN; ++n) {
      P[obase + (size_t)n * kDI] = __expf(arg);
      S[obase + (size_t)n * kDI] = (n & 1) ? Sv2[n >> 1].y : Sv2[n >> 1].x;
      arg += targ;
    }
  } else {
    float Av[16];
#pragma unroll
    for (int n = 0; n < kN; ++n) Av[n] = -__expf(A_log[d * kN + n]);
    float Pv[16], Sv[16];
#pragma unroll
    for (int n = 0; n < kN; ++n) { Pv[n] = 1.f; Sv[n] = 0.f; }
    for (int i = 0; i < kCS; i += 4) {
      float del[4] = {bias, bias, bias, bias};
#pragma unroll
      for (int r = 0; r < 16; ++r) {
        float4 v = *(const float4*)&DtB[r][i];
        del[0] += Wr[r] * v.x; del[1] += Wr[r] * v.y;
        del[2] += Wr[r] * v.z; del[3] += Wr[r] * v.w;
      }
      float du[4];
#pragma unroll
      for (int jj = 0; jj < 4; ++jj) {
        float xdl = softplusf(del[jj]);
        del[jj] = xdl;
        pDel[(size_t)(i + jj) * kDI] = xdl;
        du[jj] = xdl * bf2f(pU[(size_t)(i + jj) * kDI]);
      }
#pragma unroll
      for (int n = 0; n < kN; ++n) {
        float4 B4 = *(const float4*)&DtB[16 + n][i];
        float a;
        a = __expf(del[0] * Av[n]); Pv[n] *= a; Sv[n] = Sv[n] * a + du[0] * B4.x;
        a = __expf(del[1] * Av[n]); Pv[n] *= a; Sv[n] = Sv[n] * a + du[1] * B4.y;
        a = __expf(del[2] * Av[n]); Pv[n] *= a; Sv[n] = Sv[n] * a + du[2] * B4.z;
        a = __expf(del[3] * Av[n]); Pv[n] *= a; Sv[n] = Sv[n] * a + du[3] * B4.w;
      }
    }
#pragma unroll
    for (int n = 0; n < kN; ++n) {
      P[obase + (size_t)n * kDI] = Pv[n];
      S[obase + (size_t)n * kDI] = Sv[n];
    }
  }
}

// ---------------------------------------------------------------------------
// Scan phase B: combine chunk summaries -> per-chunk init states. 8-deep.
// ---------------------------------------------------------------------------
__global__ __launch_bounds__(256) void k_scanB(const float* __restrict__ P,
                                               const float* __restrict__ S,
                                               float* __restrict__ init) {
  int idx = blockIdx.x * 256 + threadIdx.x;  // b*8192 + n*512 + d
  int b = idx >> 13, nd = idx & 8191;
  size_t base = (size_t)b * kNC * 8192 + nd;
  float carry = 0.f;
  for (int c0 = 0; c0 < kNC; c0 += 8) {
    float p[8], s[8];
#pragma unroll
    for (int j = 0; j < 8; ++j) {
      size_t o = base + (size_t)(c0 + j) * 8192;
      p[j] = P[o]; s[j] = S[o];
    }
#pragma unroll
    for (int j = 0; j < 8; ++j) {
      init[base + (size_t)(c0 + j) * 8192] = carry;
      carry = p[j] * carry + s[j];
    }
  }
}

// ---------------------------------------------------------------------------
// Scan phase C (+gate): replay chunk using stored delta. Packed-f32 n-loop.
// ---------------------------------------------------------------------------
__global__ __launch_bounds__(256) void k_scanC(const unsigned short* __restrict__ ucb,
                                               const float* __restrict__ delta,
                                               const float* __restrict__ dbc,
                                               const float* __restrict__ A_log,
                                               const float* __restrict__ Avz,
                                               const unsigned int* __restrict__ flag,
                                               const float* __restrict__ init,
                                               const unsigned short* __restrict__ resb,
                                               const float* __restrict__ Dp,
                                               unsigned short* __restrict__ yt) {
  __shared__ __align__(16) float BCs[32][kCS];  // 0-15 B, 16-31 C
  const int b = blockIdx.z, ch = blockIdx.y;
  const int t = threadIdx.x;
  const int d = blockIdx.x * 256 + t;
  const int l0 = ch * kCS;
  {
    int lane = t & 31, g = t >> 5;
#pragma unroll
    for (int r = 0; r < 4; ++r) {
      int row = r * 8 + g;
      BCs[row][lane] = dbc[((size_t)b * 48 + 16 + row) * kL + l0 + lane];
    }
  }
  __syncthreads();
  const bool fast = (*flag != 0u);
  const float Av0 = Avz[d];
  const float Dv = Dp[d];
  const unsigned short* pU = ucb + ((size_t)b * kL + l0) * kDI + d;
  const float* pDel = delta + ((size_t)b * kL + l0) * kDI + d;
  const unsigned short* pR = resb + ((size_t)b * kL + l0) * kDI + d;
  unsigned short* pY = yt + ((size_t)b * kL + l0) * kDI + d;
  size_t ibase = (size_t)(b * kNC + ch) * (kN * kDI) + d;

  if (fast) {
    f32x2 s2[8];
#pragma unroll
    for (int m = 0; m < 8; ++m)
      s2[m] = (f32x2){init[ibase + (size_t)(2 * m) * kDI],
                      init[ibase + (size_t)(2 * m + 1) * kDI]};
    for (int i = 0; i < kCS; i += 4) {
      float uv[4];
      f32x2 a2[4], e2[4], du2[4], yacc2[4];
#pragma unroll
      for (int jj = 0; jj < 4; ++jj) {
        float xdl = pDel[(size_t)(i + jj) * kDI];
        uv[jj] = bf2f(pU[(size_t)(i + jj) * kDI]);
        float duv = xdl * uv[jj];
        du2[jj] = (f32x2){duv, duv};
        float E = __expf(xdl * Av0);
        float Esq = E * E;
        a2[jj] = (f32x2){E, Esq};
        e2[jj] = (f32x2){Esq, Esq};
        yacc2[jj] = (f32x2){0.f, 0.f};
      }
#pragma unroll
      for (int m = 0; m < 8; ++m) {
        float4 Ba = *(const float4*)&BCs[2 * m][i];
        float4 Bb = *(const float4*)&BCs[2 * m + 1][i];
        float4 Ca = *(const float4*)&BCs[16 + 2 * m][i];
        float4 Cb = *(const float4*)&BCs[16 + 2 * m + 1][i];
        s2[m] = s2[m] * a2[0] + du2[0] * (f32x2){Ba.x, Bb.x};
        yacc2[0] = yacc2[0] + s2[m] * (f32x2){Ca.x, Cb.x};
        s2[m] = s2[m] * a2[1] + du2[1] * (f32x2){Ba.y, Bb.y};
        yacc2[1] = yacc2[1] + s2[m] * (f32x2){Ca.y, Cb.y};
        s2[m] = s2[m] * a2[2] + du2[2] * (f32x2){Ba.z, Bb.z};
        yacc2[2] = yacc2[2] + s2[m] * (f32x2){Ca.z, Cb.z};
        s2[m] = s2[m] * a2[3] + du2[3] * (f32x2){Ba.w, Bb.w};
        yacc2[3] = yacc2[3] + s2[m] * (f32x2){Ca.w, Cb.w};
        if (m < 7) {
          a2[0] *= e2[0]; a2[1] *= e2[1]; a2[2] *= e2[2]; a2[3] *= e2[3];
        }
      }
#pragma unroll
      for (int jj = 0; jj < 4; ++jj) {
        float yv = yacc2[jj].x + yacc2[jj].y;
        float r = bf2f(pR[(size_t)(i + jj) * kDI]);
        float gv = (yv + uv[jj] * Dv) * siluf(r);
        pY[(size_t)(i + jj) * kDI] = f2bf(gv);
      }
    }
  } else {
    float Av[16];
#pragma unroll
    for (int n = 0; n < kN; ++n) Av[n] = -__expf(A_log[d * kN + n]);
    float s[16];
#pragma unroll
    for (int n = 0; n < kN; ++n) s[n] = init[ibase + (size_t)n * kDI];
    for (int i = 0; i < kCS; i += 4) {
      float uv[4], du[4], del[4], yacc[4] = {0.f, 0.f, 0.f, 0.f};
#pragma unroll
      for (int jj = 0; jj < 4; ++jj) {
        del[jj] = pDel[(size_t)(i + jj) * kDI];
        uv[jj] = bf2f(pU[(size_t)(i + jj) * kDI]);
        du[jj] = del[jj] * uv[jj];
      }
#pragma unroll
      for (int n = 0; n < kN; ++n) {
        float4 B4 = *(const float4*)&BCs[n][i];
        float4 C4 = *(const float4*)&BCs[16 + n][i];
        float a;
        a = __expf(del[0] * Av[n]); s[n] = s[n] * a + du[0] * B4.x; yacc[0] += s[n] * C4.x;
        a = __expf(del[1] * Av[n]); s[n] = s[n] * a + du[1] * B4.y; yacc[1] += s[n] * C4.y;
        a = __expf(del[2] * Av[n]); s[n] = s[n] * a + du[2] * B4.z; yacc[2] += s[n] * C4.z;
        a = __expf(del[3] * Av[n]); s[n] = s[n] * a + du[3] * B4.w; yacc[3] += s[n] * C4.w;
      }
#pragma unroll
      for (int jj = 0; jj < 4; ++jj) {
        float r = bf2f(pR[(size_t)(i + jj) * kDI]);
        float gv = (yacc[jj] + uv[jj] * Dv) * siluf(r);
        pY[(size_t)(i + jj) * kDI] = f2bf(gv);
      }
    }
  }
}

// ---------------------------------------------------------------------------
// out_proj GEMM: out[b][c][l] = sum_k Wo[c,k] * yt[b,l,k].
// ---------------------------------------------------------------------------
__global__ __launch_bounds__(256) void gemm_out(const unsigned short* __restrict__ A,
                                                const unsigned short* __restrict__ Bt,
                                                float* __restrict__ C0) {
  __shared__ __align__(16) unsigned short As[128 * 64];
  __shared__ __align__(16) unsigned short Bs[128 * 64];
  const int n0 = blockIdx.x * 128;
  const int m0 = blockIdx.y * 128;
  const int b  = blockIdx.z;
  const int t  = threadIdx.x;
  const int wave = t >> 6, lane = t & 63;
  const int wm = wave >> 1, wn = wave & 1;
  const unsigned short* Bb = Bt + (size_t)b * kL * kDI;

  f32x4 acc[4][4];
#pragma unroll
  for (int i = 0; i < 4; ++i)
#pragma unroll
    for (int j = 0; j < 4; ++j) acc[i][j] = (f32x4)0.0f;

  const int srow = t >> 3, sch = t & 7;
  for (int kt = 0; kt < 8; ++kt) {
    const int k0 = kt * 64;
#pragma unroll
    for (int c = 0; c < 4; ++c) {
      int row = c * 32 + srow;
      int gch = sch ^ (row & 7);
      gload_lds16(A  + (size_t)(m0 + row) * kDI + k0 + gch * 8,
                  (char*)As + c * 4096 + wave * 1024);
      gload_lds16(Bb + (size_t)(n0 + row) * kDI + k0 + gch * 8,
                  (char*)Bs + c * 4096 + wave * 1024);
    }
    __syncthreads();
#pragma unroll
    for (int ks = 0; ks < 2; ++ks) {
      bf16x8 af[4], bfr[4];
#pragma unroll
      for (int f = 0; f < 4; ++f) {
        int ra = wm * 64 + f * 16 + (lane & 15);
        int ca = (ks * 4 + (lane >> 4)) ^ (ra & 7);
        af[f] = *(const bf16x8*)((const char*)As + ra * 128 + ca * 16);
        int rb = wn * 64 + f * 16 + (lane & 15);
        int cb = (ks * 4 + (lane >> 4)) ^ (rb & 7);
        bfr[f] = *(const bf16x8*)((const char*)Bs + rb * 128 + cb * 16);
      }
#pragma unroll
      for (int i = 0; i < 4; ++i)
#pragma unroll
        for (int j = 0; j < 4; ++j)
          acc[i][j] = __builtin_amdgcn_mfma_f32_16x16x32_bf16(af[i], bfr[j], acc[i][j], 0, 0, 0);
    }
    __syncthreads();
  }
#pragma unroll
  for (int i = 0; i < 4; ++i)
#pragma unroll
    for (int j = 0; j < 4; ++j)
#pragma unroll
      for (int r = 0; r < 4; ++r) {
        int m = m0 + wm * 64 + i * 16 + (lane >> 4) * 4 + r;
        int n = n0 + wn * 64 + j * 16 + (lane & 15);
        C0[((size_t)b * kDim + m) * kL + n] = acc[i][j][r];
      }
}

// ---------------------------------------------------------------------------
extern "C" void kernel_launch(void* const* d_in, const int* in_sizes, int n_in,
                              void* d_out, int out_size, void* d_ws, size_t ws_size,
                              hipStream_t stream) {
  const float* x       = (const float*)d_in[0];
  const float* in_w    = (const float*)d_in[1];
  const float* conv_w  = (const float*)d_in[2];
  const float* conv_b  = (const float*)d_in[3];
  const float* xproj_w = (const float*)d_in[4];
  const float* dt_w    = (const float*)d_in[5];
  const float* dt_b    = (const float*)d_in[6];
  const float* A_log   = (const float*)d_in[7];
  const float* Dp      = (const float*)d_in[8];
  const float* out_w   = (const float*)d_in[9];
  float* out = (float*)d_out;

  // workspace layout (~114 MB)
  float* ws = (float*)d_ws;
  const size_t nBLD  = (size_t)kB * kL * kDI;                 // 8388608
  const size_t nPS   = (size_t)kB * kNC * kN * kDI;           // 4194304
  float* dbc    = ws;                                         // 786432 f
  float* Pb     = dbc + (size_t)kB * 48 * kL;                 // nPS
  float* Sb     = Pb + nPS;                                   // nPS
  float* initb  = Sb + nPS;                                   // nPS
  float* deltaf = initb + nPS;                                // nBLD f
  unsigned short* ubf  = (unsigned short*)(deltaf + nBLD);    // nBLD us
  unsigned short* ucb  = ubf + nBLD;
  unsigned short* resb = ucb + nBLD;
  unsigned short* wib  = resb + nBLD;                         // 262144
  unsigned short* wob  = wib + 262144;                        // 131072
  unsigned short* wxb  = wob + 131072;                        // 24576
  float* Avz           = (float*)(wxb + 24576);               // 512 f
  unsigned int* flag   = (unsigned int*)(Avz + 512);          // 1 u32
  unsigned short* xt   = (unsigned short*)initb;              // dead before scanB
  unsigned short* yt   = (unsigned short*)Pb;                 // P dead after scanB

  k_wcvt<<<dim3(1632), 256, 0, stream>>>(in_w, out_w, xproj_w, wib, wob, wxb, flag);
  k_aprep<<<dim3(2), 256, 0, stream>>>(A_log, Avz, flag);
  k_xt<<<dim3(kL / 64, kDim / 64, kB), 256, 0, stream>>>(x, xt);
  gemm_in_lm<<<dim3(8, kL / 128, kB), 256, 0, stream>>>(xt, wib, ubf, resb);
  k_conv<<<dim3((unsigned)(kB * kL * 64 / 256)), 256, 0, stream>>>(ubf, conv_w, conv_b, ucb);
  k_xproj<<<dim3(kL / 128, kB), 256, 0, stream>>>(wxb, ucb, dbc);
  k_scanA<<<dim3(2, kNC, kB), 256, 0, stream>>>(ucb, dbc, A_log, Avz, flag, dt_w, dt_b, deltaf, Pb, Sb);
  k_scanB<<<dim3(kB * kDI * kN / 256), 256, 0, stream>>>(Pb, Sb, initb);
  k_scanC<<<dim3(2, kNC, kB), 256, 0, stream>>>(ucb, deltaf, dbc, A_log, Avz, flag, initb, resb, Dp, yt);
  gemm_out<<<dim3(kL / 128, kDim / 128, kB), 256, 0, stream>>>(wob, yt, out);
}

// Round 9
// 162.636 us; speedup vs baseline: 4.1392x; 1.0093x over previous
//
#include <hip/hip_runtime.h>
#include <math.h>

// Mamba block forward, l-major activations [b, l, d].
// B=4, DIM=256, L=4096, D_INNER=512, D_STATE=16, DT_RANK=16, D_CONV=4.
// R9: dt_proj+softplus+exp hoisted into gemm_dt (MFMA, K=16 padded):
// stores E=exp(delta*Av0) f32 + du=delta*u bf16. Scan phases have zero
// transcendentals: load E/du streams, power-chain muls, packed n-loops.
// P = (prod E)^(n+1). Fallback (!fast): E-buffer holds delta, generic paths.

namespace {
constexpr int kB   = 4;
constexpr int kDim = 256;
constexpr int kL   = 4096;
constexpr int kDI  = 512;
constexpr int kN   = 16;
constexpr int kNC  = 128;  // scan chunks
constexpr int kCS  = 32;   // chunk size
} // namespace

typedef __attribute__((ext_vector_type(8))) short bf16x8;
typedef __attribute__((ext_vector_type(4))) float f32x4;
typedef __attribute__((ext_vector_type(2))) float f32x2;

__device__ __forceinline__ float rcpf(float x) { return __builtin_amdgcn_rcpf(x); }
__device__ __forceinline__ float siluf(float x) { return x * rcpf(1.f + __expf(-x)); }
__device__ __forceinline__ float softplusf(float x) {
  return fmaxf(x, 0.f) + __logf(1.f + __expf(-fabsf(x)));
}

__device__ __forceinline__ unsigned short f2bf(float x) {
  union { float f; unsigned int u; } v; v.f = x;
  unsigned int u = v.u;
  u += 0x7fffu + ((u >> 16) & 1u);   // RNE
  return (unsigned short)(u >> 16);
}
__device__ __forceinline__ float bf2f(unsigned short u) {
  union { unsigned int i; float f; } v; v.i = ((unsigned int)u) << 16; return v.f;
}

__device__ __forceinline__ void gload_lds16(const void* g, void* l) {
  __builtin_amdgcn_global_load_lds(
      (const __attribute__((address_space(1))) unsigned int*)g,
      (__attribute__((address_space(3))) unsigned int*)l, 16, 0, 0);
}

// ---------------------------------------------------------------------------
// Weights -> bf16. Also: Wdt padded [512][32] (cols 16..31 = 0), flag init.
// ---------------------------------------------------------------------------
__global__ __launch_bounds__(256) void k_wcvt(const float* __restrict__ w_in,
                                              const float* __restrict__ w_out,
                                              const float* __restrict__ w_x,
                                              const float* __restrict__ w_dt,
                                              unsigned short* __restrict__ wib,
                                              unsigned short* __restrict__ wob,
                                              unsigned short* __restrict__ wxb,
                                              unsigned short* __restrict__ wdtb,
                                              unsigned int* __restrict__ flag) {
  int idx = blockIdx.x * 256 + threadIdx.x;
  if (idx == 0) *flag = 0xFFFFFFFFu;
  if (idx < 262144) wib[idx] = f2bf(w_in[idx]);
  else if (idx < 393216) wob[idx - 262144] = f2bf(w_out[idx - 262144]);
  else if (idx < 417792) wxb[idx - 393216] = f2bf(w_x[idx - 393216]);
  else if (idx < 450560) {
    int i = idx - 417792;           // [0, 32768)
    int r = i & 31, d = i >> 5;
    wdtb[i] = (r < 16) ? f2bf(w_dt[d * 16 + r]) : (unsigned short)0;
  }
}

// ---------------------------------------------------------------------------
// A-structure prep: Av0[d] = -exp(A_log[d,0]); fast flag &= (Av[n]==(n+1)Av0).
// ---------------------------------------------------------------------------
__global__ __launch_bounds__(256) void k_aprep(const float* __restrict__ A_log,
                                               float* __restrict__ Avz,
                                               unsigned int* __restrict__ flag) {
  int d = blockIdx.x * 256 + threadIdx.x;
  float a0 = -__expf(A_log[d * kN]);
  bool ok = true;
#pragma unroll
  for (int n = 1; n < kN; ++n) {
    float av = -__expf(A_log[d * kN + n]);
    ok = ok && (fabsf(av - (n + 1) * a0) <= 1e-5f * fabsf(av));
  }
  Avz[d] = a0;
  if (!ok) atomicAnd(flag, 0u);
}

// ---------------------------------------------------------------------------
// Transpose-convert x [b, d, l] f32 -> xt [b, l, d] bf16.
// ---------------------------------------------------------------------------
__global__ __launch_bounds__(256) void k_xt(const float* __restrict__ x,
                                            unsigned short* __restrict__ xt) {
  __shared__ float Xs[64][65];
  const int b = blockIdx.z, d0 = blockIdx.y * 64, l0 = blockIdx.x * 64;
  const int t = threadIdx.x, l = t & 63;
#pragma unroll
  for (int rep = 0; rep < 16; ++rep) {
    int dd = rep * 4 + (t >> 6);
    Xs[dd][l] = x[((size_t)b * kDim + d0 + dd) * kL + l0 + l];
  }
  __syncthreads();
#pragma unroll
  for (int rep = 0; rep < 8; ++rep) {
    int lj = rep * 8 + (t >> 5);
    int di = (t & 31) * 2;
    ushort2 v;
    v.x = f2bf(Xs[di][lj]);
    v.y = f2bf(Xs[di + 1][lj]);
    *(ushort2*)(xt + ((size_t)b * kL + l0 + lj) * kDim + d0 + di) = v;
  }
}

// ---------------------------------------------------------------------------
// in_proj GEMM, l-major bf16 output.
// ---------------------------------------------------------------------------
__global__ __launch_bounds__(256) void gemm_in_lm(const unsigned short* __restrict__ xt,
                                                  const unsigned short* __restrict__ W,
                                                  unsigned short* __restrict__ ubf,
                                                  unsigned short* __restrict__ resb) {
  __shared__ __align__(16) unsigned short As[128 * 64];
  __shared__ __align__(16) unsigned short Bs[128 * 64];
  const int e0 = blockIdx.x * 128;
  const int l0 = blockIdx.y * 128;
  const int b  = blockIdx.z;
  const int t  = threadIdx.x;
  const int wave = t >> 6, lane = t & 63;
  const int wm = wave >> 1, wn = wave & 1;
  const unsigned short* Ab = xt + (size_t)b * kL * kDim;

  f32x4 acc[4][4];
#pragma unroll
  for (int i = 0; i < 4; ++i)
#pragma unroll
    for (int j = 0; j < 4; ++j) acc[i][j] = (f32x4)0.0f;

  const int srow = t >> 3, sch = t & 7;
  for (int kt = 0; kt < 4; ++kt) {
    const int k0 = kt * 64;
#pragma unroll
    for (int c = 0; c < 4; ++c) {
      int row = c * 32 + srow;
      int gch = sch ^ (row & 7);
      gload_lds16(Ab + (size_t)(l0 + row) * kDim + k0 + gch * 8,
                  (char*)As + c * 4096 + wave * 1024);
      gload_lds16(W  + (size_t)(e0 + row) * kDim + k0 + gch * 8,
                  (char*)Bs + c * 4096 + wave * 1024);
    }
    __syncthreads();
#pragma unroll
    for (int ks = 0; ks < 2; ++ks) {
      bf16x8 af[4], bfr[4];
#pragma unroll
      for (int f = 0; f < 4; ++f) {
        int ra = wm * 64 + f * 16 + (lane & 15);
        int ca = (ks * 4 + (lane >> 4)) ^ (ra & 7);
        af[f] = *(const bf16x8*)((const char*)As + ra * 128 + ca * 16);
        int rb = wn * 64 + f * 16 + (lane & 15);
        int cb = (ks * 4 + (lane >> 4)) ^ (rb & 7);
        bfr[f] = *(const bf16x8*)((const char*)Bs + rb * 128 + cb * 16);
      }
#pragma unroll
      for (int i = 0; i < 4; ++i)
#pragma unroll
        for (int j = 0; j < 4; ++j)
          acc[i][j] = __builtin_amdgcn_mfma_f32_16x16x32_bf16(af[i], bfr[j], acc[i][j], 0, 0, 0);
    }
    __syncthreads();
  }

  const bool is_u = (e0 < kDI);
  unsigned short* dst = is_u ? ubf : resb;
  const int ebase = is_u ? e0 : (e0 - kDI);
#pragma unroll
  for (int i = 0; i < 4; ++i)
#pragma unroll
    for (int j = 0; j < 4; ++j)
#pragma unroll
      for (int r = 0; r < 4; ++r) {
        int l = l0 + wm * 64 + i * 16 + (lane >> 4) * 4 + r;
        int e = ebase + wn * 64 + j * 16 + (lane & 15);
        dst[((size_t)b * kL + l) * kDI + e] = f2bf(acc[i][j][r]);
      }
}

// ---------------------------------------------------------------------------
// Causal depthwise conv k=4 + bias + SiLU, l-major, bf16 in/out, 8 d/thread.
// ---------------------------------------------------------------------------
__global__ __launch_bounds__(256) void k_conv(const unsigned short* __restrict__ ubf,
                                              const float* __restrict__ cw,
                                              const float* __restrict__ cb,
                                              unsigned short* __restrict__ ucb) {
  int idx = blockIdx.x * 256 + threadIdx.x;   // over B*L*64
  int d8 = idx & 63;
  int l  = (idx >> 6) & (kL - 1);
  int b  = idx >> 18;
  int d0 = d8 * 8;
  const unsigned short* row = ubf + ((size_t)b * kL + l) * kDI + d0;
  uint4 zero = make_uint4(0, 0, 0, 0);
  uint4 c0 = *(const uint4*)row;
  uint4 c1 = (l >= 1) ? *(const uint4*)(row - kDI)     : zero;
  uint4 c2 = (l >= 2) ? *(const uint4*)(row - 2 * kDI) : zero;
  uint4 c3 = (l >= 3) ? *(const uint4*)(row - 3 * kDI) : zero;
  const unsigned int* p0 = (const unsigned int*)&c0;
  const unsigned int* p1 = (const unsigned int*)&c1;
  const unsigned int* p2 = (const unsigned int*)&c2;
  const unsigned int* p3 = (const unsigned int*)&c3;
  unsigned short ov[8];
#pragma unroll
  for (int c = 0; c < 8; ++c) {
    int q = c >> 1, hi = c & 1;
    float u0 = bf2f((unsigned short)(hi ? (p0[q] >> 16) : (p0[q] & 0xffff)));
    float u1 = bf2f((unsigned short)(hi ? (p1[q] >> 16) : (p1[q] & 0xffff)));
    float u2 = bf2f((unsigned short)(hi ? (p2[q] >> 16) : (p2[q] & 0xffff)));
    float u3 = bf2f((unsigned short)(hi ? (p3[q] >> 16) : (p3[q] & 0xffff)));
    float4 w = *(const float4*)(cw + (d0 + c) * 4);
    float acc = cb[d0 + c] + w.x * u3 + w.y * u2 + w.z * u1 + w.w * u0;
    ov[c] = f2bf(siluf(acc));
  }
  *(uint4*)(ucb + ((size_t)b * kL + l) * kDI + d0) = *(const uint4*)ov;
}

// ---------------------------------------------------------------------------
// x_proj MFMA: m<16 -> dtT[b,l,32] bf16 (cols 16..31 zeroed);
//              m 16..47 -> dbcBC[b][m-16][l] f32 (B rows 0-15, C rows 16-31).
// ---------------------------------------------------------------------------
__global__ __launch_bounds__(256) void k_xproj(const unsigned short* __restrict__ Wx,
                                               const unsigned short* __restrict__ ucb,
                                               float* __restrict__ dbcBC,
                                               unsigned short* __restrict__ dtT) {
  __shared__ __align__(16) unsigned short As[64 * 64];
  __shared__ __align__(16) unsigned short Bs[128 * 64];
  const int l0 = blockIdx.x * 128;
  const int b  = blockIdx.y;
  const int t  = threadIdx.x;
  const int wave = t >> 6, lane = t & 63;
  const unsigned short* Bb = ucb + (size_t)b * kL * kDI;

  f32x4 acc[3][2];
#pragma unroll
  for (int i = 0; i < 3; ++i)
#pragma unroll
    for (int j = 0; j < 2; ++j) acc[i][j] = (f32x4)0.0f;

  const int srow = t >> 3, sch = t & 7;
  for (int kt = 0; kt < 8; ++kt) {
    const int k0 = kt * 64;
#pragma unroll
    for (int c = 0; c < 2; ++c) {
      int row = c * 32 + srow;
      int grow = row < 48 ? row : 47;
      int gch = sch ^ (row & 7);
      gload_lds16(Wx + (size_t)grow * kDI + k0 + gch * 8,
                  (char*)As + c * 4096 + wave * 1024);
    }
#pragma unroll
    for (int c = 0; c < 4; ++c) {
      int row = c * 32 + srow;
      int gch = sch ^ (row & 7);
      gload_lds16(Bb + (size_t)(l0 + row) * kDI + k0 + gch * 8,
                  (char*)Bs + c * 4096 + wave * 1024);
    }
    __syncthreads();
#pragma unroll
    for (int ks = 0; ks < 2; ++ks) {
      bf16x8 af[3], bfr[2];
#pragma unroll
      for (int f = 0; f < 3; ++f) {
        int ra = f * 16 + (lane & 15);
        int ca = (ks * 4 + (lane >> 4)) ^ (ra & 7);
        af[f] = *(const bf16x8*)((const char*)As + ra * 128 + ca * 16);
      }
#pragma unroll
      for (int f = 0; f < 2; ++f) {
        int rb = wave * 32 + f * 16 + (lane & 15);
        int cb = (ks * 4 + (lane >> 4)) ^ (rb & 7);
        bfr[f] = *(const bf16x8*)((const char*)Bs + rb * 128 + cb * 16);
      }
#pragma unroll
      for (int i = 0; i < 3; ++i)
#pragma unroll
        for (int j = 0; j < 2; ++j)
          acc[i][j] = __builtin_amdgcn_mfma_f32_16x16x32_bf16(af[i], bfr[j], acc[i][j], 0, 0, 0);
    }
    __syncthreads();
  }
#pragma unroll
  for (int i = 0; i < 3; ++i)
#pragma unroll
    for (int j = 0; j < 2; ++j)
#pragma unroll
      for (int r = 0; r < 4; ++r) {
        int m = i * 16 + (lane >> 4) * 4 + r;
        int l = l0 + wave * 32 + j * 16 + (lane & 15);
        if (i == 0) {
          size_t base = ((size_t)b * kL + l) * 32;
          dtT[base + m] = f2bf(acc[i][j][r]);
          dtT[base + m + 16] = 0;   // K-padding
        } else {
          dbcBC[((size_t)b * 32 + (m - 16)) * kL + l] = acc[i][j][r];
        }
      }
}

// ---------------------------------------------------------------------------
// dt_proj MFMA (K=32, cols 16..31 zero) + softplus + E/du epilogue.
// A = dtT [l,32] rows; B = wdtb [512,32] rows; out per (l,d):
//   delta = softplus(acc + bdt[d]);
//   fast: Ebuf = exp(delta*Av0[d]); else: Ebuf = delta.
//   dub = bf16(delta * u).
// ---------------------------------------------------------------------------
__global__ __launch_bounds__(256) void gemm_dt(const unsigned short* __restrict__ dtT,
                                               const unsigned short* __restrict__ Wdtb,
                                               const float* __restrict__ bdt,
                                               const float* __restrict__ Avz,
                                               const unsigned int* __restrict__ flag,
                                               const unsigned short* __restrict__ ucb,
                                               float* __restrict__ Ebuf,
                                               unsigned short* __restrict__ dub) {
  __shared__ __align__(16) unsigned short As[128 * 32];
  __shared__ __align__(16) unsigned short Bs[128 * 32];
  const int n0 = blockIdx.x * 128;   // d
  const int l0 = blockIdx.y * 128;   // l
  const int b  = blockIdx.z;
  const int t  = threadIdx.x;
  const int wave = t >> 6, lane = t & 63;
  const int wm = wave >> 1, wn = wave & 1;
  const unsigned short* Ab = dtT + (size_t)b * kL * 32;

  // stage: 2 calls x (256 threads x 16B = 64 rows of 64B)
  const int srow = t >> 2, sch = t & 3;
#pragma unroll
  for (int c = 0; c < 2; ++c) {
    int row = c * 64 + srow;
    int gch = sch ^ (row & 3);
    gload_lds16(Ab + (size_t)(l0 + row) * 32 + gch * 8,
                (char*)As + c * 4096 + t * 16);
    gload_lds16(Wdtb + (size_t)(n0 + row) * 32 + gch * 8,
                (char*)Bs + c * 4096 + t * 16);
  }
  __syncthreads();

  f32x4 acc[4][4];
#pragma unroll
  for (int i = 0; i < 4; ++i)
#pragma unroll
    for (int j = 0; j < 4; ++j) acc[i][j] = (f32x4)0.0f;

  bf16x8 af[4], bfr[4];
#pragma unroll
  for (int f = 0; f < 4; ++f) {
    int ra = wm * 64 + f * 16 + (lane & 15);
    int ca = (lane >> 4) ^ (ra & 3);
    af[f] = *(const bf16x8*)((const char*)As + ra * 64 + ca * 16);
    int rb = wn * 64 + f * 16 + (lane & 15);
    int cb = (lane >> 4) ^ (rb & 3);
    bfr[f] = *(const bf16x8*)((const char*)Bs + rb * 64 + cb * 16);
  }
#pragma unroll
  for (int i = 0; i < 4; ++i)
#pragma unroll
    for (int j = 0; j < 4; ++j)
      acc[i][j] = __builtin_amdgcn_mfma_f32_16x16x32_bf16(af[i], bfr[j], acc[i][j], 0, 0, 0);

  const bool fast = (*flag != 0u);
#pragma unroll
  for (int j = 0; j < 4; ++j) {
    int d = n0 + wn * 64 + j * 16 + (lane & 15);
    float bd = bdt[d];
    float av = Avz[d];
#pragma unroll
    for (int i = 0; i < 4; ++i)
#pragma unroll
      for (int r = 0; r < 4; ++r) {
        int l = l0 + wm * 64 + i * 16 + (lane >> 4) * 4 + r;
        size_t off = ((size_t)b * kL + l) * kDI + d;
        float delta = softplusf(acc[i][j][r] + bd);
        Ebuf[off] = fast ? __expf(delta * av) : delta;
        dub[off] = f2bf(delta * bf2f(ucb[off]));
      }
  }
}

// ---------------------------------------------------------------------------
// Scan phase A: zero transcendentals (fast). Loads E,du; LDS B rows; packed.
// P[n] = (prod E)^(n+1).
// ---------------------------------------------------------------------------
__global__ __launch_bounds__(256) void k_scanA(const float* __restrict__ Ebuf,
                                               const unsigned short* __restrict__ dub,
                                               const unsigned short* __restrict__ ucb,
                                               const float* __restrict__ dbcBC,
                                               const float* __restrict__ A_log,
                                               const unsigned int* __restrict__ flag,
                                               float* __restrict__ P,
                                               float* __restrict__ S) {
  __shared__ __align__(16) float Bsh[16][kCS];
  const int b = blockIdx.z, ch = blockIdx.y;
  const int t = threadIdx.x;
  const int d = blockIdx.x * 256 + t;
  const int l0 = ch * kCS;
  {
    int row = t >> 4, li = (t & 15) * 2;
    *(float2*)&Bsh[row][li] =
        *(const float2*)&dbcBC[((size_t)b * 32 + row) * kL + l0 + li];
  }
  __syncthreads();
  const bool fast = (*flag != 0u);
  const float* pE = Ebuf + ((size_t)b * kL + l0) * kDI + d;
  const unsigned short* pDu = dub + ((size_t)b * kL + l0) * kDI + d;
  size_t obase = (size_t)(b * kNC + ch) * (kN * kDI) + d;

  if (fast) {
    f32x2 Sv2[8];
#pragma unroll
    for (int m = 0; m < 8; ++m) Sv2[m] = (f32x2){0.f, 0.f};
    float Pprod = 1.f;
    for (int i = 0; i < kCS; i += 4) {
      float E[4];
      f32x2 a2[4], e2[4], du2[4];
#pragma unroll
      for (int jj = 0; jj < 4; ++jj) {
        E[jj] = pE[(size_t)(i + jj) * kDI];
        float duv = bf2f(pDu[(size_t)(i + jj) * kDI]);
        du2[jj] = (f32x2){duv, duv};
        float Esq = E[jj] * E[jj];
        a2[jj] = (f32x2){E[jj], Esq};
        e2[jj] = (f32x2){Esq, Esq};
      }
      Pprod *= E[0] * E[1];
      Pprod *= E[2] * E[3];
#pragma unroll
      for (int m = 0; m < 8; ++m) {
        float4 Ba = *(const float4*)&Bsh[2 * m][i];
        float4 Bb = *(const float4*)&Bsh[2 * m + 1][i];
        Sv2[m] = Sv2[m] * a2[0] + du2[0] * (f32x2){Ba.x, Bb.x};
        Sv2[m] = Sv2[m] * a2[1] + du2[1] * (f32x2){Ba.y, Bb.y};
        Sv2[m] = Sv2[m] * a2[2] + du2[2] * (f32x2){Ba.z, Bb.z};
        Sv2[m] = Sv2[m] * a2[3] + du2[3] * (f32x2){Ba.w, Bb.w};
        if (m < 7) {
          a2[0] *= e2[0]; a2[1] *= e2[1]; a2[2] *= e2[2]; a2[3] *= e2[3];
        }
      }
    }
    float pw = Pprod;
#pragma unroll
    for (int n = 0; n < kN; ++n) {
      P[obase + (size_t)n * kDI] = pw;
      S[obase + (size_t)n * kDI] = (n & 1) ? Sv2[n >> 1].y : Sv2[n >> 1].x;
      pw *= Pprod;
    }
  } else {
    // generic: Ebuf holds delta
    const unsigned short* pU = ucb + ((size_t)b * kL + l0) * kDI + d;
    float Av[16];
#pragma unroll
    for (int n = 0; n < kN; ++n) Av[n] = -__expf(A_log[d * kN + n]);
    float Pv[16], Sv[16];
#pragma unroll
    for (int n = 0; n < kN; ++n) { Pv[n] = 1.f; Sv[n] = 0.f; }
    for (int i = 0; i < kCS; i += 4) {
      float del[4], du[4];
#pragma unroll
      for (int jj = 0; jj < 4; ++jj) {
        del[jj] = pE[(size_t)(i + jj) * kDI];
        du[jj] = del[jj] * bf2f(pU[(size_t)(i + jj) * kDI]);
      }
#pragma unroll
      for (int n = 0; n < kN; ++n) {
        float4 B4 = *(const float4*)&Bsh[n][i];
        float a;
        a = __expf(del[0] * Av[n]); Pv[n] *= a; Sv[n] = Sv[n] * a + du[0] * B4.x;
        a = __expf(del[1] * Av[n]); Pv[n] *= a; Sv[n] = Sv[n] * a + du[1] * B4.y;
        a = __expf(del[2] * Av[n]); Pv[n] *= a; Sv[n] = Sv[n] * a + du[2] * B4.z;
        a = __expf(del[3] * Av[n]); Pv[n] *= a; Sv[n] = Sv[n] * a + du[3] * B4.w;
      }
    }
#pragma unroll
    for (int n = 0; n < kN; ++n) {
      P[obase + (size_t)n * kDI] = Pv[n];
      S[obase + (size_t)n * kDI] = Sv[n];
    }
  }
}

// ---------------------------------------------------------------------------
// Scan phase B: combine chunk summaries -> per-chunk init states. 8-deep.
// ---------------------------------------------------------------------------
__global__ __launch_bounds__(256) void k_scanB(const float* __restrict__ P,
                                               const float* __restrict__ S,
                                               float* __restrict__ init) {
  int idx = blockIdx.x * 256 + threadIdx.x;  // b*8192 + n*512 + d
  int b = idx >> 13, nd = idx & 8191;
  size_t base = (size_t)b * kNC * 8192 + nd;
  float carry = 0.f;
  for (int c0 = 0; c0 < kNC; c0 += 8) {
    float p[8], s[8];
#pragma unroll
    for (int j = 0; j < 8; ++j) {
      size_t o = base + (size_t)(c0 + j) * 8192;
      p[j] = P[o]; s[j] = S[o];
    }
#pragma unroll
    for (int j = 0; j < 8; ++j) {
      init[base + (size_t)(c0 + j) * 8192] = carry;
      carry = p[j] * carry + s[j];
    }
  }
}

// ---------------------------------------------------------------------------
// Scan phase C (+gate): zero transcendentals (fast). y=sum_n s_n*C_n;
// g=(y+u*D)*silu(res) -> yt bf16.
// ---------------------------------------------------------------------------
__global__ __launch_bounds__(256) void k_scanC(const float* __restrict__ Ebuf,
                                               const unsigned short* __restrict__ dub,
                                               const unsigned short* __restrict__ ucb,
                                               const float* __restrict__ dbcBC,
                                               const float* __restrict__ A_log,
                                               const unsigned int* __restrict__ flag,
                                               const float* __restrict__ init,
                                               const unsigned short* __restrict__ resb,
                                               const float* __restrict__ Dp,
                                               unsigned short* __restrict__ yt) {
  __shared__ __align__(16) float BCsh[32][kCS];  // 0-15 B, 16-31 C
  const int b = blockIdx.z, ch = blockIdx.y;
  const int t = threadIdx.x;
  const int d = blockIdx.x * 256 + t;
  const int l0 = ch * kCS;
  {
    int row = t >> 3, li = (t & 7) * 4;
    *(float4*)&BCsh[row][li] =
        *(const float4*)&dbcBC[((size_t)b * 32 + row) * kL + l0 + li];
  }
  __syncthreads();
  const bool fast = (*flag != 0u);
  const float Dv = Dp[d];
  const float* pE = Ebuf + ((size_t)b * kL + l0) * kDI + d;
  const unsigned short* pDu = dub + ((size_t)b * kL + l0) * kDI + d;
  const unsigned short* pU = ucb + ((size_t)b * kL + l0) * kDI + d;
  const unsigned short* pR = resb + ((size_t)b * kL + l0) * kDI + d;
  unsigned short* pY = yt + ((size_t)b * kL + l0) * kDI + d;
  size_t ibase = (size_t)(b * kNC + ch) * (kN * kDI) + d;

  if (fast) {
    f32x2 s2[8];
#pragma unroll
    for (int m = 0; m < 8; ++m)
      s2[m] = (f32x2){init[ibase + (size_t)(2 * m) * kDI],
                      init[ibase + (size_t)(2 * m + 1) * kDI]};
    for (int i = 0; i < kCS; i += 4) {
      float uv[4];
      f32x2 a2[4], e2[4], du2[4], yacc2[4];
#pragma unroll
      for (int jj = 0; jj < 4; ++jj) {
        float E = pE[(size_t)(i + jj) * kDI];
        float duv = bf2f(pDu[(size_t)(i + jj) * kDI]);
        uv[jj] = bf2f(pU[(size_t)(i + jj) * kDI]);
        du2[jj] = (f32x2){duv, duv};
        float Esq = E * E;
        a2[jj] = (f32x2){E, Esq};
        e2[jj] = (f32x2){Esq, Esq};
        yacc2[jj] = (f32x2){0.f, 0.f};
      }
#pragma unroll
      for (int m = 0; m < 8; ++m) {
        float4 Ba = *(const float4*)&BCsh[2 * m][i];
        float4 Bb = *(const float4*)&BCsh[2 * m + 1][i];
        float4 Ca = *(const float4*)&BCsh[16 + 2 * m][i];
        float4 Cb = *(const float4*)&BCsh[16 + 2 * m + 1][i];
        s2[m] = s2[m] * a2[0] + du2[0] * (f32x2){Ba.x, Bb.x};
        yacc2[0] = yacc2[0] + s2[m] * (f32x2){Ca.x, Cb.x};
        s2[m] = s2[m] * a2[1] + du2[1] * (f32x2){Ba.y, Bb.y};
        yacc2[1] = yacc2[1] + s2[m] * (f32x2){Ca.y, Cb.y};
        s2[m] = s2[m] * a2[2] + du2[2] * (f32x2){Ba.z, Bb.z};
        yacc2[2] = yacc2[2] + s2[m] * (f32x2){Ca.z, Cb.z};
        s2[m] = s2[m] * a2[3] + du2[3] * (f32x2){Ba.w, Bb.w};
        yacc2[3] = yacc2[3] + s2[m] * (f32x2){Ca.w, Cb.w};
        if (m < 7) {
          a2[0] *= e2[0]; a2[1] *= e2[1]; a2[2] *= e2[2]; a2[3] *= e2[3];
        }
      }
#pragma unroll
      for (int jj = 0; jj < 4; ++jj) {
        float yv = yacc2[jj].x + yacc2[jj].y;
        float r = bf2f(pR[(size_t)(i + jj) * kDI]);
        float gv = (yv + uv[jj] * Dv) * siluf(r);
        pY[(size_t)(i + jj) * kDI] = f2bf(gv);
      }
    }
  } else {
    float Av[16];
#pragma unroll
    for (int n = 0; n < kN; ++n) Av[n] = -__expf(A_log[d * kN + n]);
    float s[16];
#pragma unroll
    for (int n = 0; n < kN; ++n) s[n] = init[ibase + (size_t)n * kDI];
    for (int i = 0; i < kCS; i += 4) {
      float uv[4], du[4], del[4], yacc[4] = {0.f, 0.f, 0.f, 0.f};
#pragma unroll
      for (int jj = 0; jj < 4; ++jj) {
        del[jj] = pE[(size_t)(i + jj) * kDI];
        uv[jj] = bf2f(pU[(size_t)(i + jj) * kDI]);
        du[jj] = del[jj] * uv[jj];
      }
#pragma unroll
      for (int n = 0; n < kN; ++n) {
        float4 B4 = *(const float4*)&BCsh[n][i];
        float4 C4 = *(const float4*)&BCsh[16 + n][i];
        float a;
        a = __expf(del[0] * Av[n]); s[n] = s[n] * a + du[0] * B4.x; yacc[0] += s[n] * C4.x;
        a = __expf(del[1] * Av[n]); s[n] = s[n] * a + du[1] * B4.y; yacc[1] += s[n] * C4.y;
        a = __expf(del[2] * Av[n]); s[n] = s[n] * a + du[2] * B4.z; yacc[2] += s[n] * C4.z;
        a = __expf(del[3] * Av[n]); s[n] = s[n] * a + du[3] * B4.w; yacc[3] += s[n] * C4.w;
      }
#pragma unroll
      for (int jj = 0; jj < 4; ++jj) {
        float r = bf2f(pR[(size_t)(i + jj) * kDI]);
        float gv = (yacc[jj] + uv[jj] * Dv) * siluf(r);
        pY[(size_t)(i + jj) * kDI] = f2bf(gv);
      }
    }
  }
}

// ---------------------------------------------------------------------------
// out_proj GEMM: out[b][c][l] = sum_k Wo[c,k] * yt[b,l,k].
// ---------------------------------------------------------------------------
__global__ __launch_bounds__(256) void gemm_out(const unsigned short* __restrict__ A,
                                                const unsigned short* __restrict__ Bt,
                                                float* __restrict__ C0) {
  __shared__ __align__(16) unsigned short As[128 * 64];
  __shared__ __align__(16) unsigned short Bs[128 * 64];
  const int n0 = blockIdx.x * 128;
  const int m0 = blockIdx.y * 128;
  const int b  = blockIdx.z;
  const int t  = threadIdx.x;
  const int wave = t >> 6, lane = t & 63;
  const int wm = wave >> 1, wn = wave & 1;
  const unsigned short* Bb = Bt + (size_t)b * kL * kDI;

  f32x4 acc[4][4];
#pragma unroll
  for (int i = 0; i < 4; ++i)
#pragma unroll
    for (int j = 0; j < 4; ++j) acc[i][j] = (f32x4)0.0f;

  const int srow = t >> 3, sch = t & 7;
  for (int kt = 0; kt < 8; ++kt) {
    const int k0 = kt * 64;
#pragma unroll
    for (int c = 0; c < 4; ++c) {
      int row = c * 32 + srow;
      int gch = sch ^ (row & 7);
      gload_lds16(A  + (size_t)(m0 + row) * kDI + k0 + gch * 8,
                  (char*)As + c * 4096 + wave * 1024);
      gload_lds16(Bb + (size_t)(n0 + row) * kDI + k0 + gch * 8,
                  (char*)Bs + c * 4096 + wave * 1024);
    }
    __syncthreads();
#pragma unroll
    for (int ks = 0; ks < 2; ++ks) {
      bf16x8 af[4], bfr[4];
#pragma unroll
      for (int f = 0; f < 4; ++f) {
        int ra = wm * 64 + f * 16 + (lane & 15);
        int ca = (ks * 4 + (lane >> 4)) ^ (ra & 7);
        af[f] = *(const bf16x8*)((const char*)As + ra * 128 + ca * 16);
        int rb = wn * 64 + f * 16 + (lane & 15);
        int cb = (ks * 4 + (lane >> 4)) ^ (rb & 7);
        bfr[f] = *(const bf16x8*)((const char*)Bs + rb * 128 + cb * 16);
      }
#pragma unroll
      for (int i = 0; i < 4; ++i)
#pragma unroll
        for (int j = 0; j < 4; ++j)
          acc[i][j] = __builtin_amdgcn_mfma_f32_16x16x32_bf16(af[i], bfr[j], acc[i][j], 0, 0, 0);
    }
    __syncthreads();
  }
#pragma unroll
  for (int i = 0; i < 4; ++i)
#pragma unroll
    for (int j = 0; j < 4; ++j)
#pragma unroll
      for (int r = 0; r < 4; ++r) {
        int m = m0 + wm * 64 + i * 16 + (lane >> 4) * 4 + r;
        int n = n0 + wn * 64 + j * 16 + (lane & 15);
        C0[((size_t)b * kDim + m) * kL + n] = acc[i][j][r];
      }
}

// ---------------------------------------------------------------------------
extern "C" void kernel_launch(void* const* d_in, const int* in_sizes, int n_in,
                              void* d_out, int out_size, void* d_ws, size_t ws_size,
                              hipStream_t stream) {
  const float* x       = (const float*)d_in[0];
  const float* in_w    = (const float*)d_in[1];
  const float* conv_w  = (const float*)d_in[2];
  const float* conv_b  = (const float*)d_in[3];
  const float* xproj_w = (const float*)d_in[4];
  const float* dt_w    = (const float*)d_in[5];
  const float* dt_b    = (const float*)d_in[6];
  const float* A_log   = (const float*)d_in[7];
  const float* Dp      = (const float*)d_in[8];
  const float* out_w   = (const float*)d_in[9];
  float* out = (float*)d_out;

  // workspace layout (~116 MB)
  float* ws = (float*)d_ws;
  const size_t nBLD  = (size_t)kB * kL * kDI;                 // 8388608
  const size_t nPS   = (size_t)kB * kNC * kN * kDI;           // 4194304
  float* dbcBC = ws;                                          // 524288 f
  float* Pb    = dbcBC + 524288;                              // nPS
  float* Sb    = Pb + nPS;                                    // nPS
  float* initb = Sb + nPS;                                    // nPS
  float* Ebuf  = initb + nPS;                                 // nBLD f
  unsigned short* ubf  = (unsigned short*)Ebuf;               // overlay: dead before gemm_dt
  unsigned short* ucb  = (unsigned short*)(Ebuf + nBLD);      // nBLD us
  unsigned short* resb = ucb + nBLD;                          // nBLD us
  unsigned short* dub  = resb + nBLD;                         // nBLD us
  unsigned short* xt   = dub;                                 // overlay: dead before gemm_dt
  unsigned short* dtT  = dub + nBLD;                          // 524288 us
  unsigned short* wib  = dtT + 524288;                        // 262144
  unsigned short* wob  = wib + 262144;                        // 131072
  unsigned short* wxb  = wob + 131072;                        // 24576
  unsigned short* wdtb = wxb + 24576;                         // 32768
  float* Avz           = (float*)(wdtb + 32768);              // 512 f
  unsigned int* flag   = (unsigned int*)(Avz + 512);          // 1 u32
  unsigned short* yt   = (unsigned short*)Pb;                 // overlay after scanB

  k_wcvt<<<dim3(1760), 256, 0, stream>>>(in_w, out_w, xproj_w, dt_w, wib, wob, wxb, wdtb, flag);
  k_aprep<<<dim3(2), 256, 0, stream>>>(A_log, Avz, flag);
  k_xt<<<dim3(kL / 64, kDim / 64, kB), 256, 0, stream>>>(x, xt);
  gemm_in_lm<<<dim3(8, kL / 128, kB), 256, 0, stream>>>(xt, wib, ubf, resb);
  k_conv<<<dim3((unsigned)(kB * kL * 64 / 256)), 256, 0, stream>>>(ubf, conv_w, conv_b, ucb);
  k_xproj<<<dim3(kL / 128, kB), 256, 0, stream>>>(wxb, ucb, dbcBC, dtT);
  gemm_dt<<<dim3(kDI / 128, kL / 128, kB), 256, 0, stream>>>(dtT, wdtb, dt_b, Avz, flag, ucb, Ebuf, dub);
  k_scanA<<<dim3(2, kNC, kB), 256, 0, stream>>>(Ebuf, dub, ucb, dbcBC, A_log, flag, Pb, Sb);
  k_scanB<<<dim3(kB * kDI * kN / 256), 256, 0, stream>>>(Pb, Sb, initb);
  k_scanC<<<dim3(2, kNC, kB), 256, 0, stream>>>(Ebuf, dub, ucb, dbcBC, A_log, flag, initb, resb, Dp, yt);
  gemm_out<<<dim3(kL / 128, kDim / 128, kB), 256, 0, stream>>>(wob, yt, out);
}

// Round 10
// 154.981 us; speedup vs baseline: 4.3437x; 1.0494x over previous
//
#include <hip/hip_runtime.h>
#include <math.h>

// Mamba block forward, l-major activations [b, l, d].
// B=4, DIM=256, L=4096, D_INNER=512, D_STATE=16, DT_RANK=16, D_CONV=4.
// R10: (1) scans read delta bf16 (17MB) instead of E f32 + du bf16 (50MB);
// E/du recomputed in-scan (1 exp). (2) gemm_dt fused into k_xproj_dt
// (dt_pre -> LDS -> K=32 MFMA -> softplus -> delb). (3) wcvt+aprep+xt merged
// into k_prep. 8 kernels total (was 11).

namespace {
constexpr int kB   = 4;
constexpr int kDim = 256;
constexpr int kL   = 4096;
constexpr int kDI  = 512;
constexpr int kN   = 16;
constexpr int kNC  = 128;  // scan chunks
constexpr int kCS  = 32;   // chunk size
} // namespace

typedef __attribute__((ext_vector_type(8))) short bf16x8;
typedef __attribute__((ext_vector_type(4))) float f32x4;
typedef __attribute__((ext_vector_type(2))) float f32x2;

__device__ __forceinline__ float rcpf(float x) { return __builtin_amdgcn_rcpf(x); }
__device__ __forceinline__ float siluf(float x) { return x * rcpf(1.f + __expf(-x)); }
__device__ __forceinline__ float softplusf(float x) {
  return fmaxf(x, 0.f) + __logf(1.f + __expf(-fabsf(x)));
}

__device__ __forceinline__ unsigned short f2bf(float x) {
  union { float f; unsigned int u; } v; v.f = x;
  unsigned int u = v.u;
  u += 0x7fffu + ((u >> 16) & 1u);   // RNE
  return (unsigned short)(u >> 16);
}
__device__ __forceinline__ float bf2f(unsigned short u) {
  union { unsigned int i; float f; } v; v.i = ((unsigned int)u) << 16; return v.f;
}

__device__ __forceinline__ void gload_lds16(const void* g, void* l) {
  __builtin_amdgcn_global_load_lds(
      (const __attribute__((address_space(1))) unsigned int*)g,
      (__attribute__((address_space(3))) unsigned int*)l, 16, 0, 0);
}

// ---------------------------------------------------------------------------
// k_prep: merged weight-convert (blocks 0..1759), A-structure check (1760-61),
// x transpose-convert (1762..2785).
// ---------------------------------------------------------------------------
__global__ __launch_bounds__(256) void k_prep(const float* __restrict__ w_in,
                                              const float* __restrict__ w_out,
                                              const float* __restrict__ w_x,
                                              const float* __restrict__ w_dt,
                                              const float* __restrict__ A_log,
                                              const float* __restrict__ x,
                                              unsigned short* __restrict__ wib,
                                              unsigned short* __restrict__ wob,
                                              unsigned short* __restrict__ wxb,
                                              unsigned short* __restrict__ wdtb,
                                              float* __restrict__ Avz,
                                              unsigned int* __restrict__ flagA,
                                              unsigned short* __restrict__ xt) {
  __shared__ float Xs[64][65];
  const int blk = blockIdx.x;
  const int t = threadIdx.x;
  if (blk < 1760) {
    int idx = blk * 256 + t;
    if (idx < 262144) wib[idx] = f2bf(w_in[idx]);
    else if (idx < 393216) wob[idx - 262144] = f2bf(w_out[idx - 262144]);
    else if (idx < 417792) wxb[idx - 393216] = f2bf(w_x[idx - 393216]);
    else {
      int i = idx - 417792;           // [0, 32768)
      int r = i & 31, d = i >> 5;
      wdtb[i] = (r < 16) ? f2bf(w_dt[d * 16 + r]) : (unsigned short)0;
    }
  } else if (blk < 1762) {
    int d = (blk - 1760) * 256 + t;
    float a0 = -__expf(A_log[d * kN]);
    bool ok = true;
#pragma unroll
    for (int n = 1; n < kN; ++n) {
      float av = -__expf(A_log[d * kN + n]);
      ok = ok && (fabsf(av - (n + 1) * a0) <= 1e-5f * fabsf(av));
    }
    Avz[d] = a0;
    unsigned long long bal = __ballot(ok);
    int wv = t >> 6;
    if ((t & 63) == 0) ((unsigned long long*)Xs)[wv] = bal;
    __syncthreads();
    if (t == 0) {
      unsigned long long all = ~0ull;
#pragma unroll
      for (int w = 0; w < 4; ++w) all &= ((unsigned long long*)Xs)[w];
      flagA[blk - 1760] = (all == ~0ull) ? 1u : 0u;
    }
  } else {
    int id = blk - 1762;
    int lb = id & 63, db = (id >> 6) & 3, b = id >> 8;
    const int d0 = db * 64, l0 = lb * 64, l = t & 63;
#pragma unroll
    for (int rep = 0; rep < 16; ++rep) {
      int dd = rep * 4 + (t >> 6);
      Xs[dd][l] = x[((size_t)b * kDim + d0 + dd) * kL + l0 + l];
    }
    __syncthreads();
#pragma unroll
    for (int rep = 0; rep < 8; ++rep) {
      int lj = rep * 8 + (t >> 5);
      int di = (t & 31) * 2;
      ushort2 v;
      v.x = f2bf(Xs[di][lj]);
      v.y = f2bf(Xs[di + 1][lj]);
      *(ushort2*)(xt + ((size_t)b * kL + l0 + lj) * kDim + d0 + di) = v;
    }
  }
}

// ---------------------------------------------------------------------------
// in_proj GEMM, l-major bf16 output.
// ---------------------------------------------------------------------------
__global__ __launch_bounds__(256) void gemm_in_lm(const unsigned short* __restrict__ xt,
                                                  const unsigned short* __restrict__ W,
                                                  unsigned short* __restrict__ ubf,
                                                  unsigned short* __restrict__ resb) {
  __shared__ __align__(16) unsigned short As[128 * 64];
  __shared__ __align__(16) unsigned short Bs[128 * 64];
  const int e0 = blockIdx.x * 128;
  const int l0 = blockIdx.y * 128;
  const int b  = blockIdx.z;
  const int t  = threadIdx.x;
  const int wave = t >> 6, lane = t & 63;
  const int wm = wave >> 1, wn = wave & 1;
  const unsigned short* Ab = xt + (size_t)b * kL * kDim;

  f32x4 acc[4][4];
#pragma unroll
  for (int i = 0; i < 4; ++i)
#pragma unroll
    for (int j = 0; j < 4; ++j) acc[i][j] = (f32x4)0.0f;

  const int srow = t >> 3, sch = t & 7;
  for (int kt = 0; kt < 4; ++kt) {
    const int k0 = kt * 64;
#pragma unroll
    for (int c = 0; c < 4; ++c) {
      int row = c * 32 + srow;
      int gch = sch ^ (row & 7);
      gload_lds16(Ab + (size_t)(l0 + row) * kDim + k0 + gch * 8,
                  (char*)As + c * 4096 + wave * 1024);
      gload_lds16(W  + (size_t)(e0 + row) * kDim + k0 + gch * 8,
                  (char*)Bs + c * 4096 + wave * 1024);
    }
    __syncthreads();
#pragma unroll
    for (int ks = 0; ks < 2; ++ks) {
      bf16x8 af[4], bfr[4];
#pragma unroll
      for (int f = 0; f < 4; ++f) {
        int ra = wm * 64 + f * 16 + (lane & 15);
        int ca = (ks * 4 + (lane >> 4)) ^ (ra & 7);
        af[f] = *(const bf16x8*)((const char*)As + ra * 128 + ca * 16);
        int rb = wn * 64 + f * 16 + (lane & 15);
        int cb = (ks * 4 + (lane >> 4)) ^ (rb & 7);
        bfr[f] = *(const bf16x8*)((const char*)Bs + rb * 128 + cb * 16);
      }
#pragma unroll
      for (int i = 0; i < 4; ++i)
#pragma unroll
        for (int j = 0; j < 4; ++j)
          acc[i][j] = __builtin_amdgcn_mfma_f32_16x16x32_bf16(af[i], bfr[j], acc[i][j], 0, 0, 0);
    }
    __syncthreads();
  }

  const bool is_u = (e0 < kDI);
  unsigned short* dst = is_u ? ubf : resb;
  const int ebase = is_u ? e0 : (e0 - kDI);
#pragma unroll
  for (int i = 0; i < 4; ++i)
#pragma unroll
    for (int j = 0; j < 4; ++j)
#pragma unroll
      for (int r = 0; r < 4; ++r) {
        int l = l0 + wm * 64 + i * 16 + (lane >> 4) * 4 + r;
        int e = ebase + wn * 64 + j * 16 + (lane & 15);
        dst[((size_t)b * kL + l) * kDI + e] = f2bf(acc[i][j][r]);
      }
}

// ---------------------------------------------------------------------------
// Causal depthwise conv k=4 + bias + SiLU, l-major, bf16 in/out, 8 d/thread.
// ---------------------------------------------------------------------------
__global__ __launch_bounds__(256) void k_conv(const unsigned short* __restrict__ ubf,
                                              const float* __restrict__ cw,
                                              const float* __restrict__ cb,
                                              unsigned short* __restrict__ ucb) {
  int idx = blockIdx.x * 256 + threadIdx.x;   // over B*L*64
  int d8 = idx & 63;
  int l  = (idx >> 6) & (kL - 1);
  int b  = idx >> 18;
  int d0 = d8 * 8;
  const unsigned short* row = ubf + ((size_t)b * kL + l) * kDI + d0;
  uint4 zero = make_uint4(0, 0, 0, 0);
  uint4 c0 = *(const uint4*)row;
  uint4 c1 = (l >= 1) ? *(const uint4*)(row - kDI)     : zero;
  uint4 c2 = (l >= 2) ? *(const uint4*)(row - 2 * kDI) : zero;
  uint4 c3 = (l >= 3) ? *(const uint4*)(row - 3 * kDI) : zero;
  const unsigned int* p0 = (const unsigned int*)&c0;
  const unsigned int* p1 = (const unsigned int*)&c1;
  const unsigned int* p2 = (const unsigned int*)&c2;
  const unsigned int* p3 = (const unsigned int*)&c3;
  unsigned short ov[8];
#pragma unroll
  for (int c = 0; c < 8; ++c) {
    int q = c >> 1, hi = c & 1;
    float u0 = bf2f((unsigned short)(hi ? (p0[q] >> 16) : (p0[q] & 0xffff)));
    float u1 = bf2f((unsigned short)(hi ? (p1[q] >> 16) : (p1[q] & 0xffff)));
    float u2 = bf2f((unsigned short)(hi ? (p2[q] >> 16) : (p2[q] & 0xffff)));
    float u3 = bf2f((unsigned short)(hi ? (p3[q] >> 16) : (p3[q] & 0xffff)));
    float4 w = *(const float4*)(cw + (d0 + c) * 4);
    float acc = cb[d0 + c] + w.x * u3 + w.y * u2 + w.z * u1 + w.w * u0;
    ov[c] = f2bf(siluf(acc));
  }
  *(uint4*)(ucb + ((size_t)b * kL + l) * kDI + d0) = *(const uint4*)ov;
}

// ---------------------------------------------------------------------------
// k_xproj_dt: phase 1 = x_proj MFMA (M=48, K=512): rows 16..47 -> dbcBC f32;
// rows 0..15 (dt_pre) -> LDS [128 l][32 k] bf16 (padded). Phase 2 = dt_proj
// MFMA (M=l, N=d, K=32) vs Wdt tiles + softplus -> delb[b,l,d] bf16.
// ---------------------------------------------------------------------------
__global__ __launch_bounds__(256) void k_xproj_dt(const unsigned short* __restrict__ Wx,
                                                  const unsigned short* __restrict__ Wdtb,
                                                  const float* __restrict__ bdt,
                                                  float* __restrict__ dbcBC,
                                                  const unsigned short* __restrict__ ucb,
                                                  unsigned short* __restrict__ delb) {
  __shared__ __align__(16) unsigned short As[64 * 64];
  __shared__ __align__(16) unsigned short Bs[128 * 64];
  __shared__ __align__(16) unsigned short dtTl[128 * 32];
  __shared__ __align__(16) unsigned short Wl[128 * 32];
  const int l0 = blockIdx.x * 128;
  const int b  = blockIdx.y;
  const int t  = threadIdx.x;
  const int wave = t >> 6, lane = t & 63;
  const unsigned short* Bb = ucb + (size_t)b * kL * kDI;

  f32x4 acc[3][2];
#pragma unroll
  for (int i = 0; i < 3; ++i)
#pragma unroll
    for (int j = 0; j < 2; ++j) acc[i][j] = (f32x4)0.0f;

  const int srow = t >> 3, sch = t & 7;
  for (int kt = 0; kt < 8; ++kt) {
    const int k0 = kt * 64;
#pragma unroll
    for (int c = 0; c < 2; ++c) {
      int row = c * 32 + srow;
      int grow = row < 48 ? row : 47;
      int gch = sch ^ (row & 7);
      gload_lds16(Wx + (size_t)grow * kDI + k0 + gch * 8,
                  (char*)As + c * 4096 + wave * 1024);
    }
#pragma unroll
    for (int c = 0; c < 4; ++c) {
      int row = c * 32 + srow;
      int gch = sch ^ (row & 7);
      gload_lds16(Bb + (size_t)(l0 + row) * kDI + k0 + gch * 8,
                  (char*)Bs + c * 4096 + wave * 1024);
    }
    __syncthreads();
#pragma unroll
    for (int ks = 0; ks < 2; ++ks) {
      bf16x8 af[3], bfr[2];
#pragma unroll
      for (int f = 0; f < 3; ++f) {
        int ra = f * 16 + (lane & 15);
        int ca = (ks * 4 + (lane >> 4)) ^ (ra & 7);
        af[f] = *(const bf16x8*)((const char*)As + ra * 128 + ca * 16);
      }
#pragma unroll
      for (int f = 0; f < 2; ++f) {
        int rb = wave * 32 + f * 16 + (lane & 15);
        int cb = (ks * 4 + (lane >> 4)) ^ (rb & 7);
        bfr[f] = *(const bf16x8*)((const char*)Bs + rb * 128 + cb * 16);
      }
#pragma unroll
      for (int i = 0; i < 3; ++i)
#pragma unroll
        for (int j = 0; j < 2; ++j)
          acc[i][j] = __builtin_amdgcn_mfma_f32_16x16x32_bf16(af[i], bfr[j], acc[i][j], 0, 0, 0);
    }
    __syncthreads();
  }

  // phase-1 epilogue: B/C rows -> global; dt rows -> LDS (swizzled)
#pragma unroll
  for (int i = 1; i < 3; ++i)
#pragma unroll
    for (int j = 0; j < 2; ++j)
#pragma unroll
      for (int r = 0; r < 4; ++r) {
        int m = i * 16 + (lane >> 4) * 4 + r;
        int l = l0 + wave * 32 + j * 16 + (lane & 15);
        dbcBC[((size_t)b * 32 + (m - 16)) * kL + l] = acc[i][j][r];
      }
#pragma unroll
  for (int j = 0; j < 2; ++j) {
    int l = wave * 32 + j * 16 + (lane & 15);   // local l
    int m0 = (lane >> 4) * 4;
    ushort4 v;
    v.x = f2bf(acc[0][j][0]); v.y = f2bf(acc[0][j][1]);
    v.z = f2bf(acc[0][j][2]); v.w = f2bf(acc[0][j][3]);
    int byte = l * 64 + (((m0 >> 3) ^ (l & 3)) << 4) + ((m0 & 7) << 1);
    *(ushort4*)((char*)dtTl + byte) = v;
  }
  {
    int lz = t >> 1, zc = 2 + (t & 1);          // zero K-pad chunks 2,3
    *(uint4*)((char*)dtTl + lz * 64 + ((zc ^ (lz & 3)) << 4)) = make_uint4(0, 0, 0, 0);
  }
  __syncthreads();

  // phase 2: dt_proj, 4 d-tiles of 128
  const int wl = wave >> 1, wd = wave & 1;
  for (int dt4 = 0; dt4 < 4; ++dt4) {
#pragma unroll
    for (int c2 = 0; c2 < 2; ++c2) {
      int unit = c2 * 256 + t;
      int row = unit >> 2, sc = unit & 3;
      int gch = sc ^ (row & 3);
      gload_lds16(Wdtb + (size_t)(dt4 * 128 + row) * 32 + gch * 8,
                  (char*)Wl + c2 * 4096 + t * 16);
    }
    __syncthreads();
    f32x4 acc2[4][4];
#pragma unroll
    for (int i = 0; i < 4; ++i)
#pragma unroll
      for (int j = 0; j < 4; ++j) acc2[i][j] = (f32x4)0.0f;
    bf16x8 afr[4], bfr2[4];
#pragma unroll
    for (int f = 0; f < 4; ++f) {
      int ra = wl * 64 + f * 16 + (lane & 15);   // l row
      afr[f] = *(const bf16x8*)((const char*)dtTl + ra * 64 + (((lane >> 4) ^ (ra & 3)) << 4));
      int rb = wd * 64 + f * 16 + (lane & 15);   // d row
      bfr2[f] = *(const bf16x8*)((const char*)Wl + rb * 64 + (((lane >> 4) ^ (rb & 3)) << 4));
    }
#pragma unroll
    for (int i = 0; i < 4; ++i)
#pragma unroll
      for (int j = 0; j < 4; ++j)
        acc2[i][j] = __builtin_amdgcn_mfma_f32_16x16x32_bf16(afr[i], bfr2[j], acc2[i][j], 0, 0, 0);
#pragma unroll
    for (int j = 0; j < 4; ++j) {
      int d = dt4 * 128 + wd * 64 + j * 16 + (lane & 15);
      float bd = bdt[d];
#pragma unroll
      for (int i = 0; i < 4; ++i)
#pragma unroll
        for (int r = 0; r < 4; ++r) {
          int l = l0 + wl * 64 + i * 16 + (lane >> 4) * 4 + r;
          float delta = softplusf(acc2[i][j][r] + bd);
          delb[((size_t)b * kL + l) * kDI + d] = f2bf(delta);
        }
    }
    __syncthreads();
  }
}

// ---------------------------------------------------------------------------
// Scan phase A: reads delta bf16 + u bf16; E=exp(delta*Av0), du=delta*u;
// packed n-loop; P[n] = (prod E)^(n+1).
// ---------------------------------------------------------------------------
__global__ __launch_bounds__(256) void k_scanA(const unsigned short* __restrict__ delb,
                                               const unsigned short* __restrict__ ucb,
                                               const float* __restrict__ dbcBC,
                                               const float* __restrict__ A_log,
                                               const float* __restrict__ Avz,
                                               const unsigned int* __restrict__ flagA,
                                               float* __restrict__ P,
                                               float* __restrict__ S) {
  __shared__ __align__(16) float Bsh[16][kCS];
  const int b = blockIdx.z, ch = blockIdx.y;
  const int t = threadIdx.x;
  const int d = blockIdx.x * 256 + t;
  const int l0 = ch * kCS;
  {
    int row = t >> 4, li = (t & 15) * 2;
    *(float2*)&Bsh[row][li] =
        *(const float2*)&dbcBC[((size_t)b * 32 + row) * kL + l0 + li];
  }
  __syncthreads();
  const bool fast = (flagA[0] != 0u) && (flagA[1] != 0u);
  const float Av0 = Avz[d];
  const unsigned short* pDel = delb + ((size_t)b * kL + l0) * kDI + d;
  const unsigned short* pU = ucb + ((size_t)b * kL + l0) * kDI + d;
  size_t obase = (size_t)(b * kNC + ch) * (kN * kDI) + d;

  if (fast) {
    f32x2 Sv2[8];
#pragma unroll
    for (int m = 0; m < 8; ++m) Sv2[m] = (f32x2){0.f, 0.f};
    float Pprod = 1.f;
    for (int i = 0; i < kCS; i += 4) {
      f32x2 a2[4], e2[4], du2[4];
#pragma unroll
      for (int jj = 0; jj < 4; ++jj) {
        float dl = bf2f(pDel[(size_t)(i + jj) * kDI]);
        float uu = bf2f(pU[(size_t)(i + jj) * kDI]);
        float E = __expf(dl * Av0);
        float duv = dl * uu;
        du2[jj] = (f32x2){duv, duv};
        float Esq = E * E;
        a2[jj] = (f32x2){E, Esq};
        e2[jj] = (f32x2){Esq, Esq};
        Pprod *= E;
      }
#pragma unroll
      for (int m = 0; m < 8; ++m) {
        float4 Ba = *(const float4*)&Bsh[2 * m][i];
        float4 Bb = *(const float4*)&Bsh[2 * m + 1][i];
        Sv2[m] = Sv2[m] * a2[0] + du2[0] * (f32x2){Ba.x, Bb.x};
        Sv2[m] = Sv2[m] * a2[1] + du2[1] * (f32x2){Ba.y, Bb.y};
        Sv2[m] = Sv2[m] * a2[2] + du2[2] * (f32x2){Ba.z, Bb.z};
        Sv2[m] = Sv2[m] * a2[3] + du2[3] * (f32x2){Ba.w, Bb.w};
        if (m < 7) {
          a2[0] *= e2[0]; a2[1] *= e2[1]; a2[2] *= e2[2]; a2[3] *= e2[3];
        }
      }
    }
    float pw = Pprod;
#pragma unroll
    for (int n = 0; n < kN; ++n) {
      P[obase + (size_t)n * kDI] = pw;
      S[obase + (size_t)n * kDI] = (n & 1) ? Sv2[n >> 1].y : Sv2[n >> 1].x;
      pw *= Pprod;
    }
  } else {
    float Av[16];
#pragma unroll
    for (int n = 0; n < kN; ++n) Av[n] = -__expf(A_log[d * kN + n]);
    float Pv[16], Sv[16];
#pragma unroll
    for (int n = 0; n < kN; ++n) { Pv[n] = 1.f; Sv[n] = 0.f; }
    for (int i = 0; i < kCS; i += 4) {
      float del[4], du[4];
#pragma unroll
      for (int jj = 0; jj < 4; ++jj) {
        del[jj] = bf2f(pDel[(size_t)(i + jj) * kDI]);
        du[jj] = del[jj] * bf2f(pU[(size_t)(i + jj) * kDI]);
      }
#pragma unroll
      for (int n = 0; n < kN; ++n) {
        float4 B4 = *(const float4*)&Bsh[n][i];
        float a;
        a = __expf(del[0] * Av[n]); Pv[n] *= a; Sv[n] = Sv[n] * a + du[0] * B4.x;
        a = __expf(del[1] * Av[n]); Pv[n] *= a; Sv[n] = Sv[n] * a + du[1] * B4.y;
        a = __expf(del[2] * Av[n]); Pv[n] *= a; Sv[n] = Sv[n] * a + du[2] * B4.z;
        a = __expf(del[3] * Av[n]); Pv[n] *= a; Sv[n] = Sv[n] * a + du[3] * B4.w;
      }
    }
#pragma unroll
    for (int n = 0; n < kN; ++n) {
      P[obase + (size_t)n * kDI] = Pv[n];
      S[obase + (size_t)n * kDI] = Sv[n];
    }
  }
}

// ---------------------------------------------------------------------------
// Scan phase B: combine chunk summaries -> per-chunk init states. 8-deep.
// ---------------------------------------------------------------------------
__global__ __launch_bounds__(256) void k_scanB(const float* __restrict__ P,
                                               const float* __restrict__ S,
                                               float* __restrict__ init) {
  int idx = blockIdx.x * 256 + threadIdx.x;  // b*8192 + n*512 + d
  int b = idx >> 13, nd = idx & 8191;
  size_t base = (size_t)b * kNC * 8192 + nd;
  float carry = 0.f;
  for (int c0 = 0; c0 < kNC; c0 += 8) {
    float p[8], s[8];
#pragma unroll
    for (int j = 0; j < 8; ++j) {
      size_t o = base + (size_t)(c0 + j) * 8192;
      p[j] = P[o]; s[j] = S[o];
    }
#pragma unroll
    for (int j = 0; j < 8; ++j) {
      init[base + (size_t)(c0 + j) * 8192] = carry;
      carry = p[j] * carry + s[j];
    }
  }
}

// ---------------------------------------------------------------------------
// Scan phase C (+gate): reads delta,u,res,init; E/du recomputed; packed;
// g=(y+u*D)*silu(res) -> yt bf16.
// ---------------------------------------------------------------------------
__global__ __launch_bounds__(256) void k_scanC(const unsigned short* __restrict__ delb,
                                               const unsigned short* __restrict__ ucb,
                                               const float* __restrict__ dbcBC,
                                               const float* __restrict__ A_log,
                                               const float* __restrict__ Avz,
                                               const unsigned int* __restrict__ flagA,
                                               const float* __restrict__ init,
                                               const unsigned short* __restrict__ resb,
                                               const float* __restrict__ Dp,
                                               unsigned short* __restrict__ yt) {
  __shared__ __align__(16) float BCsh[32][kCS];  // 0-15 B, 16-31 C
  const int b = blockIdx.z, ch = blockIdx.y;
  const int t = threadIdx.x;
  const int d = blockIdx.x * 256 + t;
  const int l0 = ch * kCS;
  {
    int row = t >> 3, li = (t & 7) * 4;
    *(float4*)&BCsh[row][li] =
        *(const float4*)&dbcBC[((size_t)b * 32 + row) * kL + l0 + li];
  }
  __syncthreads();
  const bool fast = (flagA[0] != 0u) && (flagA[1] != 0u);
  const float Av0 = Avz[d];
  const float Dv = Dp[d];
  const unsigned short* pDel = delb + ((size_t)b * kL + l0) * kDI + d;
  const unsigned short* pU = ucb + ((size_t)b * kL + l0) * kDI + d;
  const unsigned short* pR = resb + ((size_t)b * kL + l0) * kDI + d;
  unsigned short* pY = yt + ((size_t)b * kL + l0) * kDI + d;
  size_t ibase = (size_t)(b * kNC + ch) * (kN * kDI) + d;

  if (fast) {
    f32x2 s2[8];
#pragma unroll
    for (int m = 0; m < 8; ++m)
      s2[m] = (f32x2){init[ibase + (size_t)(2 * m) * kDI],
                      init[ibase + (size_t)(2 * m + 1) * kDI]};
    for (int i = 0; i < kCS; i += 4) {
      float uv[4];
      f32x2 a2[4], e2[4], du2[4], yacc2[4];
#pragma unroll
      for (int jj = 0; jj < 4; ++jj) {
        float dl = bf2f(pDel[(size_t)(i + jj) * kDI]);
        uv[jj] = bf2f(pU[(size_t)(i + jj) * kDI]);
        float E = __expf(dl * Av0);
        float duv = dl * uv[jj];
        du2[jj] = (f32x2){duv, duv};
        float Esq = E * E;
        a2[jj] = (f32x2){E, Esq};
        e2[jj] = (f32x2){Esq, Esq};
        yacc2[jj] = (f32x2){0.f, 0.f};
      }
#pragma unroll
      for (int m = 0; m < 8; ++m) {
        float4 Ba = *(const float4*)&BCsh[2 * m][i];
        float4 Bb = *(const float4*)&BCsh[2 * m + 1][i];
        float4 Ca = *(const float4*)&BCsh[16 + 2 * m][i];
        float4 Cb = *(const float4*)&BCsh[16 + 2 * m + 1][i];
        s2[m] = s2[m] * a2[0] + du2[0] * (f32x2){Ba.x, Bb.x};
        yacc2[0] = yacc2[0] + s2[m] * (f32x2){Ca.x, Cb.x};
        s2[m] = s2[m] * a2[1] + du2[1] * (f32x2){Ba.y, Bb.y};
        yacc2[1] = yacc2[1] + s2[m] * (f32x2){Ca.y, Cb.y};
        s2[m] = s2[m] * a2[2] + du2[2] * (f32x2){Ba.z, Bb.z};
        yacc2[2] = yacc2[2] + s2[m] * (f32x2){Ca.z, Cb.z};
        s2[m] = s2[m] * a2[3] + du2[3] * (f32x2){Ba.w, Bb.w};
        yacc2[3] = yacc2[3] + s2[m] * (f32x2){Ca.w, Cb.w};
        if (m < 7) {
          a2[0] *= e2[0]; a2[1] *= e2[1]; a2[2] *= e2[2]; a2[3] *= e2[3];
        }
      }
#pragma unroll
      for (int jj = 0; jj < 4; ++jj) {
        float yv = yacc2[jj].x + yacc2[jj].y;
        float r = bf2f(pR[(size_t)(i + jj) * kDI]);
        float gv = (yv + uv[jj] * Dv) * siluf(r);
        pY[(size_t)(i + jj) * kDI] = f2bf(gv);
      }
    }
  } else {
    float Av[16];
#pragma unroll
    for (int n = 0; n < kN; ++n) Av[n] = -__expf(A_log[d * kN + n]);
    float s[16];
#pragma unroll
    for (int n = 0; n < kN; ++n) s[n] = init[ibase + (size_t)n * kDI];
    for (int i = 0; i < kCS; i += 4) {
      float uv[4], du[4], del[4], yacc[4] = {0.f, 0.f, 0.f, 0.f};
#pragma unroll
      for (int jj = 0; jj < 4; ++jj) {
        del[jj] = bf2f(pDel[(size_t)(i + jj) * kDI]);
        uv[jj] = bf2f(pU[(size_t)(i + jj) * kDI]);
        du[jj] = del[jj] * uv[jj];
      }
#pragma unroll
      for (int n = 0; n < kN; ++n) {
        float4 B4 = *(const float4*)&BCsh[n][i];
        float4 C4 = *(const float4*)&BCsh[16 + n][i];
        float a;
        a = __expf(del[0] * Av[n]); s[n] = s[n] * a + du[0] * B4.x; yacc[0] += s[n] * C4.x;
        a = __expf(del[1] * Av[n]); s[n] = s[n] * a + du[1] * B4.y; yacc[1] += s[n] * C4.y;
        a = __expf(del[2] * Av[n]); s[n] = s[n] * a + du[2] * B4.z; yacc[2] += s[n] * C4.z;
        a = __expf(del[3] * Av[n]); s[n] = s[n] * a + du[3] * B4.w; yacc[3] += s[n] * C4.w;
      }
#pragma unroll
      for (int jj = 0; jj < 4; ++jj) {
        float r = bf2f(pR[(size_t)(i + jj) * kDI]);
        float gv = (yacc[jj] + uv[jj] * Dv) * siluf(r);
        pY[(size_t)(i + jj) * kDI] = f2bf(gv);
      }
    }
  }
}

// ---------------------------------------------------------------------------
// out_proj GEMM: out[b][c][l] = sum_k Wo[c,k] * yt[b,l,k].
// ---------------------------------------------------------------------------
__global__ __launch_bounds__(256) void gemm_out(const unsigned short* __restrict__ A,
                                                const unsigned short* __restrict__ Bt,
                                                float* __restrict__ C0) {
  __shared__ __align__(16) unsigned short As[128 * 64];
  __shared__ __align__(16) unsigned short Bs[128 * 64];
  const int n0 = blockIdx.x * 128;
  const int m0 = blockIdx.y * 128;
  const int b  = blockIdx.z;
  const int t  = threadIdx.x;
  const int wave = t >> 6, lane = t & 63;
  const int wm = wave >> 1, wn = wave & 1;
  const unsigned short* Bb = Bt + (size_t)b * kL * kDI;

  f32x4 acc[4][4];
#pragma unroll
  for (int i = 0; i < 4; ++i)
#pragma unroll
    for (int j = 0; j < 4; ++j) acc[i][j] = (f32x4)0.0f;

  const int srow = t >> 3, sch = t & 7;
  for (int kt = 0; kt < 8; ++kt) {
    const int k0 = kt * 64;
#pragma unroll
    for (int c = 0; c < 4; ++c) {
      int row = c * 32 + srow;
      int gch = sch ^ (row & 7);
      gload_lds16(A  + (size_t)(m0 + row) * kDI + k0 + gch * 8,
                  (char*)As + c * 4096 + wave * 1024);
      gload_lds16(Bb + (size_t)(n0 + row) * kDI + k0 + gch * 8,
                  (char*)Bs + c * 4096 + wave * 1024);
    }
    __syncthreads();
#pragma unroll
    for (int ks = 0; ks < 2; ++ks) {
      bf16x8 af[4], bfr[4];
#pragma unroll
      for (int f = 0; f < 4; ++f) {
        int ra = wm * 64 + f * 16 + (lane & 15);
        int ca = (ks * 4 + (lane >> 4)) ^ (ra & 7);
        af[f] = *(const bf16x8*)((const char*)As + ra * 128 + ca * 16);
        int rb = wn * 64 + f * 16 + (lane & 15);
        int cb = (ks * 4 + (lane >> 4)) ^ (rb & 7);
        bfr[f] = *(const bf16x8*)((const char*)Bs + rb * 128 + cb * 16);
      }
#pragma unroll
      for (int i = 0; i < 4; ++i)
#pragma unroll
        for (int j = 0; j < 4; ++j)
          acc[i][j] = __builtin_amdgcn_mfma_f32_16x16x32_bf16(af[i], bfr[j], acc[i][j], 0, 0, 0);
    }
    __syncthreads();
  }
#pragma unroll
  for (int i = 0; i < 4; ++i)
#pragma unroll
    for (int j = 0; j < 4; ++j)
#pragma unroll
      for (int r = 0; r < 4; ++r) {
        int m = m0 + wm * 64 + i * 16 + (lane >> 4) * 4 + r;
        int n = n0 + wn * 64 + j * 16 + (lane & 15);
        C0[((size_t)b * kDim + m) * kL + n] = acc[i][j][r];
      }
}

// ---------------------------------------------------------------------------
extern "C" void kernel_launch(void* const* d_in, const int* in_sizes, int n_in,
                              void* d_out, int out_size, void* d_ws, size_t ws_size,
                              hipStream_t stream) {
  const float* x       = (const float*)d_in[0];
  const float* in_w    = (const float*)d_in[1];
  const float* conv_w  = (const float*)d_in[2];
  const float* conv_b  = (const float*)d_in[3];
  const float* xproj_w = (const float*)d_in[4];
  const float* dt_w    = (const float*)d_in[5];
  const float* dt_b    = (const float*)d_in[6];
  const float* A_log   = (const float*)d_in[7];
  const float* Dp      = (const float*)d_in[8];
  const float* out_w   = (const float*)d_in[9];
  float* out = (float*)d_out;

  // workspace layout (~121 MB)
  float* ws = (float*)d_ws;
  const size_t nBLD  = (size_t)kB * kL * kDI;                 // 8388608
  const size_t nPS   = (size_t)kB * kNC * kN * kDI;           // 4194304
  float* dbcBC = ws;                                          // 524288 f
  float* Pb    = dbcBC + 524288;                              // nPS
  float* Sb    = Pb + nPS;                                    // nPS
  float* initb = Sb + nPS;                                    // nPS
  unsigned short* ubf  = (unsigned short*)(initb + nPS);      // nBLD us
  unsigned short* ucb  = ubf + nBLD;                          // nBLD us
  unsigned short* resb = ucb + nBLD;                          // nBLD us
  unsigned short* delb = resb + nBLD;                         // nBLD us
  unsigned short* wib  = delb + nBLD;                         // 262144
  unsigned short* wob  = wib + 262144;                        // 131072
  unsigned short* wxb  = wob + 131072;                        // 24576
  unsigned short* wdtb = wxb + 24576;                         // 32768
  float* Avz           = (float*)(wdtb + 32768);              // 512 f
  unsigned int* flagA  = (unsigned int*)(Avz + 512);          // 2 u32
  unsigned short* xt   = delb;                                // overlay: xt dead before k_xproj_dt
  unsigned short* yt   = (unsigned short*)Pb;                 // overlay after scanB

  k_prep<<<dim3(2786), 256, 0, stream>>>(in_w, out_w, xproj_w, dt_w, A_log, x,
                                         wib, wob, wxb, wdtb, Avz, flagA, xt);
  gemm_in_lm<<<dim3(8, kL / 128, kB), 256, 0, stream>>>(xt, wib, ubf, resb);
  k_conv<<<dim3((unsigned)(kB * kL * 64 / 256)), 256, 0, stream>>>(ubf, conv_w, conv_b, ucb);
  k_xproj_dt<<<dim3(kL / 128, kB), 256, 0, stream>>>(wxb, wdtb, dt_b, dbcBC, ucb, delb);
  k_scanA<<<dim3(2, kNC, kB), 256, 0, stream>>>(delb, ucb, dbcBC, A_log, Avz, flagA, Pb, Sb);
  k_scanB<<<dim3(kB * kDI * kN / 256), 256, 0, stream>>>(Pb, Sb, initb);
  k_scanC<<<dim3(2, kNC, kB), 256, 0, stream>>>(delb, ucb, dbcBC, A_log, Avz, flagA, initb, resb, Dp, yt);
  gemm_out<<<dim3(kL / 128, kDim / 128, kB), 256, 0, stream>>>(wob, yt, out);
}